// Round 1
// baseline (29295.273 us; speedup 1.0000x reference)
//
#include <hip/hip_runtime.h>
#include <stdint.h>
#include <math.h>

// ============================================================================
// Seq2SeqReinforce — full model in one persistent kernel (MI355X / gfx950).
// Round 1: correctness-first.
//
// Roles (grid = 256 WGs x 256 thr, all co-resident):
//   WG 0..15   : "cluster" — sequential LSTM scans (encoder + O(T^2) decoder),
//                fc1 + LayerNorm. Syncs via monotonic LLC counter barriers.
//   WG 16      : "leader"  — lse + sampling + token update + embed + px0[t].
//   WG 17..255 : "gang"    — fc2 logits + gumbel + argmax/max/sumexp reduce.
// All cross-WG data uses relaxed AGENT-scope atomics (bypass non-coherent
// per-XCD L2 to LLC). Flags: release fetch_add / relaxed spin + signal fence.
// hipMemsetAsync zeroes the ws (counters + initial h-state) every call so
// graph replays are re-entrant.
// ============================================================================

#define PARTITIONABLE_PRNG 1   // JAX >= 0.4.36 default (jax_threefry_partitionable=True).
                               // If tokens mismatch next round: set to 0 (legacy layout).

namespace s2sr {

constexpr int kV = 50257, kE = 256, kH = 256, kCc = 64, kB = 4, kT = 48;
constexpr int kZ = kH + kCc;   // 320
constexpr int kG = 4 * kH;     // 1024
constexpr int kMask = 103;
constexpr float kEps = 1e-5f;
constexpr float kTiny = 1.17549435e-38f;

constexpr int NWG = 256;
constexpr int NCL = 16;
constexpr int LEAD = 16;
constexpr int GANG0 = 17;
constexpr int NGANG = NWG - GANG0;            // 239
constexpr int RPW = (kV + NGANG - 1) / NGANG; // 211 rows per gang WG

struct SyncBlk {
  unsigned int ictr;              // init barrier counter (targets 256, 512)
  unsigned int cctr;              // cluster barrier counter (monotonic)
  unsigned int Z[kT];             // z1n(t) ready (==1)
  unsigned int zread[kT];         // gang staged z1n(t) (==NGANG)
  unsigned int ctrA[kT];          // gang pass-1 done
  unsigned int ctrB[kT];          // gang pass-2 done
  unsigned int Ptok[kT];          // px0[t] ready (==1)
  unsigned long long argkey[kT][kB]; // atomicMax (ordkey(l+g)<<32 | ~row)
  unsigned int maxbits[kT][kB];      // atomicMax ordkey(max logits) for lse
  float psum[NGANG][kB];          // per-WG partial sum(exp(l-max))
};

struct WS {
  SyncBlk s;
  float h0buf[2][kB][kH];   // layer-0 h, double-buffered by position parity
  float h1buf[2][kB][kH];   // layer-1 h
  float cls[kB][kCc];
  float xd0[kB][kH];        // decoder x for position 0
  float z1pre[kB][kZ];      // fc1 pre-activation
  float z1n[2][kB][kZ];     // LN output, double-buffered by t&1
  float px0[kT][kB][kG];    // decoder layer-0 x-part: x_j @ decWih0^T
  float pxe[kT][kB][kG];    // encoder layer-0 x-part
};

static_assert(sizeof(WS) < 4u * 1024u * 1024u, "ws too big");

// ---------------- atomic helpers ----------------
__device__ __forceinline__ float aldf(const float* p) {
  return __hip_atomic_load(p, __ATOMIC_RELAXED, __HIP_MEMORY_SCOPE_AGENT);
}
__device__ __forceinline__ void astf(float* p, float v) {
  __hip_atomic_store(p, v, __ATOMIC_RELAXED, __HIP_MEMORY_SCOPE_AGENT);
}
__device__ __forceinline__ unsigned ldu(const unsigned* p) {
  return __hip_atomic_load(p, __ATOMIC_RELAXED, __HIP_MEMORY_SCOPE_AGENT);
}
__device__ __forceinline__ void relfetchadd(unsigned* p) {
  __hip_atomic_fetch_add(p, 1u, __ATOMIC_RELEASE, __HIP_MEMORY_SCOPE_AGENT);
}
__device__ __forceinline__ void spinwait(unsigned* p, unsigned tgt) {
  if (threadIdx.x == 0) {
    while (__hip_atomic_load(p, __ATOMIC_RELAXED, __HIP_MEMORY_SCOPE_AGENT) < tgt)
      __builtin_amdgcn_s_sleep(2);
    __atomic_signal_fence(__ATOMIC_ACQUIRE);
  }
  __syncthreads();
}
__device__ __forceinline__ void cbar(WS* ws, unsigned& ep) {
  __syncthreads();
  if (threadIdx.x == 0) relfetchadd(&ws->s.cctr);
  ep += (unsigned)NCL;
  spinwait(&ws->s.cctr, ep);
}
__device__ __forceinline__ void gbar(WS* ws, unsigned tgt) {
  __syncthreads();
  if (threadIdx.x == 0) relfetchadd(&ws->s.ictr);
  spinwait(&ws->s.ictr, tgt);
}

// ---------------- Threefry2x32 (matches JAX exactly) ----------------
__device__ __forceinline__ unsigned rotl32(unsigned v, int n) {
  return (v << n) | (v >> (32 - n));
}
__device__ __forceinline__ void tf2x32(unsigned k0, unsigned k1, unsigned x0, unsigned x1,
                                       unsigned& o0, unsigned& o1) {
  const unsigned k2 = k0 ^ k1 ^ 0x1BD11BDAu;
  unsigned v0 = x0 + k0, v1 = x1 + k1;
  v0 += v1; v1 = rotl32(v1, 13); v1 ^= v0;
  v0 += v1; v1 = rotl32(v1, 15); v1 ^= v0;
  v0 += v1; v1 = rotl32(v1, 26); v1 ^= v0;
  v0 += v1; v1 = rotl32(v1, 6);  v1 ^= v0;
  v0 += k1; v1 += k2 + 1u;
  v0 += v1; v1 = rotl32(v1, 17); v1 ^= v0;
  v0 += v1; v1 = rotl32(v1, 29); v1 ^= v0;
  v0 += v1; v1 = rotl32(v1, 16); v1 ^= v0;
  v0 += v1; v1 = rotl32(v1, 24); v1 ^= v0;
  v0 += k2; v1 += k0 + 2u;
  v0 += v1; v1 = rotl32(v1, 13); v1 ^= v0;
  v0 += v1; v1 = rotl32(v1, 15); v1 ^= v0;
  v0 += v1; v1 = rotl32(v1, 26); v1 ^= v0;
  v0 += v1; v1 = rotl32(v1, 6);  v1 ^= v0;
  v0 += k0; v1 += k1 + 3u;
  v0 += v1; v1 = rotl32(v1, 17); v1 ^= v0;
  v0 += v1; v1 = rotl32(v1, 29); v1 ^= v0;
  v0 += v1; v1 = rotl32(v1, 16); v1 ^= v0;
  v0 += v1; v1 = rotl32(v1, 24); v1 ^= v0;
  v0 += k1; v1 += k2 + 4u;
  v0 += v1; v1 = rotl32(v1, 13); v1 ^= v0;
  v0 += v1; v1 = rotl32(v1, 15); v1 ^= v0;
  v0 += v1; v1 = rotl32(v1, 26); v1 ^= v0;
  v0 += v1; v1 = rotl32(v1, 6);  v1 ^= v0;
  o0 = v0 + k2; o1 = v1 + k0 + 5u;
}
__device__ __forceinline__ unsigned rbits(unsigned k0, unsigned k1, unsigned i) {
#if PARTITIONABLE_PRNG
  unsigned a, b; tf2x32(k0, k1, 0u, i, a, b);
  return a ^ b;
#else
  constexpr unsigned HALF = (unsigned)((kB * kV + 1) / 2); // 100514
  unsigned a, b;
  if (i < HALF) { tf2x32(k0, k1, i, i + HALF, a, b); return a; }
  tf2x32(k0, k1, i - HALF, i, a, b); return b;
#endif
}
__device__ __forceinline__ float gumbel_from_bits(unsigned bits) {
  float f = __uint_as_float((bits >> 9) | 0x3f800000u) - 1.0f;
  f = fmaxf(f, kTiny);            // == u*(1-tiny)+tiny then max(tiny,.) in f32
  return -logf(-logf(f));
}
__device__ __forceinline__ unsigned ordkey(float f) {
  const unsigned u = __float_as_uint(f);
  return (u & 0x80000000u) ? ~u : (u | 0x80000000u);
}
__device__ __forceinline__ float inv_ordkey(unsigned x) {
  const unsigned u = (x & 0x80000000u) ? (x & 0x7FFFFFFFu) : ~x;
  return __uint_as_float(u);
}
__device__ __forceinline__ unsigned long long shflx64(unsigned long long v, int m) {
  unsigned lo = (unsigned)v, hi = (unsigned)(v >> 32);
  lo = (unsigned)__shfl_xor((int)lo, m, 64);
  hi = (unsigned)__shfl_xor((int)hi, m, 64);
  return ((unsigned long long)hi << 32) | (unsigned long long)lo;
}
__device__ __forceinline__ float sigm(float x) { return 1.0f / (1.0f + expf(-x)); }

// ---------------- LSTM position phases (cluster) ----------------
// Thread map for gate dots: tid -> (b = tid>>6, hl = (tid>>2)&15, ks = tid&3).
// WG wg owns hidx in [wg*16, wg*16+16) for ALL batches; each thread computes 4
// gate partial-dots over a k-quarter; LDS reduce; threads 0..63 hold c-state in
// registers and publish h to ws (LLC).
__device__ __forceinline__ void posA(WS* ws, float* shf,
    const float* __restrict__ Whh, const float* __restrict__ bih,
    const float* __restrict__ bhh, const float* __restrict__ px,
    int P, float& c0, unsigned& ep, int wg)
{
  const int tid = (int)threadIdx.x;
  const int pp = (P + 1) & 1, pc = P & 1;
  const float* h0prev = &ws->h0buf[pp][0][0];
  for (int i = tid; i < kB * kH; i += 256) shf[i] = aldf(h0prev + i);
  __syncthreads();
  {
    const int b = tid >> 6, hl = (tid >> 2) & 15, ks = tid & 3;
    const int hidx = wg * 16 + hl;
    const float* hv = &shf[b * kH + ks * 64];
#pragma unroll
    for (int g = 0; g < 4; g++) {
      const float* wr = Whh + (size_t)(g * 256 + hidx) * kH + ks * 64;
      float acc = 0.f;
      for (int k = 0; k < 64; k += 4) {
        const float4 wv = *reinterpret_cast<const float4*>(wr + k);
        const float4 xv = *reinterpret_cast<const float4*>(hv + k);
        acc = fmaf(xv.x, wv.x, acc); acc = fmaf(xv.y, wv.y, acc);
        acc = fmaf(xv.z, wv.z, acc); acc = fmaf(xv.w, wv.w, acc);
      }
      shf[1024 + tid * 4 + g] = acc;   // disjoint from staged region
    }
  }
  __syncthreads();
  if (tid < 64) {
    const int fb = tid >> 4, fh = tid & 15;
    const int tb = fb * 64 + fh * 4;
    const int hidx = wg * 16 + fh;
    float z[4];
#pragma unroll
    for (int g = 0; g < 4; g++) {
      const int row = g * 256 + hidx;
      z[g] = shf[1024 + (tb + 0) * 4 + g] + shf[1024 + (tb + 1) * 4 + g]
           + shf[1024 + (tb + 2) * 4 + g] + shf[1024 + (tb + 3) * 4 + g];
      z[g] += aldf(px + (size_t)fb * kG + row) + bih[row] + bhh[row];
    }
    const float cn = sigm(z[1]) * c0 + sigm(z[0]) * tanhf(z[2]);
    const float hn = sigm(z[3]) * tanhf(cn);
    c0 = cn;
    astf(&ws->h0buf[pc][fb][hidx], hn);
  }
  cbar(ws, ep);
}

__device__ __forceinline__ void posB(WS* ws, float* shf,
    const float* __restrict__ Wih, const float* __restrict__ Whh,
    const float* __restrict__ bih, const float* __restrict__ bhh,
    int P, float& c1, unsigned& ep, int wg)
{
  const int tid = (int)threadIdx.x;
  const int pp = (P + 1) & 1, pc = P & 1;
  const float* h0cur = &ws->h0buf[pc][0][0];
  const float* h1prev = &ws->h1buf[pp][0][0];
  for (int i = tid; i < kB * kH; i += 256) shf[i] = aldf(h0cur + i);
  for (int i = tid; i < kB * kH; i += 256) shf[kB * kH + i] = aldf(h1prev + i);
  __syncthreads();
  {
    const int b = tid >> 6, hl = (tid >> 2) & 15, ks = tid & 3;
    const int hidx = wg * 16 + hl;
#pragma unroll
    for (int g = 0; g < 4; g++) {
      const int row = g * 256 + hidx;
      const float* wr;
      const float* hv;
      if (ks < 2) { wr = Wih + (size_t)row * kH + ks * 128; hv = &shf[b * kH + ks * 128]; }
      else        { wr = Whh + (size_t)row * kH + (ks - 2) * 128; hv = &shf[kB * kH + b * kH + (ks - 2) * 128]; }
      float acc = 0.f;
      for (int k = 0; k < 128; k += 4) {
        const float4 wv = *reinterpret_cast<const float4*>(wr + k);
        const float4 xv = *reinterpret_cast<const float4*>(hv + k);
        acc = fmaf(xv.x, wv.x, acc); acc = fmaf(xv.y, wv.y, acc);
        acc = fmaf(xv.z, wv.z, acc); acc = fmaf(xv.w, wv.w, acc);
      }
      shf[2048 + tid * 4 + g] = acc;
    }
  }
  __syncthreads();
  if (tid < 64) {
    const int fb = tid >> 4, fh = tid & 15;
    const int tb = fb * 64 + fh * 4;
    const int hidx = wg * 16 + fh;
    float z[4];
#pragma unroll
    for (int g = 0; g < 4; g++) {
      const int row = g * 256 + hidx;
      z[g] = shf[2048 + (tb + 0) * 4 + g] + shf[2048 + (tb + 1) * 4 + g]
           + shf[2048 + (tb + 2) * 4 + g] + shf[2048 + (tb + 3) * 4 + g]
           + bih[row] + bhh[row];
    }
    const float cn = sigm(z[1]) * c1 + sigm(z[0]) * tanhf(z[2]);
    const float hn = sigm(z[3]) * tanhf(cn);
    c1 = cn;
    astf(&ws->h1buf[pc][fb][hidx], hn);
  }
  cbar(ws, ep);
}

__device__ __forceinline__ void fc1phase(WS* ws, float* shf,
    const float* __restrict__ Wfc1, const float* __restrict__ bfc1,
    int plast, unsigned& ep, int wg)
{
  const int tid = (int)threadIdx.x;
  for (int i = tid; i < kB * kZ; i += 256) {
    const int b = i / kZ, k = i % kZ;
    shf[i] = (k < kH) ? aldf(&ws->h1buf[plast][b][k]) : aldf(&ws->cls[b][k - kH]);
  }
  __syncthreads();
  if (tid < 80) {
    const int b = tid / 20, o = wg * 20 + tid % 20;
    const float* wr = Wfc1 + (size_t)o * kZ;
    float acc = bfc1[o];
    for (int k = 0; k < kZ; k += 4) {
      const float4 wv = *reinterpret_cast<const float4*>(wr + k);
      const float4 zv = *reinterpret_cast<const float4*>(&shf[b * kZ + k]);
      acc = fmaf(zv.x, wv.x, acc); acc = fmaf(zv.y, wv.y, acc);
      acc = fmaf(zv.z, wv.z, acc); acc = fmaf(zv.w, wv.w, acc);
    }
    astf(&ws->z1pre[b][o], acc);
  }
  cbar(ws, ep);
}

__device__ __forceinline__ void lnphase(WS* ws, float* shf,
    const float* __restrict__ lng, const float* __restrict__ lnb,
    int t, unsigned& ep, int wg)
{
  // before overwriting z1n[t&1], ensure the gang finished staging z1n of step t-2
  if (t >= 3) spinwait(&ws->s.zread[t - 2], (unsigned)NGANG);
  const int tid = (int)threadIdx.x;
  if (wg == 0) {
    for (int i = tid; i < kB * kZ; i += 256)
      shf[i] = fmaxf(aldf(&ws->z1pre[0][0] + i), 0.f);   // relu
    __syncthreads();
    const int b = tid >> 6, ln = tid & 63;               // one wave per batch
    float s1 = 0.f, s2 = 0.f;
    for (int i = ln; i < kZ; i += 64) { const float v = shf[b * kZ + i]; s1 += v; s2 += v * v; }
#pragma unroll
    for (int off = 32; off > 0; off >>= 1) { s1 += __shfl_xor(s1, off, 64); s2 += __shfl_xor(s2, off, 64); }
    const float mu = s1 * (1.0f / kZ);
    const float var = s2 * (1.0f / kZ) - mu * mu;        // biased var
    const float rs = 1.0f / sqrtf(var + kEps);
    for (int i = ln; i < kZ; i += 64) {
      const float v = shf[b * kZ + i];
      astf(&ws->z1n[t & 1][b][i], fmaf((v - mu) * rs, lng[i], lnb[i]));
    }
  }
  cbar(ws, ep);
  if (wg == 0 && tid == 0) relfetchadd(&ws->s.Z[t]);
}

// ---------------- kernel ----------------
__global__ void __launch_bounds__(256) s2s_kernel(
    const int* __restrict__ input_ids, const float* __restrict__ labels,
    const float* __restrict__ emb,
    const float* __restrict__ W_e2e, const float* __restrict__ b_e2e,
    const float* __restrict__ W_e2d, const float* __restrict__ b_e2d,
    const float* __restrict__ encWih, const float* __restrict__ encWhh,
    const float* __restrict__ encbih, const float* __restrict__ encbhh,
    const float* __restrict__ decWih, const float* __restrict__ decWhh,
    const float* __restrict__ decbih, const float* __restrict__ decbhh,
    const float* __restrict__ W_cls, const float* __restrict__ b_cls,
    const float* __restrict__ Wfc1, const float* __restrict__ bfc1,
    const float* __restrict__ lng, const float* __restrict__ lnb,
    const float* __restrict__ W_fc2, const float* __restrict__ b_fc2,
    float* __restrict__ out, WS* __restrict__ ws)
{
  const int wg = (int)blockIdx.x;
  const int tid = (int)threadIdx.x;
  __shared__ float shf[3136];
  __shared__ unsigned long long shk[16];
  __shared__ int shi[8];

  // ================= init phase 1 =================
  if (wg < kB * kT) {
    // xe row (b,j): relu(emb[id] @ W_e2e^T + b_e2e), kept in LDS for phase 2
    const int b = wg / kT, j = wg % kT;
    const int id = input_ids[b * kT + j];
    for (int i = tid; i < kE; i += 256) shf[i] = emb[(size_t)id * kE + i];
    __syncthreads();
    const float* wr = W_e2e + (size_t)tid * kE;
    float acc = b_e2e[tid];
    for (int k = 0; k < kE; k += 4) {
      const float4 wv = *reinterpret_cast<const float4*>(wr + k);
      const float4 xv = *reinterpret_cast<const float4*>(&shf[k]);
      acc = fmaf(xv.x, wv.x, acc); acc = fmaf(xv.y, wv.y, acc);
      acc = fmaf(xv.z, wv.z, acc); acc = fmaf(xv.w, wv.w, acc);
    }
    __syncthreads();
    shf[256 + tid] = fmaxf(acc, 0.f);
    (void)j;
  } else if (wg == 192) {
    if (tid < kB * kCc) {
      const int b = tid >> 6, c = tid & 63;
      astf(&ws->cls[b][c], fmaf(labels[b], W_cls[c], b_cls[c]));
    }
    if (tid < kB) {
      const int t0 = input_ids[tid * kT];
      out[tid * kT] = 0.f;                       // scores[:,0] = 0
      out[kB * kT + tid * kT] = (float)t0;       // tokens[:,0] = input_ids[:,0]
    }
  } else if (wg == 193) {
    // xd0 = relu(emb[tok0] @ W_e2d^T + b_e2d)
    const float* wr = W_e2d + (size_t)tid * kE;
    const float* e0 = emb + (size_t)input_ids[0 * kT] * kE;
    const float* e1 = emb + (size_t)input_ids[1 * kT] * kE;
    const float* e2 = emb + (size_t)input_ids[2 * kT] * kE;
    const float* e3 = emb + (size_t)input_ids[3 * kT] * kE;
    const float bb = b_e2d[tid];
    float a0 = bb, a1 = bb, a2 = bb, a3 = bb;
    for (int k = 0; k < kE; k += 4) {
      const float4 wv = *reinterpret_cast<const float4*>(wr + k);
      const float4 v0 = *reinterpret_cast<const float4*>(e0 + k);
      const float4 v1 = *reinterpret_cast<const float4*>(e1 + k);
      const float4 v2 = *reinterpret_cast<const float4*>(e2 + k);
      const float4 v3 = *reinterpret_cast<const float4*>(e3 + k);
      a0 = fmaf(v0.x, wv.x, a0); a0 = fmaf(v0.y, wv.y, a0); a0 = fmaf(v0.z, wv.z, a0); a0 = fmaf(v0.w, wv.w, a0);
      a1 = fmaf(v1.x, wv.x, a1); a1 = fmaf(v1.y, wv.y, a1); a1 = fmaf(v1.z, wv.z, a1); a1 = fmaf(v1.w, wv.w, a1);
      a2 = fmaf(v2.x, wv.x, a2); a2 = fmaf(v2.y, wv.y, a2); a2 = fmaf(v2.z, wv.z, a2); a2 = fmaf(v2.w, wv.w, a2);
      a3 = fmaf(v3.x, wv.x, a3); a3 = fmaf(v3.y, wv.y, a3); a3 = fmaf(v3.z, wv.z, a3); a3 = fmaf(v3.w, wv.w, a3);
    }
    astf(&ws->xd0[0][tid], fmaxf(a0, 0.f));
    astf(&ws->xd0[1][tid], fmaxf(a1, 0.f));
    astf(&ws->xd0[2][tid], fmaxf(a2, 0.f));
    astf(&ws->xd0[3][tid], fmaxf(a3, 0.f));
  }
  gbar(ws, (unsigned)NWG);

  // ================= init phase 2 =================
  if (wg < kB * kT) {
    // pxe[j][b][:] = xe(row in LDS) @ encWih0^T
    const int b = wg / kT, j = wg % kT;
#pragma unroll
    for (int r = 0; r < 4; r++) {
      const int g = r * 256 + tid;
      const float* wr = encWih + (size_t)g * kH;     // layer 0
      float acc = 0.f;
      for (int k = 0; k < kH; k += 4) {
        const float4 wv = *reinterpret_cast<const float4*>(wr + k);
        const float4 xv = *reinterpret_cast<const float4*>(&shf[256 + k]);
        acc = fmaf(xv.x, wv.x, acc); acc = fmaf(xv.y, wv.y, acc);
        acc = fmaf(xv.z, wv.z, acc); acc = fmaf(xv.w, wv.w, acc);
      }
      astf(&ws->pxe[j][0][0] + (size_t)b * kG + g, acc);
    }
  } else if (wg >= 192 && wg < 208) {
    // px0[0][b][:] = xd0[b] @ decWih0^T
    const int w2 = wg - 192, b = w2 >> 2, q = w2 & 3;
    const int g = q * 256 + tid;
    for (int i = tid; i < kH; i += 256) shf[i] = aldf(&ws->xd0[b][i]);
    __syncthreads();
    const float* wr = decWih + (size_t)g * kH;
    float acc = 0.f;
    for (int k = 0; k < kH; k += 4) {
      const float4 wv = *reinterpret_cast<const float4*>(wr + k);
      const float4 xv = *reinterpret_cast<const float4*>(&shf[k]);
      acc = fmaf(xv.x, wv.x, acc); acc = fmaf(xv.y, wv.y, acc);
      acc = fmaf(xv.z, wv.z, acc); acc = fmaf(xv.w, wv.w, acc);
    }
    astf(&ws->px0[0][0][0] + (size_t)b * kG + g, acc);
  }
  gbar(ws, (unsigned)(2 * NWG));

  // ================= roles =================
  if (wg < NCL) {
    // ---------------- cluster ----------------
    unsigned ep = 0;
    float c0 = 0.f, c1 = 0.f;   // c-state lives in registers of threads 0..63
    int P = 0;
    const float* eWih1 = encWih + (size_t)kG * kH;
    const float* eWhh1 = encWhh + (size_t)kG * kH;
    const float* dWih1 = decWih + (size_t)kG * kH;
    const float* dWhh1 = decWhh + (size_t)kG * kH;
    // encoder: 48 positions
    for (int j = 0; j < kT; j++, P++) {
      posA(ws, shf, encWhh, encbih, encbhh, &ws->pxe[j][0][0], P, c0, ep, wg);
      posB(ws, shf, eWih1, eWhh1, encbih + kG, encbhh + kG, P, c1, ep, wg);
    }
    // decoder: scan t re-processes prefix 0..t-1 with accumulated state
    for (int t = 1; t < kT; t++) {
      for (int j = 0; j < t; j++, P++) {
        if (j == t - 1 && j >= 1) spinwait(&ws->s.Ptok[j], 1u);
        posA(ws, shf, decWhh, decbih, decbhh, &ws->px0[j][0][0], P, c0, ep, wg);
        posB(ws, shf, dWih1, dWhh1, decbih + kG, decbhh + kG, P, c1, ep, wg);
      }
      fc1phase(ws, shf, Wfc1, bfc1, (P + 1) & 1, ep, wg);
      lnphase(ws, shf, lng, lnb, t, ep, wg);
    }
  } else if (wg == LEAD) {
    // ---------------- leader ----------------
    for (int t = 1; t < kT; t++) {
      spinwait(&ws->s.ctrB[t], (unsigned)NGANG);
      if (tid < kB) {
        const int b = tid;
        const unsigned long long key =
            __hip_atomic_load(&ws->s.argkey[t][b], __ATOMIC_RELAXED, __HIP_MEMORY_SCOPE_AGENT);
        const int samp = (int)(0xFFFFFFFFu - (unsigned)(key & 0xFFFFFFFFull));
        const float mx = inv_ordkey(ldu(&ws->s.maxbits[t][b]));
        float s = 0.f;
        for (int g2 = 0; g2 < NGANG; g2++) s += aldf(&ws->s.psum[g2][b]);  // fixed order
        const float lse = mx + logf(s);
        const float* wr = W_fc2 + (size_t)samp * kZ;      // recompute logits[b][samp]
        float acc = b_fc2[samp];
        for (int k = 0; k < kZ; k++) acc = fmaf(aldf(&ws->z1n[t & 1][b][k]), wr[k], acc);
        out[b * kT + t] = acc - lse;                      // score (logp of sample)
        const int cur = input_ids[b * kT + t];
        const int nxt = (cur == kMask) ? samp : cur;
        out[kB * kT + b * kT + t] = (float)nxt;           // token (as f32 value)
        shi[b] = nxt;
      }
      __syncthreads();
      { // x_t = relu(emb[tok] @ W_e2d^T + b_e2d) -> LDS
        const float* wr = W_e2d + (size_t)tid * kE;
        const float* e0 = emb + (size_t)shi[0] * kE;
        const float* e1 = emb + (size_t)shi[1] * kE;
        const float* e2 = emb + (size_t)shi[2] * kE;
        const float* e3 = emb + (size_t)shi[3] * kE;
        const float bb = b_e2d[tid];
        float a0 = bb, a1 = bb, a2 = bb, a3 = bb;
        for (int k = 0; k < kE; k += 4) {
          const float4 wv = *reinterpret_cast<const float4*>(wr + k);
          const float4 v0 = *reinterpret_cast<const float4*>(e0 + k);
          const float4 v1 = *reinterpret_cast<const float4*>(e1 + k);
          const float4 v2 = *reinterpret_cast<const float4*>(e2 + k);
          const float4 v3 = *reinterpret_cast<const float4*>(e3 + k);
          a0 = fmaf(v0.x, wv.x, a0); a0 = fmaf(v0.y, wv.y, a0); a0 = fmaf(v0.z, wv.z, a0); a0 = fmaf(v0.w, wv.w, a0);
          a1 = fmaf(v1.x, wv.x, a1); a1 = fmaf(v1.y, wv.y, a1); a1 = fmaf(v1.z, wv.z, a1); a1 = fmaf(v1.w, wv.w, a1);
          a2 = fmaf(v2.x, wv.x, a2); a2 = fmaf(v2.y, wv.y, a2); a2 = fmaf(v2.z, wv.z, a2); a2 = fmaf(v2.w, wv.w, a2);
          a3 = fmaf(v3.x, wv.x, a3); a3 = fmaf(v3.y, wv.y, a3); a3 = fmaf(v3.z, wv.z, a3); a3 = fmaf(v3.w, wv.w, a3);
        }
        __syncthreads();
        shf[0 * kH + tid] = fmaxf(a0, 0.f);
        shf[1 * kH + tid] = fmaxf(a1, 0.f);
        shf[2 * kH + tid] = fmaxf(a2, 0.f);
        shf[3 * kH + tid] = fmaxf(a3, 0.f);
      }
      __syncthreads();
      // px0[t][b][g] = x_t[b] . decWih0[g]
#pragma unroll
      for (int i = 0; i < 16; i++) {
        const int d = i * 256 + tid;
        const int b = d >> 10, g = d & 1023;
        const float* wr = decWih + (size_t)g * kH;
        const float* xv = &shf[b * kH];
        float acc = 0.f;
        for (int k = 0; k < kH; k += 4) {
          const float4 wv = *reinterpret_cast<const float4*>(wr + k);
          const float4 hv = *reinterpret_cast<const float4*>(xv + k);
          acc = fmaf(hv.x, wv.x, acc); acc = fmaf(hv.y, wv.y, acc);
          acc = fmaf(hv.z, wv.z, acc); acc = fmaf(hv.w, wv.w, acc);
        }
        astf(&ws->px0[t][0][0] + (size_t)b * kG + g, acc);
      }
      __syncthreads();
      if (tid == 0) relfetchadd(&ws->s.Ptok[t]);
    }
  } else {
    // ---------------- gang ----------------
    const int gi = wg - GANG0;
    const int start = gi * RPW;
    const int cnt = (RPW < kV - start) ? RPW : (kV - start);
    for (int t = 1; t < kT; t++) {
      spinwait(&ws->s.Z[t], 1u);
      for (int i = tid; i < kB * kZ; i += 256) shf[i] = aldf(&ws->z1n[t & 1][0][0] + i);
      __syncthreads();
      if (tid == 0)
        __hip_atomic_fetch_add(&ws->s.zread[t], 1u, __ATOMIC_RELAXED, __HIP_MEMORY_SCOPE_AGENT);
      unsigned fk0, fk1;
      tf2x32(0u, 1234u, 0u, (unsigned)t, fk0, fk1);     // fold_in(key(1234), t)
      const bool act = tid < cnt;
      const int row = start + tid;
      float lv[kB] = {0.f, 0.f, 0.f, 0.f};
      if (act) {
        const float* wr = W_fc2 + (size_t)row * kZ;
        const float bb = b_fc2[row];
        float a0 = bb, a1 = bb, a2 = bb, a3 = bb;
        for (int k = 0; k < kZ; k += 4) {
          const float4 wv = *reinterpret_cast<const float4*>(wr + k);
          const float4 z0 = *reinterpret_cast<const float4*>(&shf[0 * kZ + k]);
          const float4 z1 = *reinterpret_cast<const float4*>(&shf[1 * kZ + k]);
          const float4 z2 = *reinterpret_cast<const float4*>(&shf[2 * kZ + k]);
          const float4 z3 = *reinterpret_cast<const float4*>(&shf[3 * kZ + k]);
          a0 = fmaf(z0.x, wv.x, a0); a0 = fmaf(z0.y, wv.y, a0); a0 = fmaf(z0.z, wv.z, a0); a0 = fmaf(z0.w, wv.w, a0);
          a1 = fmaf(z1.x, wv.x, a1); a1 = fmaf(z1.y, wv.y, a1); a1 = fmaf(z1.z, wv.z, a1); a1 = fmaf(z1.w, wv.w, a1);
          a2 = fmaf(z2.x, wv.x, a2); a2 = fmaf(z2.y, wv.y, a2); a2 = fmaf(z2.z, wv.z, a2); a2 = fmaf(z2.w, wv.w, a2);
          a3 = fmaf(z3.x, wv.x, a3); a3 = fmaf(z3.y, wv.y, a3); a3 = fmaf(z3.z, wv.z, a3); a3 = fmaf(z3.w, wv.w, a3);
        }
        lv[0] = a0; lv[1] = a1; lv[2] = a2; lv[3] = a3;
      }
      // pass 1: per-batch wave reduce of argmax(l+g) key and max(l)
#pragma unroll
      for (int b = 0; b < kB; b++) {
        unsigned long long key = 0ull;
        float v = act ? lv[b] : -INFINITY;
        if (act) {
          const unsigned bits = rbits(fk0, fk1, (unsigned)(b * kV + row));
          const float pv = lv[b] + gumbel_from_bits(bits);
          key = ((unsigned long long)ordkey(pv) << 32)
              | (unsigned long long)(0xFFFFFFFFu - (unsigned)row);   // first-idx tie-break
        }
#pragma unroll
        for (int m = 1; m < 64; m <<= 1) {
          const unsigned long long ko = shflx64(key, m);
          const float vo = __shfl_xor(v, m, 64);
          if (ko > key) key = ko;
          v = fmaxf(v, vo);
        }
        if ((tid & 63) == 0) { shk[(tid >> 6) * kB + b] = key; shf[1408 + (tid >> 6) * kB + b] = v; }
      }
      __syncthreads();
      if (tid == 0) {
#pragma unroll
        for (int b = 0; b < kB; b++) {
          unsigned long long key = shk[b];
          float v = shf[1408 + b];
          for (int w = 1; w < 4; w++) {
            const unsigned long long ko = shk[w * kB + b];
            if (ko > key) key = ko;
            v = fmaxf(v, shf[1408 + w * kB + b]);
          }
          __hip_atomic_fetch_max(&ws->s.argkey[t][b], key, __ATOMIC_RELAXED, __HIP_MEMORY_SCOPE_AGENT);
          __hip_atomic_fetch_max(&ws->s.maxbits[t][b], ordkey(v), __ATOMIC_RELAXED, __HIP_MEMORY_SCOPE_AGENT);
        }
        relfetchadd(&ws->s.ctrA[t]);
      }
      spinwait(&ws->s.ctrA[t], (unsigned)NGANG);
      if (tid == 0) {
#pragma unroll
        for (int b = 0; b < kB; b++) shf[1424 + b] = inv_ordkey(ldu(&ws->s.maxbits[t][b]));
      }
      __syncthreads();
      // pass 2: sum(exp(l - max)) — logits still in registers
#pragma unroll
      for (int b = 0; b < kB; b++) {
        float sv = act ? expf(lv[b] - shf[1424 + b]) : 0.f;
#pragma unroll
        for (int m = 1; m < 64; m <<= 1) sv += __shfl_xor(sv, m, 64);
        if ((tid & 63) == 0) shf[1440 + (tid >> 6) * kB + b] = sv;
      }
      __syncthreads();
      if (tid == 0) {
#pragma unroll
        for (int b = 0; b < kB; b++) {
          const float s = shf[1440 + b] + shf[1440 + kB + b]
                        + shf[1440 + 2 * kB + b] + shf[1440 + 3 * kB + b];
          astf(&ws->s.psum[gi][b], s);
        }
        relfetchadd(&ws->s.ctrB[t]);
      }
      // next-iteration spinwait's __syncthreads orders shf reuse
    }
  }
}

} // namespace s2sr

extern "C" void kernel_launch(void* const* d_in, const int* in_sizes, int n_in,
                              void* d_out, int out_size, void* d_ws, size_t ws_size,
                              hipStream_t stream) {
  using namespace s2sr;
  (void)in_sizes; (void)n_in; (void)out_size;
  if (ws_size < sizeof(WS)) return;  // fail loudly via validation rather than corrupt
  const int*   input_ids = (const int*)d_in[0];
  // d_in[1] = attention_mask (unused by the reference forward)
  const float* labels    = (const float*)d_in[2];
  const float* emb       = (const float*)d_in[3];
  const float* W_e2e     = (const float*)d_in[4];
  const float* b_e2e     = (const float*)d_in[5];
  const float* W_e2d     = (const float*)d_in[6];
  const float* b_e2d     = (const float*)d_in[7];
  const float* encWih    = (const float*)d_in[8];
  const float* encWhh    = (const float*)d_in[9];
  const float* encbih    = (const float*)d_in[10];
  const float* encbhh    = (const float*)d_in[11];
  const float* decWih    = (const float*)d_in[12];
  const float* decWhh    = (const float*)d_in[13];
  const float* decbih    = (const float*)d_in[14];
  const float* decbhh    = (const float*)d_in[15];
  const float* W_cls     = (const float*)d_in[16];
  const float* b_cls     = (const float*)d_in[17];
  const float* W_fc1     = (const float*)d_in[18];
  const float* b_fc1     = (const float*)d_in[19];
  const float* ln_g      = (const float*)d_in[20];
  const float* ln_b      = (const float*)d_in[21];
  const float* W_fc2     = (const float*)d_in[22];
  const float* b_fc2     = (const float*)d_in[23];

  hipMemsetAsync(d_ws, 0, sizeof(WS), stream);   // re-arm flags + zero initial h-state
  hipLaunchKernelGGL(s2s_kernel, dim3(NWG), dim3(256), 0, stream,
      input_ids, labels, emb, W_e2e, b_e2e, W_e2d, b_e2d,
      encWih, encWhh, encbih, encbhh, decWih, decWhh, decbih, decbhh,
      W_cls, b_cls, W_fc1, b_fc1, ln_g, ln_b, W_fc2, b_fc2,
      (float*)d_out, (WS*)d_ws);
}

// Round 2
// 12087.839 us; speedup vs baseline: 2.4235x; 2.4235x over previous
//
#include <hip/hip_runtime.h>
#include <stdint.h>
#include <stddef.h>
#include <math.h>

// ============================================================================
// Seq2SeqReinforce — persistent kernel, round 2.
// Cluster: 32 WGs, decoder LSTM weights register-resident (96 floats/thread),
//          ONE LLC barrier per LSTM position (merged layer0(c)+layer1(c-1)).
// Leader (WG32): sample + embed + score. Gang (WG33..255): fc2+gumbel+argmax;
//          first 16 gang WGs also compute px0[t] (distributed 1MB matvec).
// ============================================================================

#define PARTITIONABLE_PRNG 1   // confirmed bit-exact in round 1

namespace s2sr {

constexpr int kV = 50257, kE = 256, kH = 256, kCc = 64, kB = 4, kT = 48;
constexpr int kZ = kH + kCc;   // 320
constexpr int kG = 4 * kH;     // 1024
constexpr int kMask = 103;
constexpr float kEps = 1e-5f;
constexpr float kTiny = 1.17549435e-38f;

constexpr int NWG = 256;
constexpr int NCL = 32;                        // cluster WGs
constexpr int LEAD = 32;
constexpr int GANG0 = 33;
constexpr int NGANG = NWG - GANG0;             // 223
constexpr int RPW = (kV + NGANG - 1) / NGANG;  // 226 rows/WG
constexpr int NPX = 16;                        // gang WGs doing px0 duty

// LDS float offsets (cluster tick layout)
constexpr int SH_H0 = 0;      // 1024: staged h0prev  [b][256]
constexpr int SH_H1 = 1024;   // 1024: staged h1prev2 [b][256]
constexpr int SH_P0 = 2048;   // 1024: l0 partials [w][32][4]
constexpr int SH_P1 = 3072;   // 1024: l1 partials
constexpr int SH_Z  = 4096;   // 256:  z rows [L][32][4]
constexpr int SH_TOT = 4608;

struct SyncBlk {
  unsigned ictr;                 // init barrier
  unsigned cctr;                 // cluster tick barrier (monotonic)
  unsigned Z[kT];                // z1n(t) ready
  unsigned zread[kT];            // gang staged z1n(t) (==NGANG)
  unsigned ctrA[kT];             // gang pass-1 done
  unsigned ctrB[kT];             // gang pass-2 done
  unsigned Etok[kT];             // leader published xcur(t)
  unsigned PtokCnt[kT];          // px0[t] slices done (==NPX)
  unsigned long long argkey[kT][kB];
  unsigned maxbits[kT][kB];
  float psumacc[kT][kB];         // float atomic accumulation of sum(exp)
};

struct WS {
  // ---- zeroed head (memset each launch) ----
  SyncBlk s;
  float h0buf[2][kB][kH];
  float h1buf[2][kB][kH];
  float cls[kB][kCc];
  float xd0[kB][kH];
  float z1pre[kB][kZ];
  float z1n[2][kB][kZ];
  float xcur[kB][kH];
  // ---- not zeroed (always written before read, gated by flags) ----
  float px0[kT][kB][kG];
  float pxe[kT][kB][kG];
};

// ---------------- atomic helpers ----------------
__device__ __forceinline__ float aldf(const float* p) {
  return __hip_atomic_load(p, __ATOMIC_RELAXED, __HIP_MEMORY_SCOPE_AGENT);
}
__device__ __forceinline__ void astf(float* p, float v) {
  __hip_atomic_store(p, v, __ATOMIC_RELAXED, __HIP_MEMORY_SCOPE_AGENT);
}
__device__ __forceinline__ unsigned ldu(const unsigned* p) {
  return __hip_atomic_load(p, __ATOMIC_RELAXED, __HIP_MEMORY_SCOPE_AGENT);
}
__device__ __forceinline__ void relfetchadd(unsigned* p) {
  __hip_atomic_fetch_add(p, 1u, __ATOMIC_RELEASE, __HIP_MEMORY_SCOPE_AGENT);
}
// all-lane spin (cluster): every thread polls; wave loads coalesce to 1 req.
__device__ __forceinline__ void spin_all(unsigned* p, unsigned tgt) {
  while (__hip_atomic_load(p, __ATOMIC_RELAXED, __HIP_MEMORY_SCOPE_AGENT) < tgt)
    __builtin_amdgcn_s_sleep(1);
  __atomic_signal_fence(__ATOMIC_ACQUIRE);
}
// tid0 spin + syncthreads (gang/leader; fewer LLC pollers)
template <int SLP>
__device__ __forceinline__ void spinwait(unsigned* p, unsigned tgt) {
  if (threadIdx.x == 0) {
    while (__hip_atomic_load(p, __ATOMIC_RELAXED, __HIP_MEMORY_SCOPE_AGENT) < tgt)
      __builtin_amdgcn_s_sleep(SLP);
    __atomic_signal_fence(__ATOMIC_ACQUIRE);
  }
  __syncthreads();
}
__device__ __forceinline__ void cbar(SyncBlk* s, unsigned& ep) {
  __syncthreads();                       // drains each thread's stores (vmcnt0)
  if (threadIdx.x == 0) relfetchadd(&s->cctr);
  ep += (unsigned)NCL;
  spin_all(&s->cctr, ep);
}
__device__ __forceinline__ void gbar(SyncBlk* s, unsigned tgt) {
  __syncthreads();
  if (threadIdx.x == 0) relfetchadd(&s->ictr);
  spinwait<2>(&s->ictr, tgt);
}

// ---------------- Threefry2x32 (bit-exact vs JAX; validated round 1) --------
__device__ __forceinline__ unsigned rotl32(unsigned v, int n) {
  return (v << n) | (v >> (32 - n));
}
__device__ __forceinline__ void tf2x32(unsigned k0, unsigned k1, unsigned x0, unsigned x1,
                                       unsigned& o0, unsigned& o1) {
  const unsigned k2 = k0 ^ k1 ^ 0x1BD11BDAu;
  unsigned v0 = x0 + k0, v1 = x1 + k1;
  v0 += v1; v1 = rotl32(v1, 13); v1 ^= v0;
  v0 += v1; v1 = rotl32(v1, 15); v1 ^= v0;
  v0 += v1; v1 = rotl32(v1, 26); v1 ^= v0;
  v0 += v1; v1 = rotl32(v1, 6);  v1 ^= v0;
  v0 += k1; v1 += k2 + 1u;
  v0 += v1; v1 = rotl32(v1, 17); v1 ^= v0;
  v0 += v1; v1 = rotl32(v1, 29); v1 ^= v0;
  v0 += v1; v1 = rotl32(v1, 16); v1 ^= v0;
  v0 += v1; v1 = rotl32(v1, 24); v1 ^= v0;
  v0 += k2; v1 += k0 + 2u;
  v0 += v1; v1 = rotl32(v1, 13); v1 ^= v0;
  v0 += v1; v1 = rotl32(v1, 15); v1 ^= v0;
  v0 += v1; v1 = rotl32(v1, 26); v1 ^= v0;
  v0 += v1; v1 = rotl32(v1, 6);  v1 ^= v0;
  v0 += k0; v1 += k1 + 3u;
  v0 += v1; v1 = rotl32(v1, 17); v1 ^= v0;
  v0 += v1; v1 = rotl32(v1, 29); v1 ^= v0;
  v0 += v1; v1 = rotl32(v1, 16); v1 ^= v0;
  v0 += v1; v1 = rotl32(v1, 24); v1 ^= v0;
  v0 += k1; v1 += k2 + 4u;
  v0 += v1; v1 = rotl32(v1, 13); v1 ^= v0;
  v0 += v1; v1 = rotl32(v1, 15); v1 ^= v0;
  v0 += v1; v1 = rotl32(v1, 26); v1 ^= v0;
  v0 += v1; v1 = rotl32(v1, 6);  v1 ^= v0;
  o0 = v0 + k2; o1 = v1 + k0 + 5u;
}
__device__ __forceinline__ unsigned rbits(unsigned k0, unsigned k1, unsigned i) {
#if PARTITIONABLE_PRNG
  unsigned a, b; tf2x32(k0, k1, 0u, i, a, b);
  return a ^ b;
#else
  constexpr unsigned HALF = (unsigned)((kB * kV + 1) / 2);
  unsigned a, b;
  if (i < HALF) { tf2x32(k0, k1, i, i + HALF, a, b); return a; }
  tf2x32(k0, k1, i - HALF, i, a, b); return b;
#endif
}
__device__ __forceinline__ float gumbel_from_bits(unsigned bits) {
  float f = __uint_as_float((bits >> 9) | 0x3f800000u) - 1.0f;
  f = fmaxf(f, kTiny);
  return -logf(-logf(f));
}
__device__ __forceinline__ unsigned ordkey(float f) {
  const unsigned u = __float_as_uint(f);
  return (u & 0x80000000u) ? ~u : (u | 0x80000000u);
}
__device__ __forceinline__ float inv_ordkey(unsigned x) {
  const unsigned u = (x & 0x80000000u) ? (x & 0x7FFFFFFFu) : ~x;
  return __uint_as_float(u);
}
__device__ __forceinline__ unsigned long long shflx64(unsigned long long v, int m) {
  unsigned lo = (unsigned)v, hi = (unsigned)(v >> 32);
  lo = (unsigned)__shfl_xor((int)lo, m, 64);
  hi = (unsigned)__shfl_xor((int)hi, m, 64);
  return ((unsigned long long)hi << 32) | (unsigned long long)lo;
}
__device__ __forceinline__ float sigm(float x) { return 1.0f / (1.0f + expf(-x)); }

// ---------------- merged LSTM tick ------------------------------------------
// Tick for cell cc: layer0(cc) [reads h0buf[(cc-1)&1], writes h0buf[cc&1]]
//               +   layer1(cc-1) [x = h0buf[(cc-1)&1], h = h1buf[(cc-2)&1],
//                                 writes h1buf[(cc-1)&1]]
// Thread map: r = tid&31 -> gate-row grow = (r&3)*256 + cw*8 + (r>>2);
//             w = tid>>5 -> k-window (l0: 32 floats, l1: 64 of the 512-concat)
template <bool STREAM>
__device__ __forceinline__ void lstm_tick(
    SyncBlk* sb, WS* ws, float* shf, int cw, unsigned& ep, int cc,
    bool do_l0, bool do_l1, const float* px,
    const float* pW0, const float* pW1,
    const float4* w0r, const float4* w1r,
    float biasr, float& c0, float& c1, int grow, int r, int w) {
  const int tid = (int)threadIdx.x;
  // px prefetch for l0 reducers (threads 0..31)
  float pxv0 = 0.f, pxv1 = 0.f, pxv2 = 0.f, pxv3 = 0.f;
  if (do_l0 && tid < 32) {
    pxv0 = aldf(px + 0 * kG + grow);
    pxv1 = aldf(px + 1 * kG + grow);
    pxv2 = aldf(px + 2 * kG + grow);
    pxv3 = aldf(px + 3 * kG + grow);
  }
  // stage h0prev (always: l0 operand AND l1 x-input); h1prev2 if l1 active
  {
    const float* h0p = &ws->h0buf[(cc + 1) & 1][0][0];
#pragma unroll
    for (int i = 0; i < 4; ++i) shf[SH_H0 + tid + i * 256] = aldf(h0p + tid + i * 256);
    if (do_l1) {
      const float* h1p = &ws->h1buf[cc & 1][0][0];   // (cc-2)&1
#pragma unroll
      for (int i = 0; i < 4; ++i) shf[SH_H1 + tid + i * 256] = aldf(h1p + tid + i * 256);
    }
  }
  __syncthreads();
  // weights: registers (decoder) or streamed (encoder)
  float4 wv0[8], wv1[16];
  if (do_l0) {
#pragma unroll
    for (int i = 0; i < 8; ++i)
      wv0[i] = STREAM ? *reinterpret_cast<const float4*>(pW0 + i * 4) : w0r[i];
  }
  if (do_l1) {
#pragma unroll
    for (int i = 0; i < 16; ++i)
      wv1[i] = STREAM ? *reinterpret_cast<const float4*>(pW1 + i * 4) : w1r[i];
  }
  // layer0 partial dots (32-float window, 4 batches)
  if (do_l0) {
    const float* A = &shf[SH_H0 + w * 32];
    float a0 = 0.f, a1 = 0.f, a2 = 0.f, a3 = 0.f;
#pragma unroll
    for (int i = 0; i < 8; ++i) {
      const float4 wv = wv0[i];
      const float4 x0 = *reinterpret_cast<const float4*>(A + 0 * 256 + i * 4);
      const float4 x1 = *reinterpret_cast<const float4*>(A + 1 * 256 + i * 4);
      const float4 x2 = *reinterpret_cast<const float4*>(A + 2 * 256 + i * 4);
      const float4 x3 = *reinterpret_cast<const float4*>(A + 3 * 256 + i * 4);
      a0 = fmaf(wv.x, x0.x, a0); a0 = fmaf(wv.y, x0.y, a0); a0 = fmaf(wv.z, x0.z, a0); a0 = fmaf(wv.w, x0.w, a0);
      a1 = fmaf(wv.x, x1.x, a1); a1 = fmaf(wv.y, x1.y, a1); a1 = fmaf(wv.z, x1.z, a1); a1 = fmaf(wv.w, x1.w, a1);
      a2 = fmaf(wv.x, x2.x, a2); a2 = fmaf(wv.y, x2.y, a2); a2 = fmaf(wv.z, x2.z, a2); a2 = fmaf(wv.w, x2.w, a2);
      a3 = fmaf(wv.x, x3.x, a3); a3 = fmaf(wv.y, x3.y, a3); a3 = fmaf(wv.z, x3.z, a3); a3 = fmaf(wv.w, x3.w, a3);
    }
    *reinterpret_cast<float4*>(&shf[SH_P0 + w * 128 + r * 4]) = float4{a0, a1, a2, a3};
  }
  // layer1 partial dots (64-float window of the [h0|h1] 512-concat)
  if (do_l1) {
    const float* Bp = (w < 4) ? &shf[SH_H0 + w * 64] : &shf[SH_H1 + (w - 4) * 64];
    float a0 = 0.f, a1 = 0.f, a2 = 0.f, a3 = 0.f;
#pragma unroll
    for (int i = 0; i < 16; ++i) {
      const float4 wv = wv1[i];
      const float4 x0 = *reinterpret_cast<const float4*>(Bp + 0 * 256 + i * 4);
      const float4 x1 = *reinterpret_cast<const float4*>(Bp + 1 * 256 + i * 4);
      const float4 x2 = *reinterpret_cast<const float4*>(Bp + 2 * 256 + i * 4);
      const float4 x3 = *reinterpret_cast<const float4*>(Bp + 3 * 256 + i * 4);
      a0 = fmaf(wv.x, x0.x, a0); a0 = fmaf(wv.y, x0.y, a0); a0 = fmaf(wv.z, x0.z, a0); a0 = fmaf(wv.w, x0.w, a0);
      a1 = fmaf(wv.x, x1.x, a1); a1 = fmaf(wv.y, x1.y, a1); a1 = fmaf(wv.z, x1.z, a1); a1 = fmaf(wv.w, x1.w, a1);
      a2 = fmaf(wv.x, x2.x, a2); a2 = fmaf(wv.y, x2.y, a2); a2 = fmaf(wv.z, x2.z, a2); a2 = fmaf(wv.w, x2.w, a2);
      a3 = fmaf(wv.x, x3.x, a3); a3 = fmaf(wv.y, x3.y, a3); a3 = fmaf(wv.z, x3.z, a3); a3 = fmaf(wv.w, x3.w, a3);
    }
    *reinterpret_cast<float4*>(&shf[SH_P1 + w * 128 + r * 4]) = float4{a0, a1, a2, a3};
  }
  __syncthreads();
  // reduce over the 8 windows, add bias (+ px for l0); z rows -> SH_Z
  if (tid < 64) {
    const int L = tid >> 5, rr = tid & 31;
    const bool en = L ? do_l1 : do_l0;
    if (en) {
      const int base = (L ? SH_P1 : SH_P0) + rr * 4;
      float4 z = float4{0.f, 0.f, 0.f, 0.f};
#pragma unroll
      for (int w2 = 0; w2 < 8; ++w2) {
        const float4 p = *reinterpret_cast<const float4*>(&shf[base + w2 * 128]);
        z.x += p.x; z.y += p.y; z.z += p.z; z.w += p.w;
      }
      z.x += biasr; z.y += biasr; z.z += biasr; z.w += biasr;
      if (L == 0) { z.x += pxv0; z.y += pxv1; z.z += pxv2; z.w += pxv3; }
      *reinterpret_cast<float4*>(&shf[SH_Z + L * 128 + rr * 4]) = z;
    }
  }
  __syncthreads();
  // finish: gates -> c,h ; publish h slice to LLC
  if (tid < 64) {
    const int L = tid >> 5, slot = tid & 31;
    const bool en = L ? do_l1 : do_l0;
    if (en) {
      const int b = slot >> 3, u = slot & 7;
      const int zb = SH_Z + L * 128 + u * 16 + b;
      const float zi = shf[zb], zf = shf[zb + 4], zg = shf[zb + 8], zo = shf[zb + 12];
      const float cs = L ? c1 : c0;
      const float cn = sigm(zf) * cs + sigm(zi) * tanhf(zg);
      const float hn = sigm(zo) * tanhf(cn);
      if (L) { c1 = cn; astf(&ws->h1buf[(cc + 1) & 1][b][cw * 8 + u], hn); }
      else   { c0 = cn; astf(&ws->h0buf[cc & 1][b][cw * 8 + u], hn); }
    }
  }
  cbar(sb, ep);
}

// fc1 tick: 320 rows distributed 10/WG; z = [h1last ; cls]
__device__ __forceinline__ void fc1_tick(SyncBlk* sb, WS* ws, float* shf, int cw,
                                         unsigned& ep, int p1,
                                         const float* Wfc1, const float* bfc1) {
  const int tid = (int)threadIdx.x;
  for (int i = tid; i < kB * kZ; i += 256) {
    const int b = i / kZ, k = i - b * kZ;
    shf[i] = (k < kH) ? aldf(&ws->h1buf[p1][b][k]) : aldf(&ws->cls[b][k - kH]);
  }
  __syncthreads();
  if (tid < 160) {
    const int task = tid >> 2, q = tid & 3;
    const int rowl = task >> 2, b = task & 3;
    const int rowg = cw * 10 + rowl;
    const float* wr = Wfc1 + (size_t)rowg * kZ + q * 80;
    const float* zz = &shf[b * kZ + q * 80];
    float acc = 0.f;
#pragma unroll
    for (int k = 0; k < 80; k += 4) {
      const float4 wv = *reinterpret_cast<const float4*>(wr + k);
      const float4 zv = *reinterpret_cast<const float4*>(zz + k);
      acc = fmaf(zv.x, wv.x, acc); acc = fmaf(zv.y, wv.y, acc);
      acc = fmaf(zv.z, wv.z, acc); acc = fmaf(zv.w, wv.w, acc);
    }
    shf[SH_P0 + task * 4 + q] = acc;
  }
  __syncthreads();
  if (tid < 40) {
    const int rowl = tid >> 2, b = tid & 3;
    const int rowg = cw * 10 + rowl;
    const float z1 = shf[SH_P0 + tid * 4 + 0] + shf[SH_P0 + tid * 4 + 1] +
                     shf[SH_P0 + tid * 4 + 2] + shf[SH_P0 + tid * 4 + 3] + bfc1[rowg];
    astf(&ws->z1pre[b][rowg], z1);
  }
  cbar(sb, ep);
}

// LN (WG0 only, folded after fc1's barrier) -> z1n[t&1] -> release Z[t]
__device__ __forceinline__ void ln_work(SyncBlk* sb, WS* ws, float* shf,
                                        const float* lng, const float* lnb, int t) {
  const int tid = (int)threadIdx.x;
  if (t >= 3) spin_all(&sb->zread[t - 2], (unsigned)NGANG);
  for (int i = tid; i < kB * kZ; i += 256)
    shf[i] = fmaxf(aldf(&ws->z1pre[0][0] + i), 0.f);
  __syncthreads();
  const int b = tid >> 6, ln = tid & 63;
  float s1 = 0.f, s2 = 0.f;
  for (int i = ln; i < kZ; i += 64) { const float v = shf[b * kZ + i]; s1 += v; s2 += v * v; }
#pragma unroll
  for (int off = 32; off > 0; off >>= 1) { s1 += __shfl_xor(s1, off, 64); s2 += __shfl_xor(s2, off, 64); }
  const float mu = s1 * (1.0f / kZ);
  const float var = s2 * (1.0f / kZ) - mu * mu;
  const float rs = 1.0f / sqrtf(var + kEps);
  for (int i = ln; i < kZ; i += 64) {
    const float v = shf[b * kZ + i];
    astf(&ws->z1n[t & 1][b][i], fmaf((v - mu) * rs, lng[i], lnb[i]));
  }
  __syncthreads();
  if (tid == 0) relfetchadd(&sb->Z[t]);
}

// ---------------- kernel ----------------
__global__ void __launch_bounds__(256, 1) s2s_kernel(
    const int* __restrict__ input_ids, const float* __restrict__ labels,
    const float* __restrict__ emb,
    const float* __restrict__ W_e2e, const float* __restrict__ b_e2e,
    const float* __restrict__ W_e2d, const float* __restrict__ b_e2d,
    const float* __restrict__ encWih, const float* __restrict__ encWhh,
    const float* __restrict__ encbih, const float* __restrict__ encbhh,
    const float* __restrict__ decWih, const float* __restrict__ decWhh,
    const float* __restrict__ decbih, const float* __restrict__ decbhh,
    const float* __restrict__ W_cls, const float* __restrict__ b_cls,
    const float* __restrict__ Wfc1, const float* __restrict__ bfc1,
    const float* __restrict__ lng, const float* __restrict__ lnb,
    const float* __restrict__ W_fc2, const float* __restrict__ b_fc2,
    float* __restrict__ out, WS* __restrict__ ws) {
  const int wg = (int)blockIdx.x;
  const int tid = (int)threadIdx.x;
  SyncBlk* sb = &ws->s;
  __shared__ __align__(16) float shf[SH_TOT];
  __shared__ unsigned long long shk[16];
  __shared__ int shi[8];

  // ================= init phase 1 =================
  if (wg < kB * kT) {
    const int b = wg / kT, j = wg % kT;
    const int id = input_ids[b * kT + j];
    for (int i = tid; i < kE; i += 256) shf[i] = emb[(size_t)id * kE + i];
    __syncthreads();
    const float* wr = W_e2e + (size_t)tid * kE;
    float acc = b_e2e[tid];
    for (int k = 0; k < kE; k += 4) {
      const float4 wv = *reinterpret_cast<const float4*>(wr + k);
      const float4 xv = *reinterpret_cast<const float4*>(&shf[k]);
      acc = fmaf(xv.x, wv.x, acc); acc = fmaf(xv.y, wv.y, acc);
      acc = fmaf(xv.z, wv.z, acc); acc = fmaf(xv.w, wv.w, acc);
    }
    __syncthreads();
    shf[256 + tid] = fmaxf(acc, 0.f);
  } else if (wg == 192) {
    if (tid < kB * kCc) {
      const int b = tid >> 6, c = tid & 63;
      astf(&ws->cls[b][c], fmaf(labels[b], W_cls[c], b_cls[c]));
    }
    if (tid < kB) {
      const int t0 = input_ids[tid * kT];
      out[tid * kT] = 0.f;
      out[kB * kT + tid * kT] = (float)t0;
    }
  } else if (wg == 193) {
    const float* wr = W_e2d + (size_t)tid * kE;
    const float* e0 = emb + (size_t)input_ids[0 * kT] * kE;
    const float* e1 = emb + (size_t)input_ids[1 * kT] * kE;
    const float* e2 = emb + (size_t)input_ids[2 * kT] * kE;
    const float* e3 = emb + (size_t)input_ids[3 * kT] * kE;
    const float bb = b_e2d[tid];
    float a0 = bb, a1 = bb, a2 = bb, a3 = bb;
    for (int k = 0; k < kE; k += 4) {
      const float4 wv = *reinterpret_cast<const float4*>(wr + k);
      const float4 v0 = *reinterpret_cast<const float4*>(e0 + k);
      const float4 v1 = *reinterpret_cast<const float4*>(e1 + k);
      const float4 v2 = *reinterpret_cast<const float4*>(e2 + k);
      const float4 v3 = *reinterpret_cast<const float4*>(e3 + k);
      a0 = fmaf(v0.x, wv.x, a0); a0 = fmaf(v0.y, wv.y, a0); a0 = fmaf(v0.z, wv.z, a0); a0 = fmaf(v0.w, wv.w, a0);
      a1 = fmaf(v1.x, wv.x, a1); a1 = fmaf(v1.y, wv.y, a1); a1 = fmaf(v1.z, wv.z, a1); a1 = fmaf(v1.w, wv.w, a1);
      a2 = fmaf(v2.x, wv.x, a2); a2 = fmaf(v2.y, wv.y, a2); a2 = fmaf(v2.z, wv.z, a2); a2 = fmaf(v2.w, wv.w, a2);
      a3 = fmaf(v3.x, wv.x, a3); a3 = fmaf(v3.y, wv.y, a3); a3 = fmaf(v3.z, wv.z, a3); a3 = fmaf(v3.w, wv.w, a3);
    }
    astf(&ws->xd0[0][tid], fmaxf(a0, 0.f));
    astf(&ws->xd0[1][tid], fmaxf(a1, 0.f));
    astf(&ws->xd0[2][tid], fmaxf(a2, 0.f));
    astf(&ws->xd0[3][tid], fmaxf(a3, 0.f));
  }
  gbar(sb, (unsigned)NWG);

  // ================= init phase 2 =================
  if (wg < kB * kT) {
    const int b = wg / kT, j = wg % kT;
#pragma unroll
    for (int rr = 0; rr < 4; ++rr) {
      const int g = rr * 256 + tid;
      const float* wr = encWih + (size_t)g * kH;
      float acc = 0.f;
      for (int k = 0; k < kH; k += 4) {
        const float4 wv = *reinterpret_cast<const float4*>(wr + k);
        const float4 xv = *reinterpret_cast<const float4*>(&shf[256 + k]);
        acc = fmaf(xv.x, wv.x, acc); acc = fmaf(xv.y, wv.y, acc);
        acc = fmaf(xv.z, wv.z, acc); acc = fmaf(xv.w, wv.w, acc);
      }
      astf(&ws->pxe[j][0][0] + (size_t)b * kG + g, acc);
    }
  } else if (wg >= 192 && wg < 208) {
    const int w2 = wg - 192, b = w2 >> 2, q = w2 & 3;
    const int g = q * 256 + tid;
    for (int i = tid; i < kH; i += 256) shf[i] = aldf(&ws->xd0[b][i]);
    __syncthreads();
    const float* wr = decWih + (size_t)g * kH;
    float acc = 0.f;
    for (int k = 0; k < kH; k += 4) {
      const float4 wv = *reinterpret_cast<const float4*>(wr + k);
      const float4 xv = *reinterpret_cast<const float4*>(&shf[k]);
      acc = fmaf(xv.x, wv.x, acc); acc = fmaf(xv.y, wv.y, acc);
      acc = fmaf(xv.z, wv.z, acc); acc = fmaf(xv.w, wv.w, acc);
    }
    astf(&ws->px0[0][0][0] + (size_t)b * kG + g, acc);
  }
  gbar(sb, (unsigned)(2 * NWG));

  // ================= roles =================
  if (wg < NCL) {
    // ---------------- cluster ----------------
    const int cw = wg;
    const int r = tid & 31, w = tid >> 5;
    const int grow = (r & 3) * 256 + cw * 8 + (r >> 2);
    const int L = tid >> 5;
    unsigned ep = 0;
    float c0 = 0.f, c1 = 0.f;
    float biasr = 0.f;
    if (tid < 64)
      biasr = (L == 0) ? encbih[grow] + encbhh[grow]
                       : encbih[kG + grow] + encbhh[kG + grow];
    const float* pW0e = encWhh + (size_t)grow * kH + w * 32;
    const float* pW1e = (w < 4)
        ? encWih + (size_t)kG * kH + (size_t)grow * kH + w * 64
        : encWhh + (size_t)kG * kH + (size_t)grow * kH + (w - 4) * 64;
    int cc = 0;
    // encoder (weights streamed; gang idle -> L2 warm)
    for (int j = 0; j < kT; ++j, ++cc)
      lstm_tick<true>(sb, ws, shf, cw, ep, cc, true, j > 0, &ws->pxe[j][0][0],
                      pW0e, pW1e, nullptr, nullptr, biasr, c0, c1, grow, r, w);
    lstm_tick<true>(sb, ws, shf, cw, ep, cc, false, true, nullptr,
                    pW0e, pW1e, nullptr, nullptr, biasr, c0, c1, grow, r, w);
    // decoder weights -> registers (96 floats/thread)
    float4 w0d[8], w1d[16];
    {
      const float* p0 = decWhh + (size_t)grow * kH + w * 32;
#pragma unroll
      for (int i = 0; i < 8; ++i) w0d[i] = *reinterpret_cast<const float4*>(p0 + i * 4);
      const float* p1 = (w < 4)
          ? decWih + (size_t)kG * kH + (size_t)grow * kH + w * 64
          : decWhh + (size_t)kG * kH + (size_t)grow * kH + (w - 4) * 64;
#pragma unroll
      for (int i = 0; i < 16; ++i) w1d[i] = *reinterpret_cast<const float4*>(p1 + i * 4);
      if (tid < 64)
        biasr = (L == 0) ? decbih[grow] + decbhh[grow]
                         : decbih[kG + grow] + decbhh[kG + grow];
    }
    // decoder scans
    for (int t = 1; t < kT; ++t) {
      for (int j = 0; j < t; ++j, ++cc) {
        if (j == t - 1 && t >= 2) spin_all(&sb->PtokCnt[t - 1], (unsigned)NPX);
        lstm_tick<false>(sb, ws, shf, cw, ep, cc, true, j > 0, &ws->px0[j][0][0],
                         nullptr, nullptr, w0d, w1d, biasr, c0, c1, grow, r, w);
      }
      lstm_tick<false>(sb, ws, shf, cw, ep, cc, false, true, nullptr,
                       nullptr, nullptr, w0d, w1d, biasr, c0, c1, grow, r, w);
      fc1_tick(sb, ws, shf, cw, ep, (cc - 1) & 1, Wfc1, bfc1);
      if (cw == 0) ln_work(sb, ws, shf, lng, lnb, t);  // folded; WG0 rejoins late
    }
  } else if (wg == LEAD) {
    // ---------------- leader ----------------
    for (int t = 1; t < kT; ++t) {
      spinwait<2>(&sb->ctrB[t], (unsigned)NGANG);
      if (tid < kB) {
        const int b = tid;
        const unsigned long long key =
            __hip_atomic_load(&sb->argkey[t][b], __ATOMIC_RELAXED, __HIP_MEMORY_SCOPE_AGENT);
        const int samp = (int)(0xFFFFFFFFu - (unsigned)(key & 0xFFFFFFFFull));
        const float mx = inv_ordkey(ldu(&sb->maxbits[t][b]));
        const float s = aldf(&sb->psumacc[t][b]);
        const float lse = mx + logf(s);
        const int cur = input_ids[b * kT + t];
        const int nxt = (cur == kMask) ? samp : cur;
        out[kB * kT + b * kT + t] = (float)nxt;
        shi[b] = nxt; shi[4 + b] = samp;
        shf[1300 + b] = lse;
      }
      __syncthreads();
      if (t < kT - 1) {
        // x_t = relu(emb[tok] @ W_e2d^T + b) -> xcur (LLC); release Etok
        const float* wr = W_e2d + (size_t)tid * kE;
        const float* e0 = emb + (size_t)shi[0] * kE;
        const float* e1 = emb + (size_t)shi[1] * kE;
        const float* e2 = emb + (size_t)shi[2] * kE;
        const float* e3 = emb + (size_t)shi[3] * kE;
        const float bb = b_e2d[tid];
        float a0 = bb, a1 = bb, a2 = bb, a3 = bb;
        for (int k = 0; k < kE; k += 4) {
          const float4 wv = *reinterpret_cast<const float4*>(wr + k);
          const float4 v0 = *reinterpret_cast<const float4*>(e0 + k);
          const float4 v1 = *reinterpret_cast<const float4*>(e1 + k);
          const float4 v2 = *reinterpret_cast<const float4*>(e2 + k);
          const float4 v3 = *reinterpret_cast<const float4*>(e3 + k);
          a0 = fmaf(v0.x, wv.x, a0); a0 = fmaf(v0.y, wv.y, a0); a0 = fmaf(v0.z, wv.z, a0); a0 = fmaf(v0.w, wv.w, a0);
          a1 = fmaf(v1.x, wv.x, a1); a1 = fmaf(v1.y, wv.y, a1); a1 = fmaf(v1.z, wv.z, a1); a1 = fmaf(v1.w, wv.w, a1);
          a2 = fmaf(v2.x, wv.x, a2); a2 = fmaf(v2.y, wv.y, a2); a2 = fmaf(v2.z, wv.z, a2); a2 = fmaf(v2.w, wv.w, a2);
          a3 = fmaf(v3.x, wv.x, a3); a3 = fmaf(v3.y, wv.y, a3); a3 = fmaf(v3.z, wv.z, a3); a3 = fmaf(v3.w, wv.w, a3);
        }
        astf(&ws->xcur[0][tid], fmaxf(a0, 0.f));
        astf(&ws->xcur[1][tid], fmaxf(a1, 0.f));
        astf(&ws->xcur[2][tid], fmaxf(a2, 0.f));
        astf(&ws->xcur[3][tid], fmaxf(a3, 0.f));
        __syncthreads();
        if (tid == 0) relfetchadd(&sb->Etok[t]);
      }
      // score: logp[b][samp] = logits - lse (parallel: wave b, 64 lanes)
      for (int i = tid; i < kB * kZ; i += 256) shf[i] = aldf(&ws->z1n[t & 1][0][0] + i);
      __syncthreads();
      {
        const int b = tid >> 6, lane = tid & 63;
        const int sb_ = shi[4 + b];
        const float* wr = W_fc2 + (size_t)sb_ * kZ;
        float acc = 0.f;
#pragma unroll
        for (int i = 0; i < 5; ++i)
          acc = fmaf(shf[b * kZ + lane + i * 64], wr[lane + i * 64], acc);
#pragma unroll
        for (int off = 32; off > 0; off >>= 1) acc += __shfl_xor(acc, off, 64);
        if (lane == 0) out[b * kT + t] = acc + b_fc2[sb_] - shf[1300 + b];
      }
      __syncthreads();
    }
  } else {
    // ---------------- gang ----------------
    const int gi = wg - GANG0;
    const int start = gi * RPW;
    const int cnt = (RPW < kV - start) ? RPW : (kV - start);
    for (int t = 1; t < kT; ++t) {
      spinwait<8>(&sb->Z[t], 1u);
      for (int i = tid; i < kB * kZ; i += 256) shf[i] = aldf(&ws->z1n[t & 1][0][0] + i);
      __syncthreads();
      if (tid == 0)
        __hip_atomic_fetch_add(&sb->zread[t], 1u, __ATOMIC_RELAXED, __HIP_MEMORY_SCOPE_AGENT);
      unsigned fk0, fk1;
      tf2x32(0u, 1234u, 0u, (unsigned)t, fk0, fk1);
      const bool act = tid < cnt;
      const int row = start + tid;
      float lv[kB] = {0.f, 0.f, 0.f, 0.f};
      if (act) {
        const float* wr = W_fc2 + (size_t)row * kZ;
        const float bb = b_fc2[row];
        float a0 = bb, a1 = bb, a2 = bb, a3 = bb;
        for (int k = 0; k < kZ; k += 4) {
          const float4 wv = *reinterpret_cast<const float4*>(wr + k);
          const float4 z0 = *reinterpret_cast<const float4*>(&shf[0 * kZ + k]);
          const float4 z1 = *reinterpret_cast<const float4*>(&shf[1 * kZ + k]);
          const float4 z2 = *reinterpret_cast<const float4*>(&shf[2 * kZ + k]);
          const float4 z3 = *reinterpret_cast<const float4*>(&shf[3 * kZ + k]);
          a0 = fmaf(z0.x, wv.x, a0); a0 = fmaf(z0.y, wv.y, a0); a0 = fmaf(z0.z, wv.z, a0); a0 = fmaf(z0.w, wv.w, a0);
          a1 = fmaf(z1.x, wv.x, a1); a1 = fmaf(z1.y, wv.y, a1); a1 = fmaf(z1.z, wv.z, a1); a1 = fmaf(z1.w, wv.w, a1);
          a2 = fmaf(z2.x, wv.x, a2); a2 = fmaf(z2.y, wv.y, a2); a2 = fmaf(z2.z, wv.z, a2); a2 = fmaf(z2.w, wv.w, a2);
          a3 = fmaf(z3.x, wv.x, a3); a3 = fmaf(z3.y, wv.y, a3); a3 = fmaf(z3.z, wv.z, a3); a3 = fmaf(z3.w, wv.w, a3);
        }
        lv[0] = a0; lv[1] = a1; lv[2] = a2; lv[3] = a3;
      }
      // pass 1: argmax(l+g) key + max(l)
#pragma unroll
      for (int b = 0; b < kB; ++b) {
        unsigned long long key = 0ull;
        float v = act ? lv[b] : -INFINITY;
        if (act) {
          const unsigned bits = rbits(fk0, fk1, (unsigned)(b * kV + row));
          const float pv = lv[b] + gumbel_from_bits(bits);
          key = ((unsigned long long)ordkey(pv) << 32)
              | (unsigned long long)(0xFFFFFFFFu - (unsigned)row);
        }
#pragma unroll
        for (int m = 1; m < 64; m <<= 1) {
          const unsigned long long ko = shflx64(key, m);
          const float vo = __shfl_xor(v, m, 64);
          if (ko > key) key = ko;
          v = fmaxf(v, vo);
        }
        if ((tid & 63) == 0) { shk[(tid >> 6) * kB + b] = key; shf[1408 + (tid >> 6) * kB + b] = v; }
      }
      __syncthreads();
      if (tid == 0) {
#pragma unroll
        for (int b = 0; b < kB; ++b) {
          unsigned long long key = shk[b];
          float v = shf[1408 + b];
          for (int w2 = 1; w2 < 4; ++w2) {
            const unsigned long long ko = shk[w2 * kB + b];
            if (ko > key) key = ko;
            v = fmaxf(v, shf[1408 + w2 * kB + b]);
          }
          __hip_atomic_fetch_max(&sb->argkey[t][b], key, __ATOMIC_RELAXED, __HIP_MEMORY_SCOPE_AGENT);
          __hip_atomic_fetch_max(&sb->maxbits[t][b], ordkey(v), __ATOMIC_RELAXED, __HIP_MEMORY_SCOPE_AGENT);
        }
        relfetchadd(&sb->ctrA[t]);
      }
      spinwait<8>(&sb->ctrA[t], (unsigned)NGANG);
      if (tid == 0) {
#pragma unroll
        for (int b = 0; b < kB; ++b) shf[1424 + b] = inv_ordkey(ldu(&sb->maxbits[t][b]));
      }
      __syncthreads();
      // pass 2: sum(exp(l - max)) -> float LLC atomic add
#pragma unroll
      for (int b = 0; b < kB; ++b) {
        float sv = act ? expf(lv[b] - shf[1424 + b]) : 0.f;
#pragma unroll
        for (int m = 1; m < 64; m <<= 1) sv += __shfl_xor(sv, m, 64);
        if ((tid & 63) == 0) shf[1440 + (tid >> 6) * kB + b] = sv;
      }
      __syncthreads();
      if (tid == 0) {
#pragma unroll
        for (int b = 0; b < kB; ++b) {
          const float s = shf[1440 + b] + shf[1440 + kB + b] +
                          shf[1440 + 2 * kB + b] + shf[1440 + 3 * kB + b];
          __hip_atomic_fetch_add(&sb->psumacc[t][b], s, __ATOMIC_RELAXED, __HIP_MEMORY_SCOPE_AGENT);
        }
        relfetchadd(&sb->ctrB[t]);
      }
      // px0 duty: 16 WGs × 64 gate-rows, behind leader's Etok
      if (gi < NPX && t < kT - 1) {
        spinwait<2>(&sb->Etok[t], 1u);
        for (int i = tid; i < kB * kH; i += 256) shf[i] = aldf(&ws->xcur[0][0] + i);
        __syncthreads();
        {
          const int rowg = gi * 64 + (tid & 63), b = tid >> 6;
          const float* wr = decWih + (size_t)rowg * kH;   // layer-0 Wih
          const float* xz = &shf[b * kH];
          float acc = 0.f;
          for (int k = 0; k < kH; k += 4) {
            const float4 wv = *reinterpret_cast<const float4*>(wr + k);
            const float4 xv = *reinterpret_cast<const float4*>(xz + k);
            acc = fmaf(xv.x, wv.x, acc); acc = fmaf(xv.y, wv.y, acc);
            acc = fmaf(xv.z, wv.z, acc); acc = fmaf(xv.w, wv.w, acc);
          }
          astf(&ws->px0[t][0][0] + (size_t)b * kG + rowg, acc);
        }
        __syncthreads();
        if (tid == 0) relfetchadd(&sb->PtokCnt[t]);
      }
    }
  }
}

} // namespace s2sr

extern "C" void kernel_launch(void* const* d_in, const int* in_sizes, int n_in,
                              void* d_out, int out_size, void* d_ws, size_t ws_size,
                              hipStream_t stream) {
  using namespace s2sr;
  (void)in_sizes; (void)n_in; (void)out_size;
  if (ws_size < sizeof(WS)) return;
  const int*   input_ids = (const int*)d_in[0];
  // d_in[1] = attention_mask (unused)
  const float* labels    = (const float*)d_in[2];
  const float* emb       = (const float*)d_in[3];
  const float* W_e2e     = (const float*)d_in[4];
  const float* b_e2e     = (const float*)d_in[5];
  const float* W_e2d     = (const float*)d_in[6];
  const float* b_e2d     = (const float*)d_in[7];
  const float* encWih    = (const float*)d_in[8];
  const float* encWhh    = (const float*)d_in[9];
  const float* encbih    = (const float*)d_in[10];
  const float* encbhh    = (const float*)d_in[11];
  const float* decWih    = (const float*)d_in[12];
  const float* decWhh    = (const float*)d_in[13];
  const float* decbih    = (const float*)d_in[14];
  const float* decbhh    = (const float*)d_in[15];
  const float* W_cls     = (const float*)d_in[16];
  const float* b_cls     = (const float*)d_in[17];
  const float* W_fc1     = (const float*)d_in[18];
  const float* b_fc1     = (const float*)d_in[19];
  const float* ln_g      = (const float*)d_in[20];
  const float* ln_b      = (const float*)d_in[21];
  const float* W_fc2     = (const float*)d_in[22];
  const float* b_fc2     = (const float*)d_in[23];

  // re-arm flags + zero initial LSTM state (head of WS only)
  hipMemsetAsync(d_ws, 0, (size_t)offsetof(WS, px0), stream);
  hipLaunchKernelGGL(s2s_kernel, dim3(NWG), dim3(256), 0, stream,
      input_ids, labels, emb, W_e2e, b_e2e, W_e2d, b_e2d,
      encWih, encWhh, encbih, encbhh, decWih, decWhh, decbih, decbhh,
      W_cls, b_cls, W_fc1, b_fc1, ln_g, ln_b, W_fc2, b_fc2,
      (float*)d_out, (WS*)d_ws);
}

// Round 4
// 9108.987 us; speedup vs baseline: 3.2161x; 1.3270x over previous
//
#include <hip/hip_runtime.h>
#include <stdint.h>
#include <stddef.h>
#include <math.h>

// ============================================================================
// Seq2SeqReinforce — persistent kernel, round 4.
// Round-2 structure (proven correct) + contention fixes:
//  - every sync flag on its own 128B LLC line
//  - two-line sense-reversing barriers (RMW line separate from polled line)
//  - LN moved to the leader (cluster has no straggler WG)
//  - gang single-pass softmax (no max pass; logits bounded ~|5|), 8-way split
//    float-atomic psum
// All cross-WG data uses agent-scope __hip_atomic_* (LLC) — the primitives
// validated bit-exact in rounds 1-2. No inline asm, no XCD discovery.
// ============================================================================

#define PARTITIONABLE_PRNG 1   // confirmed bit-exact in rounds 1-2

namespace s2sr {

constexpr int kV = 50257, kE = 256, kH = 256, kCc = 64, kB = 4, kT = 48;
constexpr int kZ = kH + kCc;   // 320
constexpr int kG = 4 * kH;     // 1024
constexpr int kMask = 103;
constexpr float kEps = 1e-5f;
constexpr float kTiny = 1.17549435e-38f;

constexpr int NWG = 256, TPB = 256;
constexpr int NCL = 32;                        // cluster WGs
constexpr int LEAD = 32;
constexpr int GANG0 = 33;
constexpr int NGANG = NWG - GANG0;             // 223
constexpr int RPW = (kV + NGANG - 1) / NGANG;  // 226 rows/WG
constexpr int NPX = 16;                        // gang WGs doing px0 duty

// LDS float offsets (cluster tick layout)
constexpr int SH_H0 = 0;      // 1024: staged h0prev  [b][256]
constexpr int SH_H1 = 1024;   // 1024: staged h1prev2 [b][256]
constexpr int SH_P0 = 2048;   // 1024: l0 partials [w][32][4]
constexpr int SH_P1 = 3072;   // 1024: l1 partials
constexpr int SH_Z  = 4096;   // 256:  z rows [L][32][4]
constexpr int SH_TOT = 4608;

struct alignas(128) Pad  { unsigned v; unsigned _p[31]; };
struct alignas(128) PadK { unsigned long long v; unsigned long long _p[15]; };
struct alignas(128) PadF { float v[kB]; float _p[28]; };

struct SyncBlk {
  Pad ictr, igen;          // init barrier (arrivals / generation)
  Pad cctr, cgen;          // cluster tick barrier
  Pad Zpre[kT];            // fc1 done (cluster -> leader), ==1
  Pad Z[kT];               // z1n ready (leader -> gang), ==1
  Pad zread[kT];           // gang staged z1n (==NGANG)
  Pad ctrB[kT];            // gang done (==NGANG)
  Pad Etok[kT];            // leader published xcur, ==1
  Pad Ptok[kT];            // px0[t] slices done (==NPX)
  PadK argkey[kT][kB];     // atomicMax (ordkey(l+g)<<32 | ~row)
  PadF psum8[kT][8];       // 8-way split sum(exp(l)) float atomics
};

struct WS {
  // ---- zeroed head (memset each launch) ----
  SyncBlk s;
  float h0buf[2][kB][kH];
  float h1buf[2][kB][kH];
  float cls[kB][kCc];
  float xd0[kB][kH];
  float z1pre[kB][kZ];
  float z1n[2][kB][kZ];
  float xcur[kB][kH];
  // ---- not zeroed (always written before read, gated by flags) ----
  float px0[kT][kB][kG];
  float pxe[kT][kB][kG];
};

// ---------------- atomic helpers (agent scope = LLC) ----------------
__device__ __forceinline__ float aldf(const float* p) {
  return __hip_atomic_load(p, __ATOMIC_RELAXED, __HIP_MEMORY_SCOPE_AGENT);
}
__device__ __forceinline__ void astf(float* p, float v) {
  __hip_atomic_store(p, v, __ATOMIC_RELAXED, __HIP_MEMORY_SCOPE_AGENT);
}
__device__ __forceinline__ void relfetchadd(unsigned* p) {
  __hip_atomic_fetch_add(p, 1u, __ATOMIC_RELEASE, __HIP_MEMORY_SCOPE_AGENT);
}
// tid0 spin + syncthreads, on a padded (read-only traffic) line
template <int SLP>
__device__ __forceinline__ void spin(Pad* p, unsigned tgt) {
  if (threadIdx.x == 0) {
    while (__hip_atomic_load(&p->v, __ATOMIC_RELAXED, __HIP_MEMORY_SCOPE_AGENT) < tgt)
      __builtin_amdgcn_s_sleep(SLP);
    __atomic_signal_fence(__ATOMIC_ACQUIRE);
  }
  __syncthreads();
}
// cluster tick barrier: arrivals on cctr line (no readers), poll on cgen line
__device__ __forceinline__ void cbar(SyncBlk* sb, unsigned& ep) {
  __syncthreads();                       // drains this WG's stores
  ep += (unsigned)NCL;
  if (threadIdx.x == 0) {
    const unsigned old = __hip_atomic_fetch_add(&sb->cctr.v, 1u, __ATOMIC_RELEASE,
                                                __HIP_MEMORY_SCOPE_AGENT);
    if (old == ep - 1u)
      __hip_atomic_store(&sb->cgen.v, ep, __ATOMIC_RELEASE, __HIP_MEMORY_SCOPE_AGENT);
    while (__hip_atomic_load(&sb->cgen.v, __ATOMIC_RELAXED, __HIP_MEMORY_SCOPE_AGENT) < ep)
      __builtin_amdgcn_s_sleep(1);
    __atomic_signal_fence(__ATOMIC_ACQUIRE);
  }
  __syncthreads();
}
__device__ __forceinline__ void gbar(SyncBlk* sb, unsigned tgt) {
  __syncthreads();
  if (threadIdx.x == 0) {
    const unsigned old = __hip_atomic_fetch_add(&sb->ictr.v, 1u, __ATOMIC_RELEASE,
                                                __HIP_MEMORY_SCOPE_AGENT);
    if (old == tgt - 1u)
      __hip_atomic_store(&sb->igen.v, tgt, __ATOMIC_RELEASE, __HIP_MEMORY_SCOPE_AGENT);
    while (__hip_atomic_load(&sb->igen.v, __ATOMIC_RELAXED, __HIP_MEMORY_SCOPE_AGENT) < tgt)
      __builtin_amdgcn_s_sleep(2);
    __atomic_signal_fence(__ATOMIC_ACQUIRE);
  }
  __syncthreads();
}

// ---------------- Threefry2x32 (bit-exact vs JAX; validated) ----------------
__device__ __forceinline__ unsigned rotl32(unsigned v, int n) {
  return (v << n) | (v >> (32 - n));
}
__device__ __forceinline__ void tf2x32(unsigned k0, unsigned k1, unsigned x0, unsigned x1,
                                       unsigned& o0, unsigned& o1) {
  const unsigned k2 = k0 ^ k1 ^ 0x1BD11BDAu;
  unsigned v0 = x0 + k0, v1 = x1 + k1;
  v0 += v1; v1 = rotl32(v1, 13); v1 ^= v0;
  v0 += v1; v1 = rotl32(v1, 15); v1 ^= v0;
  v0 += v1; v1 = rotl32(v1, 26); v1 ^= v0;
  v0 += v1; v1 = rotl32(v1, 6);  v1 ^= v0;
  v0 += k1; v1 += k2 + 1u;
  v0 += v1; v1 = rotl32(v1, 17); v1 ^= v0;
  v0 += v1; v1 = rotl32(v1, 29); v1 ^= v0;
  v0 += v1; v1 = rotl32(v1, 16); v1 ^= v0;
  v0 += v1; v1 = rotl32(v1, 24); v1 ^= v0;
  v0 += k2; v1 += k0 + 2u;
  v0 += v1; v1 = rotl32(v1, 13); v1 ^= v0;
  v0 += v1; v1 = rotl32(v1, 15); v1 ^= v0;
  v0 += v1; v1 = rotl32(v1, 26); v1 ^= v0;
  v0 += v1; v1 = rotl32(v1, 6);  v1 ^= v0;
  v0 += k0; v1 += k1 + 3u;
  v0 += v1; v1 = rotl32(v1, 17); v1 ^= v0;
  v0 += v1; v1 = rotl32(v1, 29); v1 ^= v0;
  v0 += v1; v1 = rotl32(v1, 16); v1 ^= v0;
  v0 += v1; v1 = rotl32(v1, 24); v1 ^= v0;
  v0 += k1; v1 += k2 + 4u;
  v0 += v1; v1 = rotl32(v1, 13); v1 ^= v0;
  v0 += v1; v1 = rotl32(v1, 15); v1 ^= v0;
  v0 += v1; v1 = rotl32(v1, 26); v1 ^= v0;
  v0 += v1; v1 = rotl32(v1, 6);  v1 ^= v0;
  o0 = v0 + k2; o1 = v1 + k0 + 5u;
}
__device__ __forceinline__ unsigned rbits(unsigned k0, unsigned k1, unsigned i) {
#if PARTITIONABLE_PRNG
  unsigned a, b; tf2x32(k0, k1, 0u, i, a, b);
  return a ^ b;
#else
  constexpr unsigned HALF = (unsigned)((kB * kV + 1) / 2);
  unsigned a, b;
  if (i < HALF) { tf2x32(k0, k1, i, i + HALF, a, b); return a; }
  tf2x32(k0, k1, i - HALF, i, a, b); return b;
#endif
}
__device__ __forceinline__ float gumbel_from_bits(unsigned bits) {
  float f = __uint_as_float((bits >> 9) | 0x3f800000u) - 1.0f;
  f = fmaxf(f, kTiny);
  return -logf(-logf(f));
}
__device__ __forceinline__ unsigned ordkey(float f) {
  const unsigned u = __float_as_uint(f);
  return (u & 0x80000000u) ? ~u : (u | 0x80000000u);
}
__device__ __forceinline__ unsigned long long shflx64(unsigned long long v, int m) {
  unsigned lo = (unsigned)v, hi = (unsigned)(v >> 32);
  lo = (unsigned)__shfl_xor((int)lo, m, 64);
  hi = (unsigned)__shfl_xor((int)hi, m, 64);
  return ((unsigned long long)hi << 32) | (unsigned long long)lo;
}
__device__ __forceinline__ float sigm(float x) { return 1.0f / (1.0f + expf(-x)); }

// ---------------- merged LSTM tick (round-2 verbatim math) ------------------
// Tick for cell cc: layer0(cc) [reads h0buf[(cc+1)&1], writes h0buf[cc&1]]
//               +   layer1(cc-1) [x = h0buf[(cc+1)&1], h = h1buf[cc&1],
//                                 writes h1buf[(cc+1)&1]]
// Thread map: r = tid&31 -> gate-row grow = (r&3)*256 + cw*8 + (r>>2);
//             w = tid>>5 -> k-window (l0: 32 floats, l1: 64 of the 512-concat)
template <bool STREAM>
__device__ __forceinline__ void lstm_tick(
    SyncBlk* sb, WS* ws, float* shf, int cw, unsigned& ep, int cc,
    bool do_l0, bool do_l1, const float* px,
    const float* pW0, const float* pW1,
    const float4* w0r, const float4* w1r,
    float biasr, float& c0, float& c1, int grow, int r, int w) {
  const int tid = (int)threadIdx.x;
  float pxv0 = 0.f, pxv1 = 0.f, pxv2 = 0.f, pxv3 = 0.f;
  if (do_l0 && tid < 32) {
    pxv0 = aldf(px + 0 * kG + grow);
    pxv1 = aldf(px + 1 * kG + grow);
    pxv2 = aldf(px + 2 * kG + grow);
    pxv3 = aldf(px + 3 * kG + grow);
  }
  {
    const float* h0p = &ws->h0buf[(cc + 1) & 1][0][0];
#pragma unroll
    for (int i = 0; i < 4; ++i) shf[SH_H0 + tid + i * 256] = aldf(h0p + tid + i * 256);
    if (do_l1) {
      const float* h1p = &ws->h1buf[cc & 1][0][0];   // (cc-2)&1
#pragma unroll
      for (int i = 0; i < 4; ++i) shf[SH_H1 + tid + i * 256] = aldf(h1p + tid + i * 256);
    }
  }
  __syncthreads();
  float4 wv0[8], wv1[16];
  if (do_l0) {
#pragma unroll
    for (int i = 0; i < 8; ++i)
      wv0[i] = STREAM ? *reinterpret_cast<const float4*>(pW0 + i * 4) : w0r[i];
  }
  if (do_l1) {
#pragma unroll
    for (int i = 0; i < 16; ++i)
      wv1[i] = STREAM ? *reinterpret_cast<const float4*>(pW1 + i * 4) : w1r[i];
  }
  if (do_l0) {
    const float* A = &shf[SH_H0 + w * 32];
    float a0 = 0.f, a1 = 0.f, a2 = 0.f, a3 = 0.f;
#pragma unroll
    for (int i = 0; i < 8; ++i) {
      const float4 wv = wv0[i];
      const float4 x0 = *reinterpret_cast<const float4*>(A + 0 * 256 + i * 4);
      const float4 x1 = *reinterpret_cast<const float4*>(A + 1 * 256 + i * 4);
      const float4 x2 = *reinterpret_cast<const float4*>(A + 2 * 256 + i * 4);
      const float4 x3 = *reinterpret_cast<const float4*>(A + 3 * 256 + i * 4);
      a0 = fmaf(wv.x, x0.x, a0); a0 = fmaf(wv.y, x0.y, a0); a0 = fmaf(wv.z, x0.z, a0); a0 = fmaf(wv.w, x0.w, a0);
      a1 = fmaf(wv.x, x1.x, a1); a1 = fmaf(wv.y, x1.y, a1); a1 = fmaf(wv.z, x1.z, a1); a1 = fmaf(wv.w, x1.w, a1);
      a2 = fmaf(wv.x, x2.x, a2); a2 = fmaf(wv.y, x2.y, a2); a2 = fmaf(wv.z, x2.z, a2); a2 = fmaf(wv.w, x2.w, a2);
      a3 = fmaf(wv.x, x3.x, a3); a3 = fmaf(wv.y, x3.y, a3); a3 = fmaf(wv.z, x3.z, a3); a3 = fmaf(wv.w, x3.w, a3);
    }
    *reinterpret_cast<float4*>(&shf[SH_P0 + w * 128 + r * 4]) = float4{a0, a1, a2, a3};
  }
  if (do_l1) {
    const float* Bp = (w < 4) ? &shf[SH_H0 + w * 64] : &shf[SH_H1 + (w - 4) * 64];
    float a0 = 0.f, a1 = 0.f, a2 = 0.f, a3 = 0.f;
#pragma unroll
    for (int i = 0; i < 16; ++i) {
      const float4 wv = wv1[i];
      const float4 x0 = *reinterpret_cast<const float4*>(Bp + 0 * 256 + i * 4);
      const float4 x1 = *reinterpret_cast<const float4*>(Bp + 1 * 256 + i * 4);
      const float4 x2 = *reinterpret_cast<const float4*>(Bp + 2 * 256 + i * 4);
      const float4 x3 = *reinterpret_cast<const float4*>(Bp + 3 * 256 + i * 4);
      a0 = fmaf(wv.x, x0.x, a0); a0 = fmaf(wv.y, x0.y, a0); a0 = fmaf(wv.z, x0.z, a0); a0 = fmaf(wv.w, x0.w, a0);
      a1 = fmaf(wv.x, x1.x, a1); a1 = fmaf(wv.y, x1.y, a1); a1 = fmaf(wv.z, x1.z, a1); a1 = fmaf(wv.w, x1.w, a1);
      a2 = fmaf(wv.x, x2.x, a2); a2 = fmaf(wv.y, x2.y, a2); a2 = fmaf(wv.z, x2.z, a2); a2 = fmaf(wv.w, x2.w, a2);
      a3 = fmaf(wv.x, x3.x, a3); a3 = fmaf(wv.y, x3.y, a3); a3 = fmaf(wv.z, x3.z, a3); a3 = fmaf(wv.w, x3.w, a3);
    }
    *reinterpret_cast<float4*>(&shf[SH_P1 + w * 128 + r * 4]) = float4{a0, a1, a2, a3};
  }
  __syncthreads();
  if (tid < 64) {
    const int L = tid >> 5, rr = tid & 31;
    const bool en = L ? do_l1 : do_l0;
    if (en) {
      const int base = (L ? SH_P1 : SH_P0) + rr * 4;
      float4 z = float4{0.f, 0.f, 0.f, 0.f};
#pragma unroll
      for (int w2 = 0; w2 < 8; ++w2) {
        const float4 p = *reinterpret_cast<const float4*>(&shf[base + w2 * 128]);
        z.x += p.x; z.y += p.y; z.z += p.z; z.w += p.w;
      }
      z.x += biasr; z.y += biasr; z.z += biasr; z.w += biasr;
      if (L == 0) { z.x += pxv0; z.y += pxv1; z.z += pxv2; z.w += pxv3; }
      *reinterpret_cast<float4*>(&shf[SH_Z + L * 128 + rr * 4]) = z;
    }
  }
  __syncthreads();
  if (tid < 64) {
    const int L = tid >> 5, slot = tid & 31;
    const bool en = L ? do_l1 : do_l0;
    if (en) {
      const int b = slot >> 3, u = slot & 7;
      const int zb = SH_Z + L * 128 + u * 16 + b;
      const float zi = shf[zb], zf = shf[zb + 4], zg = shf[zb + 8], zo = shf[zb + 12];
      const float cs = L ? c1 : c0;
      const float cn = sigm(zf) * cs + sigm(zi) * tanhf(zg);
      const float hn = sigm(zo) * tanhf(cn);
      if (L) { c1 = cn; astf(&ws->h1buf[(cc + 1) & 1][b][cw * 8 + u], hn); }
      else   { c0 = cn; astf(&ws->h0buf[cc & 1][b][cw * 8 + u], hn); }
    }
  }
  cbar(sb, ep);
}

// fc1 tick: 320 rows distributed 10/WG; z = [h1last ; cls]
__device__ __forceinline__ void fc1_tick(SyncBlk* sb, WS* ws, float* shf, int cw,
                                         unsigned& ep, int t, int p1,
                                         const float* Wfc1, const float* bfc1) {
  // leader must have consumed z1pre of scan t-1 (it releases Z[t-1] after)
  if (t >= 2) spin<1>(&sb->Z[t - 1], 1u);
  const int tid = (int)threadIdx.x;
  for (int i = tid; i < kB * kZ; i += 256) {
    const int b = i / kZ, k = i - b * kZ;
    shf[i] = (k < kH) ? aldf(&ws->h1buf[p1][b][k]) : aldf(&ws->cls[b][k - kH]);
  }
  __syncthreads();
  if (tid < 160) {
    const int task = tid >> 2, q = tid & 3;
    const int rowl = task >> 2, b = task & 3;
    const int rowg = cw * 10 + rowl;
    const float* wr = Wfc1 + (size_t)rowg * kZ + q * 80;
    const float* zz = &shf[b * kZ + q * 80];
    float acc = 0.f;
#pragma unroll
    for (int k = 0; k < 80; k += 4) {
      const float4 wv = *reinterpret_cast<const float4*>(wr + k);
      const float4 zv = *reinterpret_cast<const float4*>(zz + k);
      acc = fmaf(zv.x, wv.x, acc); acc = fmaf(zv.y, wv.y, acc);
      acc = fmaf(zv.z, wv.z, acc); acc = fmaf(zv.w, wv.w, acc);
    }
    shf[SH_P0 + task * 4 + q] = acc;
  }
  __syncthreads();
  if (tid < 40) {
    const int rowl = tid >> 2, b = tid & 3;
    const int rowg = cw * 10 + rowl;
    const float z1 = shf[SH_P0 + tid * 4 + 0] + shf[SH_P0 + tid * 4 + 1] +
                     shf[SH_P0 + tid * 4 + 2] + shf[SH_P0 + tid * 4 + 3] + bfc1[rowg];
    astf(&ws->z1pre[b][rowg], z1);
  }
  cbar(sb, ep);
  if (cw == 0 && tid == 0) relfetchadd(&sb->Zpre[t].v);
}

// ---------------- kernel ----------------
__global__ void __launch_bounds__(TPB, 1) s2s_kernel(
    const int* __restrict__ input_ids, const float* __restrict__ labels,
    const float* __restrict__ emb,
    const float* __restrict__ W_e2e, const float* __restrict__ b_e2e,
    const float* __restrict__ W_e2d, const float* __restrict__ b_e2d,
    const float* __restrict__ encWih, const float* __restrict__ encWhh,
    const float* __restrict__ encbih, const float* __restrict__ encbhh,
    const float* __restrict__ decWih, const float* __restrict__ decWhh,
    const float* __restrict__ decbih, const float* __restrict__ decbhh,
    const float* __restrict__ W_cls, const float* __restrict__ b_cls,
    const float* __restrict__ Wfc1, const float* __restrict__ bfc1,
    const float* __restrict__ lng, const float* __restrict__ lnb,
    const float* __restrict__ W_fc2, const float* __restrict__ b_fc2,
    float* __restrict__ out, WS* __restrict__ ws) {
  const int wg = (int)blockIdx.x;
  const int tid = (int)threadIdx.x;
  SyncBlk* sb = &ws->s;
  __shared__ __align__(16) float shf[SH_TOT];
  __shared__ unsigned long long shk[16];
  __shared__ int shi[8];

  // ================= init phase 1 =================
  if (wg < kB * kT) {
    const int b = wg / kT, j = wg % kT;
    const int id = input_ids[b * kT + j];
    for (int i = tid; i < kE; i += 256) shf[i] = emb[(size_t)id * kE + i];
    __syncthreads();
    const float* wr = W_e2e + (size_t)tid * kE;
    float acc = b_e2e[tid];
    for (int k = 0; k < kE; k += 4) {
      const float4 wv = *reinterpret_cast<const float4*>(wr + k);
      const float4 xv = *reinterpret_cast<const float4*>(&shf[k]);
      acc = fmaf(xv.x, wv.x, acc); acc = fmaf(xv.y, wv.y, acc);
      acc = fmaf(xv.z, wv.z, acc); acc = fmaf(xv.w, wv.w, acc);
    }
    __syncthreads();
    shf[256 + tid] = fmaxf(acc, 0.f);
  } else if (wg == 192) {
    if (tid < kB * kCc) {
      const int b = tid >> 6, c = tid & 63;
      astf(&ws->cls[b][c], fmaf(labels[b], W_cls[c], b_cls[c]));
    }
    if (tid < kB) {
      const int t0 = input_ids[tid * kT];
      out[tid * kT] = 0.f;
      out[kB * kT + tid * kT] = (float)t0;
    }
  } else if (wg == 193) {
    const float* wr = W_e2d + (size_t)tid * kE;
    const float* e0 = emb + (size_t)input_ids[0 * kT] * kE;
    const float* e1 = emb + (size_t)input_ids[1 * kT] * kE;
    const float* e2 = emb + (size_t)input_ids[2 * kT] * kE;
    const float* e3 = emb + (size_t)input_ids[3 * kT] * kE;
    const float bb = b_e2d[tid];
    float a0 = bb, a1 = bb, a2 = bb, a3 = bb;
    for (int k = 0; k < kE; k += 4) {
      const float4 wv = *reinterpret_cast<const float4*>(wr + k);
      const float4 v0 = *reinterpret_cast<const float4*>(e0 + k);
      const float4 v1 = *reinterpret_cast<const float4*>(e1 + k);
      const float4 v2 = *reinterpret_cast<const float4*>(e2 + k);
      const float4 v3 = *reinterpret_cast<const float4*>(e3 + k);
      a0 = fmaf(v0.x, wv.x, a0); a0 = fmaf(v0.y, wv.y, a0); a0 = fmaf(v0.z, wv.z, a0); a0 = fmaf(v0.w, wv.w, a0);
      a1 = fmaf(v1.x, wv.x, a1); a1 = fmaf(v1.y, wv.y, a1); a1 = fmaf(v1.z, wv.z, a1); a1 = fmaf(v1.w, wv.w, a1);
      a2 = fmaf(v2.x, wv.x, a2); a2 = fmaf(v2.y, wv.y, a2); a2 = fmaf(v2.z, wv.z, a2); a2 = fmaf(v2.w, wv.w, a2);
      a3 = fmaf(v3.x, wv.x, a3); a3 = fmaf(v3.y, wv.y, a3); a3 = fmaf(v3.z, wv.z, a3); a3 = fmaf(v3.w, wv.w, a3);
    }
    astf(&ws->xd0[0][tid], fmaxf(a0, 0.f));
    astf(&ws->xd0[1][tid], fmaxf(a1, 0.f));
    astf(&ws->xd0[2][tid], fmaxf(a2, 0.f));
    astf(&ws->xd0[3][tid], fmaxf(a3, 0.f));
  }
  gbar(sb, (unsigned)NWG);

  // ================= init phase 2 =================
  if (wg < kB * kT) {
    const int b = wg / kT, j = wg % kT;
#pragma unroll
    for (int rr = 0; rr < 4; ++rr) {
      const int g = rr * 256 + tid;
      const float* wr = encWih + (size_t)g * kH;
      float acc = 0.f;
      for (int k = 0; k < kH; k += 4) {
        const float4 wv = *reinterpret_cast<const float4*>(wr + k);
        const float4 xv = *reinterpret_cast<const float4*>(&shf[256 + k]);
        acc = fmaf(xv.x, wv.x, acc); acc = fmaf(xv.y, wv.y, acc);
        acc = fmaf(xv.z, wv.z, acc); acc = fmaf(xv.w, wv.w, acc);
      }
      astf(&ws->pxe[j][0][0] + (size_t)b * kG + g, acc);
    }
  } else if (wg >= 192 && wg < 208) {
    const int w2 = wg - 192, b = w2 >> 2, q = w2 & 3;
    const int g = q * 256 + tid;
    for (int i = tid; i < kH; i += 256) shf[i] = aldf(&ws->xd0[b][i]);
    __syncthreads();
    const float* wr = decWih + (size_t)g * kH;
    float acc = 0.f;
    for (int k = 0; k < kH; k += 4) {
      const float4 wv = *reinterpret_cast<const float4*>(wr + k);
      const float4 xv = *reinterpret_cast<const float4*>(&shf[k]);
      acc = fmaf(xv.x, wv.x, acc); acc = fmaf(xv.y, wv.y, acc);
      acc = fmaf(xv.z, wv.z, acc); acc = fmaf(xv.w, wv.w, acc);
    }
    astf(&ws->px0[0][0][0] + (size_t)b * kG + g, acc);
  }
  gbar(sb, (unsigned)(2 * NWG));

  // ================= roles =================
  if (wg < NCL) {
    // ---------------- cluster ----------------
    const int cw = wg;
    const int r = tid & 31, w = tid >> 5;
    const int grow = (r & 3) * 256 + cw * 8 + (r >> 2);
    const int L = tid >> 5;
    unsigned ep = 0;
    float c0 = 0.f, c1 = 0.f;
    float biasr = 0.f;
    if (tid < 64)
      biasr = (L == 0) ? encbih[grow] + encbhh[grow]
                       : encbih[kG + grow] + encbhh[kG + grow];
    const float* pW0e = encWhh + (size_t)grow * kH + w * 32;
    const float* pW1e = (w < 4)
        ? encWih + (size_t)kG * kH + (size_t)grow * kH + w * 64
        : encWhh + (size_t)kG * kH + (size_t)grow * kH + (w - 4) * 64;
    int cc = 0;
    // encoder (weights streamed; L2-resident after first tick)
    for (int j = 0; j < kT; ++j, ++cc)
      lstm_tick<true>(sb, ws, shf, cw, ep, cc, true, j > 0, &ws->pxe[j][0][0],
                      pW0e, pW1e, nullptr, nullptr, biasr, c0, c1, grow, r, w);
    lstm_tick<true>(sb, ws, shf, cw, ep, cc, false, true, nullptr,
                    pW0e, pW1e, nullptr, nullptr, biasr, c0, c1, grow, r, w);
    // decoder weights -> registers (96 floats/thread)
    float4 w0d[8], w1d[16];
    {
      const float* p0 = decWhh + (size_t)grow * kH + w * 32;
#pragma unroll
      for (int i = 0; i < 8; ++i) w0d[i] = *reinterpret_cast<const float4*>(p0 + i * 4);
      const float* p1 = (w < 4)
          ? decWih + (size_t)kG * kH + (size_t)grow * kH + w * 64
          : decWhh + (size_t)kG * kH + (size_t)grow * kH + (w - 4) * 64;
#pragma unroll
      for (int i = 0; i < 16; ++i) w1d[i] = *reinterpret_cast<const float4*>(p1 + i * 4);
      if (tid < 64)
        biasr = (L == 0) ? decbih[grow] + decbhh[grow]
                         : decbih[kG + grow] + decbhh[kG + grow];
    }
    // decoder scans
    for (int t = 1; t < kT; ++t) {
      for (int j = 0; j < t; ++j, ++cc) {
        if (j == t - 1 && t >= 2) spin<1>(&sb->Ptok[t - 1], (unsigned)NPX);
        lstm_tick<false>(sb, ws, shf, cw, ep, cc, true, j > 0, &ws->px0[j][0][0],
                         nullptr, nullptr, w0d, w1d, biasr, c0, c1, grow, r, w);
      }
      lstm_tick<false>(sb, ws, shf, cw, ep, cc, false, true, nullptr,
                       nullptr, nullptr, w0d, w1d, biasr, c0, c1, grow, r, w);
      fc1_tick(sb, ws, shf, cw, ep, t, (cc + 1) & 1, Wfc1, bfc1);
    }
  } else if (wg == LEAD) {
    // ---------------- leader: LN + sample + embed + xcur ----------------
    for (int t = 1; t < kT; ++t) {
      spin<1>(&sb->Zpre[t], 1u);
      if (t >= 3) spin<1>(&sb->zread[t - 2], (unsigned)NGANG);
      // stage z1pre + relu
      for (int i = tid; i < kB * kZ; i += 256)
        shf[i] = fmaxf(aldf(&ws->z1pre[0][0] + i), 0.f);
      __syncthreads();
      {  // LayerNorm, in place; publish z1n
        const int b = tid >> 6, ln = tid & 63;
        float s1 = 0.f, s2 = 0.f;
        for (int i = ln; i < kZ; i += 64) { const float v = shf[b * kZ + i]; s1 += v; s2 += v * v; }
#pragma unroll
        for (int o = 32; o > 0; o >>= 1) { s1 += __shfl_xor(s1, o, 64); s2 += __shfl_xor(s2, o, 64); }
        const float mu = s1 * (1.0f / kZ);
        const float var = s2 * (1.0f / kZ) - mu * mu;
        const float rs = 1.0f / sqrtf(var + kEps);
        for (int i = ln; i < kZ; i += 64) {
          const float v = fmaf((shf[b * kZ + i] - mu) * rs, lng[i], lnb[i]);
          shf[b * kZ + i] = v;
          astf(&ws->z1n[t & 1][b][i], v);
        }
      }
      __syncthreads();
      if (tid == 0) relfetchadd(&sb->Z[t].v);
      // wait for gang
      spin<2>(&sb->ctrB[t], (unsigned)NGANG);
      if (tid < kB) {
        const int b = tid;
        const unsigned long long key =
            __hip_atomic_load(&sb->argkey[t][b].v, __ATOMIC_RELAXED, __HIP_MEMORY_SCOPE_AGENT);
        const int samp = (int)(0xFFFFFFFFu - (unsigned)(key & 0xFFFFFFFFull));
        float s = 0.f;
#pragma unroll
        for (int k = 0; k < 8; ++k) s += aldf(&sb->psum8[t][k].v[b]);
        const float lse = logf(s);
        const int cur = input_ids[b * kT + t];
        const int nxt = (cur == kMask) ? samp : cur;
        out[kB * kT + b * kT + t] = (float)nxt;
        shi[b] = nxt; shi[4 + b] = samp;
        shf[1300 + b] = lse;
      }
      __syncthreads();
      if (t < kT - 1) {
        // xcur = relu(emb[tok] @ W_e2d^T + b) -> LLC; release Etok
        const float* wr = W_e2d + (size_t)tid * kE;
        const float* e0 = emb + (size_t)shi[0] * kE;
        const float* e1 = emb + (size_t)shi[1] * kE;
        const float* e2 = emb + (size_t)shi[2] * kE;
        const float* e3 = emb + (size_t)shi[3] * kE;
        const float bb = b_e2d[tid];
        float a0 = bb, a1 = bb, a2 = bb, a3 = bb;
        for (int k = 0; k < kE; k += 4) {
          const float4 wv = *reinterpret_cast<const float4*>(wr + k);
          const float4 v0 = *reinterpret_cast<const float4*>(e0 + k);
          const float4 v1 = *reinterpret_cast<const float4*>(e1 + k);
          const float4 v2 = *reinterpret_cast<const float4*>(e2 + k);
          const float4 v3 = *reinterpret_cast<const float4*>(e3 + k);
          a0 = fmaf(v0.x, wv.x, a0); a0 = fmaf(v0.y, wv.y, a0); a0 = fmaf(v0.z, wv.z, a0); a0 = fmaf(v0.w, wv.w, a0);
          a1 = fmaf(v1.x, wv.x, a1); a1 = fmaf(v1.y, wv.y, a1); a1 = fmaf(v1.z, wv.z, a1); a1 = fmaf(v1.w, wv.w, a1);
          a2 = fmaf(v2.x, wv.x, a2); a2 = fmaf(v2.y, wv.y, a2); a2 = fmaf(v2.z, wv.z, a2); a2 = fmaf(v2.w, wv.w, a2);
          a3 = fmaf(v3.x, wv.x, a3); a3 = fmaf(v3.y, wv.y, a3); a3 = fmaf(v3.z, wv.z, a3); a3 = fmaf(v3.w, wv.w, a3);
        }
        astf(&ws->xcur[0][tid], fmaxf(a0, 0.f));
        astf(&ws->xcur[1][tid], fmaxf(a1, 0.f));
        astf(&ws->xcur[2][tid], fmaxf(a2, 0.f));
        astf(&ws->xcur[3][tid], fmaxf(a3, 0.f));
        __syncthreads();
        if (tid == 0) relfetchadd(&sb->Etok[t].v);
      }
      // score = logit[b][samp] - lse, using local normalized z1n in shf
      {
        const int b = tid >> 6, lane = tid & 63;
        const int sp = shi[4 + b];
        const float* wr = W_fc2 + (size_t)sp * kZ;
        float acc = 0.f;
#pragma unroll
        for (int i = 0; i < 5; ++i)
          acc = fmaf(shf[b * kZ + lane + i * 64], wr[lane + i * 64], acc);
#pragma unroll
        for (int o = 32; o > 0; o >>= 1) acc += __shfl_xor(acc, o, 64);
        if (lane == 0) out[b * kT + t] = acc + b_fc2[sp] - shf[1300 + b];
      }
      __syncthreads();
    }
  } else {
    // ---------------- gang ----------------
    const int gi = wg - GANG0;
    const int start = gi * RPW;
    const int cnt = (RPW < kV - start) ? RPW : (kV - start);
    const bool act = tid < cnt;
    const int row = start + tid;
    for (int t = 1; t < kT; ++t) {
      spin<8>(&sb->Z[t], 1u);
      for (int i = tid; i < kB * kZ; i += 256) shf[i] = aldf(&ws->z1n[t & 1][0][0] + i);
      __syncthreads();
      if (tid == 0) relfetchadd(&sb->zread[t].v);
      unsigned fk0, fk1;
      tf2x32(0u, 1234u, 0u, (unsigned)t, fk0, fk1);
      float lv[kB] = {0.f, 0.f, 0.f, 0.f};
      if (act) {
        const float* wr = W_fc2 + (size_t)row * kZ;
        const float bb = b_fc2[row];
        float a0 = bb, a1 = bb, a2 = bb, a3 = bb;
        for (int k = 0; k < kZ; k += 4) {
          const float4 wv = *reinterpret_cast<const float4*>(wr + k);
          const float4 z0 = *reinterpret_cast<const float4*>(&shf[0 * kZ + k]);
          const float4 z1 = *reinterpret_cast<const float4*>(&shf[1 * kZ + k]);
          const float4 z2 = *reinterpret_cast<const float4*>(&shf[2 * kZ + k]);
          const float4 z3 = *reinterpret_cast<const float4*>(&shf[3 * kZ + k]);
          a0 = fmaf(z0.x, wv.x, a0); a0 = fmaf(z0.y, wv.y, a0); a0 = fmaf(z0.z, wv.z, a0); a0 = fmaf(z0.w, wv.w, a0);
          a1 = fmaf(z1.x, wv.x, a1); a1 = fmaf(z1.y, wv.y, a1); a1 = fmaf(z1.z, wv.z, a1); a1 = fmaf(z1.w, wv.w, a1);
          a2 = fmaf(z2.x, wv.x, a2); a2 = fmaf(z2.y, wv.y, a2); a2 = fmaf(z2.z, wv.z, a2); a2 = fmaf(z2.w, wv.w, a2);
          a3 = fmaf(z3.x, wv.x, a3); a3 = fmaf(z3.y, wv.y, a3); a3 = fmaf(z3.z, wv.z, a3); a3 = fmaf(z3.w, wv.w, a3);
        }
        lv[0] = a0; lv[1] = a1; lv[2] = a2; lv[3] = a3;
      }
      // single pass: argmax(l+g) key + sum(exp(l))  (|l| ~ 5 -> no overflow)
#pragma unroll
      for (int b = 0; b < kB; ++b) {
        unsigned long long key = 0ull;
        float sv = 0.f;
        if (act) {
          const unsigned bits = rbits(fk0, fk1, (unsigned)(b * kV + row));
          const float pv = lv[b] + gumbel_from_bits(bits);
          key = ((unsigned long long)ordkey(pv) << 32) |
                (unsigned long long)(0xFFFFFFFFu - (unsigned)row);
          sv = expf(lv[b]);
        }
#pragma unroll
        for (int m = 1; m < 64; m <<= 1) {
          const unsigned long long ko = shflx64(key, m);
          sv += __shfl_xor(sv, m, 64);
          if (ko > key) key = ko;
        }
        if ((tid & 63) == 0) { shk[(tid >> 6) * kB + b] = key; shf[1408 + (tid >> 6) * kB + b] = sv; }
      }
      __syncthreads();
      if (tid == 0) {
#pragma unroll
        for (int b = 0; b < kB; ++b) {
          unsigned long long key = shk[b];
          float s = shf[1408 + b];
          for (int w2 = 1; w2 < 4; ++w2) {
            const unsigned long long ko = shk[w2 * kB + b];
            if (ko > key) key = ko;
            s += shf[1408 + w2 * kB + b];
          }
          __hip_atomic_fetch_max(&sb->argkey[t][b].v, key, __ATOMIC_RELAXED, __HIP_MEMORY_SCOPE_AGENT);
          __hip_atomic_fetch_add(&sb->psum8[t][gi & 7].v[b], s, __ATOMIC_RELAXED, __HIP_MEMORY_SCOPE_AGENT);
        }
        relfetchadd(&sb->ctrB[t].v);
      }
      // px0 duty: 16 WGs x 64 gate-rows, behind leader's Etok
      if (gi < NPX && t < kT - 1) {
        spin<1>(&sb->Etok[t], 1u);
        for (int i = tid; i < kB * kH; i += 256) shf[i] = aldf(&ws->xcur[0][0] + i);
        __syncthreads();
        {
          const int rowg = gi * 64 + (tid & 63), b = tid >> 6;
          const float* wr = decWih + (size_t)rowg * kH;   // layer-0 Wih
          const float* xz = &shf[b * kH];
          float acc = 0.f;
          for (int k = 0; k < kH; k += 4) {
            const float4 wv = *reinterpret_cast<const float4*>(wr + k);
            const float4 xv = *reinterpret_cast<const float4*>(xz + k);
            acc = fmaf(xv.x, wv.x, acc); acc = fmaf(xv.y, wv.y, acc);
            acc = fmaf(xv.z, wv.z, acc); acc = fmaf(xv.w, wv.w, acc);
          }
          astf(&ws->px0[t][0][0] + (size_t)b * kG + rowg, acc);
        }
        __syncthreads();
        if (tid == 0) relfetchadd(&sb->Ptok[t].v);
      }
      __syncthreads();   // protect shf reuse across iterations
    }
  }
}

} // namespace s2sr

extern "C" void kernel_launch(void* const* d_in, const int* in_sizes, int n_in,
                              void* d_out, int out_size, void* d_ws, size_t ws_size,
                              hipStream_t stream) {
  using namespace s2sr;
  (void)in_sizes; (void)n_in; (void)out_size;
  if (ws_size < sizeof(WS)) return;
  const int*   input_ids = (const int*)d_in[0];
  // d_in[1] = attention_mask (unused)
  const float* labels    = (const float*)d_in[2];
  const float* emb       = (const float*)d_in[3];
  const float* W_e2e     = (const float*)d_in[4];
  const float* b_e2e     = (const float*)d_in[5];
  const float* W_e2d     = (const float*)d_in[6];
  const float* b_e2d     = (const float*)d_in[7];
  const float* encWih    = (const float*)d_in[8];
  const float* encWhh    = (const float*)d_in[9];
  const float* encbih    = (const float*)d_in[10];
  const float* encbhh    = (const float*)d_in[11];
  const float* decWih    = (const float*)d_in[12];
  const float* decWhh    = (const float*)d_in[13];
  const float* decbih    = (const float*)d_in[14];
  const float* decbhh    = (const float*)d_in[15];
  const float* W_cls     = (const float*)d_in[16];
  const float* b_cls     = (const float*)d_in[17];
  const float* W_fc1     = (const float*)d_in[18];
  const float* b_fc1     = (const float*)d_in[19];
  const float* ln_g      = (const float*)d_in[20];
  const float* ln_b      = (const float*)d_in[21];
  const float* W_fc2     = (const float*)d_in[22];
  const float* b_fc2     = (const float*)d_in[23];

  // re-arm flags + zero initial LSTM state (head of WS only)
  hipMemsetAsync(d_ws, 0, (size_t)offsetof(WS, px0), stream);
  hipLaunchKernelGGL(s2s_kernel, dim3(NWG), dim3(TPB), 0, stream,
      input_ids, labels, emb, W_e2e, b_e2e, W_e2d, b_e2d,
      encWih, encWhh, encbih, encbhh, decWih, decWhh, decbih, decbhh,
      W_cls, b_cls, W_fc1, b_fc1, ln_g, ln_b, W_fc2, b_fc2,
      (float*)d_out, (WS*)d_ws);
}

// Round 5
// 8574.373 us; speedup vs baseline: 3.4166x; 1.0624x over previous
//
#include <hip/hip_runtime.h>
#include <stdint.h>
#include <stddef.h>
#include <math.h>

// ============================================================================
// Seq2SeqReinforce — persistent kernel, round 5.
// Changes vs round 4 (same proven agent-scope primitives, leaner protocol):
//  - cluster barrier = per-WG tag lines (release store + poll 32 lines);
//    NO atomics anywhere on the tick path.
//  - scan-boundary merge: each scan's last l1 rides the next scan's first tick;
//    fc1+LN moved to the leader (cluster publishes hz at boundary ticks).
//  - sampling path: per-gang-WG output lines {key[4], psum[4], tag} — no
//    atomicMax/atomicAdd/ctrB chains; leader polls 223 lines and tree-reduces.
//  - idle pollers (gang on zT, px on eT) use long s_sleep backoff.
// ============================================================================

#define PARTITIONABLE_PRNG 1   // bit-exact vs JAX, confirmed rounds 1-4

namespace s2sr {

constexpr int kV = 50257, kE = 256, kH = 256, kCc = 64, kB = 4, kT = 48;
constexpr int kZ = kH + kCc;   // 320
constexpr int kG = 4 * kH;     // 1024
constexpr int kMask = 103;
constexpr float kEps = 1e-5f;
constexpr float kTiny = 1.17549435e-38f;

constexpr int NWG = 256, TPB = 256;
constexpr int NCL = 32;                        // cluster WGs
constexpr int LEAD = 32;
constexpr int GANG0 = 33;
constexpr int NGANG = NWG - GANG0;             // 223
constexpr int RPW = (kV + NGANG - 1) / NGANG;  // 226 rows/WG
constexpr int NPX = 16;                        // gang WGs doing px0 duty

// LDS float offsets (cluster tick layout)
constexpr int SH_H0 = 0;      // 1024: staged h0prev  [b][256]
constexpr int SH_H1 = 1024;   // 1024: staged h1prev2 [b][256]
constexpr int SH_P0 = 2048;   // 1024: l0 partials
constexpr int SH_P1 = 3072;   // 1024: l1 partials
constexpr int SH_Z  = 4096;   // 256:  z rows
constexpr int SH_TOT = 4608;
// leader LDS offsets
constexpr int LD_ZIN = 0;     // 1280: fc1 input [b][320]
constexpr int LD_Z1  = 1280;  // 1280: fc1 out / LN result
constexpr int LD_CLS = 2560;  // 256:  cls cache [b][64]
constexpr int LD_LSE = 2816;  // 4
constexpr int LD_WPS = 2820;  // 16: wave psum partials

struct alignas(128) Tag { unsigned v; unsigned _p[31]; };
struct alignas(128) GOut {
  unsigned long long key[kB];  // 32B
  float ps[kB];                // 16B
  unsigned tag;                // 4B
  unsigned _p[19];
};

struct SyncBlk {
  Tag ictr, igen;        // init barrier (RMW; init only)
  Tag ctag[NCL];         // cluster tick tags (monotonic ep)
  Tag ptok[NPX];         // px0 ready tags (value t)
  Tag hzT;               // hz ready (value t)
  Tag zT;                // z1n ready (value t)
  Tag eT;                // xcur ready (value t)
  GOut gout[NGANG];      // per-gang-WG sampling outputs
};

struct WS {
  // ---- zeroed head (memset each launch) ----
  SyncBlk s;
  float h0buf[2][kB][kH];
  float h1buf[2][kB][kH];
  // ---- not zeroed (written before read, gated by tags) ----
  float hz[2][kB][kH];      // scan-boundary h1 for leader fc1
  float z1n[2][kB][kZ];
  float xcur[kB][kH];
  float xd0[kB][kH];
  float px0[kT][kB][kG];
  float pxe[kT][kB][kG];
};

// ---------------- agent-scope helpers (LLC) ----------------
__device__ __forceinline__ float aldf(const float* p) {
  return __hip_atomic_load(p, __ATOMIC_RELAXED, __HIP_MEMORY_SCOPE_AGENT);
}
__device__ __forceinline__ void astf(float* p, float v) {
  __hip_atomic_store(p, v, __ATOMIC_RELAXED, __HIP_MEMORY_SCOPE_AGENT);
}
__device__ __forceinline__ unsigned ldu(const unsigned* p) {
  return __hip_atomic_load(p, __ATOMIC_RELAXED, __HIP_MEMORY_SCOPE_AGENT);
}
__device__ __forceinline__ void relTag(Tag* tg, unsigned v) {
  __hip_atomic_store(&tg->v, v, __ATOMIC_RELEASE, __HIP_MEMORY_SCOPE_AGENT);
}
template <int SLP>
__device__ __forceinline__ void spinTag(Tag* tg, unsigned tgt) {
  if (threadIdx.x == 0) {
    while (ldu(&tg->v) < tgt) __builtin_amdgcn_s_sleep(SLP);
    __atomic_signal_fence(__ATOMIC_ACQUIRE);
  }
  __syncthreads();
}
// cluster tick barrier: release own tag, poll all 32 tag lines
__device__ __forceinline__ void cbar(SyncBlk* sb, unsigned& ep, int cw) {
  __syncthreads();                       // drains each wave's stores
  ep += 1u;
  const int tid = (int)threadIdx.x;
  if (tid == 0) relTag(&sb->ctag[cw], ep);
  if (tid < NCL) {
    while (ldu(&sb->ctag[tid].v) < ep) {}
    __atomic_signal_fence(__ATOMIC_ACQUIRE);
  }
  __syncthreads();
}
// wait for all 16 px tags >= tgt
__device__ __forceinline__ void wait_ptok(SyncBlk* sb, unsigned tgt) {
  if (threadIdx.x < NPX) {
    while (ldu(&sb->ptok[threadIdx.x].v) < tgt) {}
    __atomic_signal_fence(__ATOMIC_ACQUIRE);
  }
  __syncthreads();
}
// init barrier (RMW; used twice at startup only)
__device__ __forceinline__ void gbar(SyncBlk* sb, unsigned tgt) {
  __syncthreads();
  if (threadIdx.x == 0) {
    const unsigned old = __hip_atomic_fetch_add(&sb->ictr.v, 1u, __ATOMIC_RELEASE,
                                                __HIP_MEMORY_SCOPE_AGENT);
    if (old == tgt - 1u) relTag(&sb->igen, tgt);
    while (ldu(&sb->igen.v) < tgt) __builtin_amdgcn_s_sleep(2);
    __atomic_signal_fence(__ATOMIC_ACQUIRE);
  }
  __syncthreads();
}

// ---------------- Threefry2x32 (bit-exact vs JAX; validated) ----------------
__device__ __forceinline__ unsigned rotl32(unsigned v, int n) {
  return (v << n) | (v >> (32 - n));
}
__device__ __forceinline__ void tf2x32(unsigned k0, unsigned k1, unsigned x0, unsigned x1,
                                       unsigned& o0, unsigned& o1) {
  const unsigned k2 = k0 ^ k1 ^ 0x1BD11BDAu;
  unsigned v0 = x0 + k0, v1 = x1 + k1;
  v0 += v1; v1 = rotl32(v1, 13); v1 ^= v0;
  v0 += v1; v1 = rotl32(v1, 15); v1 ^= v0;
  v0 += v1; v1 = rotl32(v1, 26); v1 ^= v0;
  v0 += v1; v1 = rotl32(v1, 6);  v1 ^= v0;
  v0 += k1; v1 += k2 + 1u;
  v0 += v1; v1 = rotl32(v1, 17); v1 ^= v0;
  v0 += v1; v1 = rotl32(v1, 29); v1 ^= v0;
  v0 += v1; v1 = rotl32(v1, 16); v1 ^= v0;
  v0 += v1; v1 = rotl32(v1, 24); v1 ^= v0;
  v0 += k2; v1 += k0 + 2u;
  v0 += v1; v1 = rotl32(v1, 13); v1 ^= v0;
  v0 += v1; v1 = rotl32(v1, 15); v1 ^= v0;
  v0 += v1; v1 = rotl32(v1, 26); v1 ^= v0;
  v0 += v1; v1 = rotl32(v1, 6);  v1 ^= v0;
  v0 += k0; v1 += k1 + 3u;
  v0 += v1; v1 = rotl32(v1, 17); v1 ^= v0;
  v0 += v1; v1 = rotl32(v1, 29); v1 ^= v0;
  v0 += v1; v1 = rotl32(v1, 16); v1 ^= v0;
  v0 += v1; v1 = rotl32(v1, 24); v1 ^= v0;
  v0 += k1; v1 += k2 + 4u;
  v0 += v1; v1 = rotl32(v1, 13); v1 ^= v0;
  v0 += v1; v1 = rotl32(v1, 15); v1 ^= v0;
  v0 += v1; v1 = rotl32(v1, 26); v1 ^= v0;
  v0 += v1; v1 = rotl32(v1, 6);  v1 ^= v0;
  o0 = v0 + k2; o1 = v1 + k0 + 5u;
}
__device__ __forceinline__ unsigned rbits(unsigned k0, unsigned k1, unsigned i) {
#if PARTITIONABLE_PRNG
  unsigned a, b; tf2x32(k0, k1, 0u, i, a, b);
  return a ^ b;
#else
  constexpr unsigned HALF = (unsigned)((kB * kV + 1) / 2);
  unsigned a, b;
  if (i < HALF) { tf2x32(k0, k1, i, i + HALF, a, b); return a; }
  tf2x32(k0, k1, i - HALF, i, a, b); return b;
#endif
}
__device__ __forceinline__ float gumbel_from_bits(unsigned bits) {
  float f = __uint_as_float((bits >> 9) | 0x3f800000u) - 1.0f;
  f = fmaxf(f, kTiny);
  return -logf(-logf(f));
}
__device__ __forceinline__ unsigned ordkey(float f) {
  const unsigned u = __float_as_uint(f);
  return (u & 0x80000000u) ? ~u : (u | 0x80000000u);
}
__device__ __forceinline__ unsigned long long shflx64(unsigned long long v, int m) {
  unsigned lo = (unsigned)v, hi = (unsigned)(v >> 32);
  lo = (unsigned)__shfl_xor((int)lo, m, 64);
  hi = (unsigned)__shfl_xor((int)hi, m, 64);
  return ((unsigned long long)hi << 32) | (unsigned long long)lo;
}
__device__ __forceinline__ float sigm(float x) { return 1.0f / (1.0f + expf(-x)); }

// ---------------- merged LSTM tick (round-4 math; tag barrier; hz publish) --
template <bool STREAM>
__device__ __forceinline__ void lstm_tick(
    SyncBlk* sb, WS* ws, float* shf, int cw, unsigned& ep, int cc,
    bool do_l0, bool do_l1, const float* px,
    const float* pW0, const float* pW1,
    const float4* w0r, const float4* w1r,
    float biasr, float& c0, float& c1, int grow, int r, int w, int hzt) {
  const int tid = (int)threadIdx.x;
  float pxv0 = 0.f, pxv1 = 0.f, pxv2 = 0.f, pxv3 = 0.f;
  if (do_l0 && tid < 32) {
    pxv0 = aldf(px + 0 * kG + grow);
    pxv1 = aldf(px + 1 * kG + grow);
    pxv2 = aldf(px + 2 * kG + grow);
    pxv3 = aldf(px + 3 * kG + grow);
  }
  {
    const float* h0p = &ws->h0buf[(cc + 1) & 1][0][0];
#pragma unroll
    for (int i = 0; i < 4; ++i) shf[SH_H0 + tid + i * 256] = aldf(h0p + tid + i * 256);
    if (do_l1) {
      const float* h1p = &ws->h1buf[cc & 1][0][0];
#pragma unroll
      for (int i = 0; i < 4; ++i) shf[SH_H1 + tid + i * 256] = aldf(h1p + tid + i * 256);
    }
  }
  __syncthreads();
  float4 wv0[8], wv1[16];
  if (do_l0) {
#pragma unroll
    for (int i = 0; i < 8; ++i)
      wv0[i] = STREAM ? *reinterpret_cast<const float4*>(pW0 + i * 4) : w0r[i];
  }
  if (do_l1) {
#pragma unroll
    for (int i = 0; i < 16; ++i)
      wv1[i] = STREAM ? *reinterpret_cast<const float4*>(pW1 + i * 4) : w1r[i];
  }
  if (do_l0) {
    const float* A = &shf[SH_H0 + w * 32];
    float a0 = 0.f, a1 = 0.f, a2 = 0.f, a3 = 0.f;
#pragma unroll
    for (int i = 0; i < 8; ++i) {
      const float4 wv = wv0[i];
      const float4 x0 = *reinterpret_cast<const float4*>(A + 0 * 256 + i * 4);
      const float4 x1 = *reinterpret_cast<const float4*>(A + 1 * 256 + i * 4);
      const float4 x2 = *reinterpret_cast<const float4*>(A + 2 * 256 + i * 4);
      const float4 x3 = *reinterpret_cast<const float4*>(A + 3 * 256 + i * 4);
      a0 = fmaf(wv.x, x0.x, a0); a0 = fmaf(wv.y, x0.y, a0); a0 = fmaf(wv.z, x0.z, a0); a0 = fmaf(wv.w, x0.w, a0);
      a1 = fmaf(wv.x, x1.x, a1); a1 = fmaf(wv.y, x1.y, a1); a1 = fmaf(wv.z, x1.z, a1); a1 = fmaf(wv.w, x1.w, a1);
      a2 = fmaf(wv.x, x2.x, a2); a2 = fmaf(wv.y, x2.y, a2); a2 = fmaf(wv.z, x2.z, a2); a2 = fmaf(wv.w, x2.w, a2);
      a3 = fmaf(wv.x, x3.x, a3); a3 = fmaf(wv.y, x3.y, a3); a3 = fmaf(wv.z, x3.z, a3); a3 = fmaf(wv.w, x3.w, a3);
    }
    *reinterpret_cast<float4*>(&shf[SH_P0 + w * 128 + r * 4]) = float4{a0, a1, a2, a3};
  }
  if (do_l1) {
    const float* Bp = (w < 4) ? &shf[SH_H0 + w * 64] : &shf[SH_H1 + (w - 4) * 64];
    float a0 = 0.f, a1 = 0.f, a2 = 0.f, a3 = 0.f;
#pragma unroll
    for (int i = 0; i < 16; ++i) {
      const float4 wv = wv1[i];
      const float4 x0 = *reinterpret_cast<const float4*>(Bp + 0 * 256 + i * 4);
      const float4 x1 = *reinterpret_cast<const float4*>(Bp + 1 * 256 + i * 4);
      const float4 x2 = *reinterpret_cast<const float4*>(Bp + 2 * 256 + i * 4);
      const float4 x3 = *reinterpret_cast<const float4*>(Bp + 3 * 256 + i * 4);
      a0 = fmaf(wv.x, x0.x, a0); a0 = fmaf(wv.y, x0.y, a0); a0 = fmaf(wv.z, x0.z, a0); a0 = fmaf(wv.w, x0.w, a0);
      a1 = fmaf(wv.x, x1.x, a1); a1 = fmaf(wv.y, x1.y, a1); a1 = fmaf(wv.z, x1.z, a1); a1 = fmaf(wv.w, x1.w, a1);
      a2 = fmaf(wv.x, x2.x, a2); a2 = fmaf(wv.y, x2.y, a2); a2 = fmaf(wv.z, x2.z, a2); a2 = fmaf(wv.w, x2.w, a2);
      a3 = fmaf(wv.x, x3.x, a3); a3 = fmaf(wv.y, x3.y, a3); a3 = fmaf(wv.z, x3.z, a3); a3 = fmaf(wv.w, x3.w, a3);
    }
    *reinterpret_cast<float4*>(&shf[SH_P1 + w * 128 + r * 4]) = float4{a0, a1, a2, a3};
  }
  __syncthreads();
  if (tid < 64) {
    const int L = tid >> 5, rr = tid & 31;
    const bool en = L ? do_l1 : do_l0;
    if (en) {
      const int base = (L ? SH_P1 : SH_P0) + rr * 4;
      float4 z = float4{0.f, 0.f, 0.f, 0.f};
#pragma unroll
      for (int w2 = 0; w2 < 8; ++w2) {
        const float4 p = *reinterpret_cast<const float4*>(&shf[base + w2 * 128]);
        z.x += p.x; z.y += p.y; z.z += p.z; z.w += p.w;
      }
      z.x += biasr; z.y += biasr; z.z += biasr; z.w += biasr;
      if (L == 0) { z.x += pxv0; z.y += pxv1; z.z += pxv2; z.w += pxv3; }
      *reinterpret_cast<float4*>(&shf[SH_Z + L * 128 + rr * 4]) = z;
    }
  }
  __syncthreads();
  if (tid < 64) {
    const int L = tid >> 5, slot = tid & 31;
    const bool en = L ? do_l1 : do_l0;
    if (en) {
      const int b = slot >> 3, u = slot & 7;
      const int zb = SH_Z + L * 128 + u * 16 + b;
      const float zi = shf[zb], zf = shf[zb + 4], zg = shf[zb + 8], zo = shf[zb + 12];
      const float cs = L ? c1 : c0;
      const float cn = sigm(zf) * cs + sigm(zi) * tanhf(zg);
      const float hn = sigm(zo) * tanhf(cn);
      if (L) {
        c1 = cn;
        astf(&ws->h1buf[(cc + 1) & 1][b][cw * 8 + u], hn);
        if (hzt >= 0) astf(&ws->hz[hzt & 1][b][cw * 8 + u], hn);
      } else {
        c0 = cn;
        astf(&ws->h0buf[cc & 1][b][cw * 8 + u], hn);
      }
    }
  }
  cbar(sb, ep, cw);
}

// ---------------- kernel ----------------
__global__ void __launch_bounds__(TPB, 1) s2s_kernel(
    const int* __restrict__ input_ids, const float* __restrict__ labels,
    const float* __restrict__ emb,
    const float* __restrict__ W_e2e, const float* __restrict__ b_e2e,
    const float* __restrict__ W_e2d, const float* __restrict__ b_e2d,
    const float* __restrict__ encWih, const float* __restrict__ encWhh,
    const float* __restrict__ encbih, const float* __restrict__ encbhh,
    const float* __restrict__ decWih, const float* __restrict__ decWhh,
    const float* __restrict__ decbih, const float* __restrict__ decbhh,
    const float* __restrict__ W_cls, const float* __restrict__ b_cls,
    const float* __restrict__ Wfc1, const float* __restrict__ bfc1,
    const float* __restrict__ lng, const float* __restrict__ lnb,
    const float* __restrict__ W_fc2, const float* __restrict__ b_fc2,
    float* __restrict__ out, WS* __restrict__ ws) {
  const int wg = (int)blockIdx.x;
  const int tid = (int)threadIdx.x;
  SyncBlk* sb = &ws->s;
  __shared__ __align__(16) float shf[SH_TOT];
  __shared__ unsigned long long shk[16];
  __shared__ int shi[8];

  // ================= init phase 1 =================
  if (wg < kB * kT) {
    const int b = wg / kT, j = wg % kT;
    const int id = input_ids[b * kT + j];
    for (int i = tid; i < kE; i += 256) shf[i] = emb[(size_t)id * kE + i];
    __syncthreads();
    const float* wr = W_e2e + (size_t)tid * kE;
    float acc = b_e2e[tid];
    for (int k = 0; k < kE; k += 4) {
      const float4 wv = *reinterpret_cast<const float4*>(wr + k);
      const float4 xv = *reinterpret_cast<const float4*>(&shf[k]);
      acc = fmaf(xv.x, wv.x, acc); acc = fmaf(xv.y, wv.y, acc);
      acc = fmaf(xv.z, wv.z, acc); acc = fmaf(xv.w, wv.w, acc);
    }
    __syncthreads();
    shf[256 + tid] = fmaxf(acc, 0.f);
  } else if (wg == 192) {
    if (tid < kB) {
      const int t0 = input_ids[tid * kT];
      out[tid * kT] = 0.f;
      out[kB * kT + tid * kT] = (float)t0;
    }
  } else if (wg == 193) {
    const float* wr = W_e2d + (size_t)tid * kE;
    const float* e0 = emb + (size_t)input_ids[0 * kT] * kE;
    const float* e1 = emb + (size_t)input_ids[1 * kT] * kE;
    const float* e2 = emb + (size_t)input_ids[2 * kT] * kE;
    const float* e3 = emb + (size_t)input_ids[3 * kT] * kE;
    const float bb = b_e2d[tid];
    float a0 = bb, a1 = bb, a2 = bb, a3 = bb;
    for (int k = 0; k < kE; k += 4) {
      const float4 wv = *reinterpret_cast<const float4*>(wr + k);
      const float4 v0 = *reinterpret_cast<const float4*>(e0 + k);
      const float4 v1 = *reinterpret_cast<const float4*>(e1 + k);
      const float4 v2 = *reinterpret_cast<const float4*>(e2 + k);
      const float4 v3 = *reinterpret_cast<const float4*>(e3 + k);
      a0 = fmaf(v0.x, wv.x, a0); a0 = fmaf(v0.y, wv.y, a0); a0 = fmaf(v0.z, wv.z, a0); a0 = fmaf(v0.w, wv.w, a0);
      a1 = fmaf(v1.x, wv.x, a1); a1 = fmaf(v1.y, wv.y, a1); a1 = fmaf(v1.z, wv.z, a1); a1 = fmaf(v1.w, wv.w, a1);
      a2 = fmaf(v2.x, wv.x, a2); a2 = fmaf(v2.y, wv.y, a2); a2 = fmaf(v2.z, wv.z, a2); a2 = fmaf(v2.w, wv.w, a2);
      a3 = fmaf(v3.x, wv.x, a3); a3 = fmaf(v3.y, wv.y, a3); a3 = fmaf(v3.z, wv.z, a3); a3 = fmaf(v3.w, wv.w, a3);
    }
    astf(&ws->xd0[0][tid], fmaxf(a0, 0.f));
    astf(&ws->xd0[1][tid], fmaxf(a1, 0.f));
    astf(&ws->xd0[2][tid], fmaxf(a2, 0.f));
    astf(&ws->xd0[3][tid], fmaxf(a3, 0.f));
  }
  gbar(sb, (unsigned)NWG);

  // ================= init phase 2 =================
  if (wg < kB * kT) {
    const int b = wg / kT, j = wg % kT;
#pragma unroll
    for (int rr = 0; rr < 4; ++rr) {
      const int g = rr * 256 + tid;
      const float* wr = encWih + (size_t)g * kH;
      float acc = 0.f;
      for (int k = 0; k < kH; k += 4) {
        const float4 wv = *reinterpret_cast<const float4*>(wr + k);
        const float4 xv = *reinterpret_cast<const float4*>(&shf[256 + k]);
        acc = fmaf(xv.x, wv.x, acc); acc = fmaf(xv.y, wv.y, acc);
        acc = fmaf(xv.z, wv.z, acc); acc = fmaf(xv.w, wv.w, acc);
      }
      astf(&ws->pxe[j][0][0] + (size_t)b * kG + g, acc);
    }
  } else if (wg >= 192 && wg < 208) {
    const int w2 = wg - 192, b = w2 >> 2, q = w2 & 3;
    const int g = q * 256 + tid;
    for (int i = tid; i < kH; i += 256) shf[i] = aldf(&ws->xd0[b][i]);
    __syncthreads();
    const float* wr = decWih + (size_t)g * kH;
    float acc = 0.f;
    for (int k = 0; k < kH; k += 4) {
      const float4 wv = *reinterpret_cast<const float4*>(wr + k);
      const float4 xv = *reinterpret_cast<const float4*>(&shf[k]);
      acc = fmaf(xv.x, wv.x, acc); acc = fmaf(xv.y, wv.y, acc);
      acc = fmaf(xv.z, wv.z, acc); acc = fmaf(xv.w, wv.w, acc);
    }
    astf(&ws->px0[0][0][0] + (size_t)b * kG + g, acc);
  }
  gbar(sb, (unsigned)(2 * NWG));

  // ================= roles =================
  if (wg < NCL) {
    // ---------------- cluster ----------------
    const int cw = wg;
    const int r = tid & 31, w = tid >> 5;
    const int grow = (r & 3) * 256 + cw * 8 + (r >> 2);
    const int L = tid >> 5;
    unsigned ep = 0;
    float c0 = 0.f, c1 = 0.f;
    float biasr = 0.f;
    if (tid < 64)
      biasr = (L == 0) ? encbih[grow] + encbhh[grow]
                       : encbih[kG + grow] + encbhh[kG + grow];
    const float* pW0e = encWhh + (size_t)grow * kH + w * 32;
    const float* pW1e = (w < 4)
        ? encWih + (size_t)kG * kH + (size_t)grow * kH + w * 64
        : encWhh + (size_t)kG * kH + (size_t)grow * kH + (w - 4) * 64;
    int cc = 0;
    // encoder
    for (int j = 0; j < kT; ++j, ++cc)
      lstm_tick<true>(sb, ws, shf, cw, ep, cc, true, j > 0, &ws->pxe[j][0][0],
                      pW0e, pW1e, nullptr, nullptr, biasr, c0, c1, grow, r, w, -1);
    // enc trailing l1 (cell 47); shares cc with scan 1's first tick
    lstm_tick<true>(sb, ws, shf, cw, ep, cc, false, true, nullptr,
                    pW0e, pW1e, nullptr, nullptr, biasr, c0, c1, grow, r, w, -1);
    // decoder weights -> registers
    float4 w0d[8], w1d[16];
    {
      const float* p0 = decWhh + (size_t)grow * kH + w * 32;
#pragma unroll
      for (int i = 0; i < 8; ++i) w0d[i] = *reinterpret_cast<const float4*>(p0 + i * 4);
      const float* p1 = (w < 4)
          ? decWih + (size_t)kG * kH + (size_t)grow * kH + w * 64
          : decWhh + (size_t)kG * kH + (size_t)grow * kH + (w - 4) * 64;
#pragma unroll
      for (int i = 0; i < 16; ++i) w1d[i] = *reinterpret_cast<const float4*>(p1 + i * 4);
      if (tid < 64)
        biasr = (L == 0) ? decbih[grow] + decbhh[grow]
                         : decbih[kG + grow] + decbhh[kG + grow];
    }
    // decoder scans (scan t's first tick carries scan t-1's last l1 + hz)
    for (int t = 1; t < kT; ++t) {
      for (int j = 0; j < t; ++j, ++cc) {
        const bool d1 = (j > 0) || (t >= 2);
        const int hzt = (j == 0 && t >= 2) ? (t - 1) : -1;
        if (j == t - 1 && t >= 2) wait_ptok(sb, (unsigned)(t - 1));
        lstm_tick<false>(sb, ws, shf, cw, ep, cc, true, d1, &ws->px0[j][0][0],
                         nullptr, nullptr, w0d, w1d, biasr, c0, c1, grow, r, w, hzt);
        if (hzt >= 0 && cw == 0 && tid == 0) relTag(&sb->hzT, (unsigned)hzt);
      }
    }
    // final trailing l1 (scan 47's last cell) -> hz[47&1]
    lstm_tick<false>(sb, ws, shf, cw, ep, cc, false, true, nullptr,
                     nullptr, nullptr, w0d, w1d, biasr, c0, c1, grow, r, w, kT - 1);
    if (cw == 0 && tid == 0) relTag(&sb->hzT, (unsigned)(kT - 1));
  } else if (wg == LEAD) {
    // ---------------- leader: fc1 + LN + sample + embed ----------------
    if (tid < kB * kCc) {
      const int b = tid >> 6, c = tid & 63;
      shf[LD_CLS + tid] = fmaf(labels[b], W_cls[c], b_cls[c]);
    }
    __syncthreads();
    for (int t = 1; t < kT; ++t) {
      spinTag<1>(&sb->hzT, (unsigned)t);
      // stage fc1 input z = [hz[t&1], cls]
      for (int i = tid; i < kB * kZ; i += 256) {
        const int b = i / kZ, k = i - b * kZ;
        shf[LD_ZIN + i] = (k < kH) ? aldf(&ws->hz[t & 1][b][k])
                                   : shf[LD_CLS + b * kCc + (k - kH)];
      }
      __syncthreads();
      // fc1 (+relu): 1280 outputs, 5 per thread
#pragma unroll
      for (int rep = 0; rep < 5; ++rep) {
        const int task = tid + rep * 256;
        const int b = task / kZ, o = task - b * kZ;
        const float* wr = Wfc1 + (size_t)o * kZ;
        const float* zz = &shf[LD_ZIN + b * kZ];
        float acc = bfc1[o];
        for (int k = 0; k < kZ; k += 4) {
          const float4 wv = *reinterpret_cast<const float4*>(wr + k);
          const float4 zv = *reinterpret_cast<const float4*>(zz + k);
          acc = fmaf(zv.x, wv.x, acc); acc = fmaf(zv.y, wv.y, acc);
          acc = fmaf(zv.z, wv.z, acc); acc = fmaf(zv.w, wv.w, acc);
        }
        shf[LD_Z1 + task] = fmaxf(acc, 0.f);
      }
      __syncthreads();
      {  // LayerNorm per batch (wave b), publish z1n
        const int b = tid >> 6, ln = tid & 63;
        float s1 = 0.f, s2 = 0.f;
        for (int i = ln; i < kZ; i += 64) {
          const float v = shf[LD_Z1 + b * kZ + i]; s1 += v; s2 += v * v;
        }
#pragma unroll
        for (int o = 32; o > 0; o >>= 1) { s1 += __shfl_xor(s1, o, 64); s2 += __shfl_xor(s2, o, 64); }
        const float mu = s1 * (1.0f / kZ);
        const float var = s2 * (1.0f / kZ) - mu * mu;
        const float rs = 1.0f / sqrtf(var + kEps);
        for (int i = ln; i < kZ; i += 64) {
          const float v = fmaf((shf[LD_Z1 + b * kZ + i] - mu) * rs, lng[i], lnb[i]);
          shf[LD_Z1 + b * kZ + i] = v;
          astf(&ws->z1n[t & 1][b][i], v);
        }
      }
      __syncthreads();
      if (tid == 0) relTag(&sb->zT, (unsigned)t);
      // wait all gang outputs for step t
      if (tid < NGANG) {
        while (ldu(&sb->gout[tid].tag) < (unsigned)t) __builtin_amdgcn_s_sleep(2);
        __atomic_signal_fence(__ATOMIC_ACQUIRE);
      }
      __syncthreads();
      // reduce 223 lines: per b max key, sum ps (deterministic tree)
      {
        unsigned long long kk[kB];
        float pp[kB];
        if (tid < NGANG) {
          const GOut* g = &sb->gout[tid];
#pragma unroll
          for (int b = 0; b < kB; ++b) {
            kk[b] = __hip_atomic_load(&g->key[b], __ATOMIC_RELAXED, __HIP_MEMORY_SCOPE_AGENT);
            pp[b] = aldf(&g->ps[b]);
          }
        } else {
#pragma unroll
          for (int b = 0; b < kB; ++b) { kk[b] = 0ull; pp[b] = 0.f; }
        }
#pragma unroll
        for (int b = 0; b < kB; ++b) {
#pragma unroll
          for (int m = 1; m < 64; m <<= 1) {
            const unsigned long long ko = shflx64(kk[b], m);
            pp[b] += __shfl_xor(pp[b], m, 64);
            if (ko > kk[b]) kk[b] = ko;
          }
        }
        if ((tid & 63) == 0) {
          const int wv = tid >> 6;
#pragma unroll
          for (int b = 0; b < kB; ++b) { shk[wv * kB + b] = kk[b]; shf[LD_WPS + wv * kB + b] = pp[b]; }
        }
      }
      __syncthreads();
      if (tid < kB) {
        const int b = tid;
        unsigned long long key = shk[b];
        float s = shf[LD_WPS + b];
        for (int wv = 1; wv < 4; ++wv) {
          const unsigned long long ko = shk[wv * kB + b];
          if (ko > key) key = ko;
          s += shf[LD_WPS + wv * kB + b];
        }
        const int samp = (int)(0xFFFFFFFFu - (unsigned)(key & 0xFFFFFFFFull));
        const float lse = logf(s);
        const int cur = input_ids[b * kT + t];
        const int nxt = (cur == kMask) ? samp : cur;
        out[kB * kT + b * kT + t] = (float)nxt;
        shi[b] = nxt; shi[4 + b] = samp;
        shf[LD_LSE + b] = lse;
      }
      __syncthreads();
      if (t < kT - 1) {
        // xcur = relu(emb[tok] @ W_e2d^T + b); publish; release eT
        const float* wr = W_e2d + (size_t)tid * kE;
        const float* e0 = emb + (size_t)shi[0] * kE;
        const float* e1 = emb + (size_t)shi[1] * kE;
        const float* e2 = emb + (size_t)shi[2] * kE;
        const float* e3 = emb + (size_t)shi[3] * kE;
        const float bb = b_e2d[tid];
        float a0 = bb, a1 = bb, a2 = bb, a3 = bb;
        for (int k = 0; k < kE; k += 4) {
          const float4 wv = *reinterpret_cast<const float4*>(wr + k);
          const float4 v0 = *reinterpret_cast<const float4*>(e0 + k);
          const float4 v1 = *reinterpret_cast<const float4*>(e1 + k);
          const float4 v2 = *reinterpret_cast<const float4*>(e2 + k);
          const float4 v3 = *reinterpret_cast<const float4*>(e3 + k);
          a0 = fmaf(v0.x, wv.x, a0); a0 = fmaf(v0.y, wv.y, a0); a0 = fmaf(v0.z, wv.z, a0); a0 = fmaf(v0.w, wv.w, a0);
          a1 = fmaf(v1.x, wv.x, a1); a1 = fmaf(v1.y, wv.y, a1); a1 = fmaf(v1.z, wv.z, a1); a1 = fmaf(v1.w, wv.w, a1);
          a2 = fmaf(v2.x, wv.x, a2); a2 = fmaf(v2.y, wv.y, a2); a2 = fmaf(v2.z, wv.z, a2); a2 = fmaf(v2.w, wv.w, a2);
          a3 = fmaf(v3.x, wv.x, a3); a3 = fmaf(v3.y, wv.y, a3); a3 = fmaf(v3.z, wv.z, a3); a3 = fmaf(v3.w, wv.w, a3);
        }
        astf(&ws->xcur[0][tid], fmaxf(a0, 0.f));
        astf(&ws->xcur[1][tid], fmaxf(a1, 0.f));
        astf(&ws->xcur[2][tid], fmaxf(a2, 0.f));
        astf(&ws->xcur[3][tid], fmaxf(a3, 0.f));
        __syncthreads();
        if (tid == 0) relTag(&sb->eT, (unsigned)t);
      }
      // score = logit[b][samp] - lse (LN'd z1 kept in LDS)
      {
        const int b = tid >> 6, lane = tid & 63;
        const int sp = shi[4 + b];
        const float* wr = W_fc2 + (size_t)sp * kZ;
        float acc = 0.f;
#pragma unroll
        for (int i = 0; i < 5; ++i)
          acc = fmaf(shf[LD_Z1 + b * kZ + lane + i * 64], wr[lane + i * 64], acc);
#pragma unroll
        for (int o = 32; o > 0; o >>= 1) acc += __shfl_xor(acc, o, 64);
        if (lane == 0) out[b * kT + t] = acc + b_fc2[sp] - shf[LD_LSE + b];
      }
      __syncthreads();
    }
  } else {
    // ---------------- gang ----------------
    const int gi = wg - GANG0;
    const int start = gi * RPW;
    const int cnt = (RPW < kV - start) ? RPW : (kV - start);
    const bool act = tid < cnt;
    const int row = start + tid;
    for (int t = 1; t < kT; ++t) {
      spinTag<16>(&sb->zT, (unsigned)t);
      for (int i = tid; i < kB * kZ; i += 256) shf[i] = aldf(&ws->z1n[t & 1][0][0] + i);
      __syncthreads();
      unsigned fk0, fk1;
      tf2x32(0u, 1234u, 0u, (unsigned)t, fk0, fk1);
      float lv[kB] = {0.f, 0.f, 0.f, 0.f};
      if (act) {
        const float* wr = W_fc2 + (size_t)row * kZ;
        const float bb = b_fc2[row];
        float a0 = bb, a1 = bb, a2 = bb, a3 = bb;
        for (int k = 0; k < kZ; k += 4) {
          const float4 wv = *reinterpret_cast<const float4*>(wr + k);
          const float4 z0 = *reinterpret_cast<const float4*>(&shf[0 * kZ + k]);
          const float4 z1 = *reinterpret_cast<const float4*>(&shf[1 * kZ + k]);
          const float4 z2 = *reinterpret_cast<const float4*>(&shf[2 * kZ + k]);
          const float4 z3 = *reinterpret_cast<const float4*>(&shf[3 * kZ + k]);
          a0 = fmaf(z0.x, wv.x, a0); a0 = fmaf(z0.y, wv.y, a0); a0 = fmaf(z0.z, wv.z, a0); a0 = fmaf(z0.w, wv.w, a0);
          a1 = fmaf(z1.x, wv.x, a1); a1 = fmaf(z1.y, wv.y, a1); a1 = fmaf(z1.z, wv.z, a1); a1 = fmaf(z1.w, wv.w, a1);
          a2 = fmaf(z2.x, wv.x, a2); a2 = fmaf(z2.y, wv.y, a2); a2 = fmaf(z2.z, wv.z, a2); a2 = fmaf(z2.w, wv.w, a2);
          a3 = fmaf(z3.x, wv.x, a3); a3 = fmaf(z3.y, wv.y, a3); a3 = fmaf(z3.z, wv.z, a3); a3 = fmaf(z3.w, wv.w, a3);
        }
        lv[0] = a0; lv[1] = a1; lv[2] = a2; lv[3] = a3;
      }
      // single pass: argmax(l+g) key + sum(exp(l)) (|l| small -> safe)
#pragma unroll
      for (int b = 0; b < kB; ++b) {
        unsigned long long key = 0ull;
        float sv = 0.f;
        if (act) {
          const unsigned bits = rbits(fk0, fk1, (unsigned)(b * kV + row));
          const float pv = lv[b] + gumbel_from_bits(bits);
          key = ((unsigned long long)ordkey(pv) << 32) |
                (unsigned long long)(0xFFFFFFFFu - (unsigned)row);
          sv = expf(lv[b]);
        }
#pragma unroll
        for (int m = 1; m < 64; m <<= 1) {
          const unsigned long long ko = shflx64(key, m);
          sv += __shfl_xor(sv, m, 64);
          if (ko > key) key = ko;
        }
        if ((tid & 63) == 0) { shk[(tid >> 6) * kB + b] = key; shf[1408 + (tid >> 6) * kB + b] = sv; }
      }
      __syncthreads();
      if (tid == 0) {
        GOut* g = &sb->gout[gi];
#pragma unroll
        for (int b = 0; b < kB; ++b) {
          unsigned long long key = shk[b];
          float s = shf[1408 + b];
          for (int w2 = 1; w2 < 4; ++w2) {
            const unsigned long long ko = shk[w2 * kB + b];
            if (ko > key) key = ko;
            s += shf[1408 + w2 * kB + b];
          }
          __hip_atomic_store(&g->key[b], key, __ATOMIC_RELAXED, __HIP_MEMORY_SCOPE_AGENT);
          astf(&g->ps[b], s);
        }
        __hip_atomic_store(&g->tag, (unsigned)t, __ATOMIC_RELEASE, __HIP_MEMORY_SCOPE_AGENT);
      }
      // px0 duty: 16 WGs x 64 gate-rows each, behind leader's eT
      if (gi < NPX && t < kT - 1) {
        spinTag<4>(&sb->eT, (unsigned)t);
        for (int i = tid; i < kB * kH; i += 256) shf[i] = aldf(&ws->xcur[0][0] + i);
        __syncthreads();
        {
          const int rowg = gi * 64 + (tid & 63), b = tid >> 6;
          const float* wr = decWih + (size_t)rowg * kH;
          const float* xz = &shf[b * kH];
          float acc = 0.f;
          for (int k = 0; k < kH; k += 4) {
            const float4 wv = *reinterpret_cast<const float4*>(wr + k);
            const float4 xv = *reinterpret_cast<const float4*>(xz + k);
            acc = fmaf(xv.x, wv.x, acc); acc = fmaf(xv.y, wv.y, acc);
            acc = fmaf(xv.z, wv.z, acc); acc = fmaf(xv.w, wv.w, acc);
          }
          astf(&ws->px0[t][0][0] + (size_t)b * kG + rowg, acc);
        }
        __syncthreads();
        if (tid == 0) relTag(&sb->ptok[gi], (unsigned)t);
      }
      __syncthreads();   // protect shf reuse across iterations
    }
  }
}

} // namespace s2sr

extern "C" void kernel_launch(void* const* d_in, const int* in_sizes, int n_in,
                              void* d_out, int out_size, void* d_ws, size_t ws_size,
                              hipStream_t stream) {
  using namespace s2sr;
  (void)in_sizes; (void)n_in; (void)out_size;
  if (ws_size < sizeof(WS)) return;
  const int*   input_ids = (const int*)d_in[0];
  // d_in[1] = attention_mask (unused)
  const float* labels    = (const float*)d_in[2];
  const float* emb       = (const float*)d_in[3];
  const float* W_e2e     = (const float*)d_in[4];
  const float* b_e2e     = (const float*)d_in[5];
  const float* W_e2d     = (const float*)d_in[6];
  const float* b_e2d     = (const float*)d_in[7];
  const float* encWih    = (const float*)d_in[8];
  const float* encWhh    = (const float*)d_in[9];
  const float* encbih    = (const float*)d_in[10];
  const float* encbhh    = (const float*)d_in[11];
  const float* decWih    = (const float*)d_in[12];
  const float* decWhh    = (const float*)d_in[13];
  const float* decbih    = (const float*)d_in[14];
  const float* decbhh    = (const float*)d_in[15];
  const float* W_cls     = (const float*)d_in[16];
  const float* b_cls     = (const float*)d_in[17];
  const float* W_fc1     = (const float*)d_in[18];
  const float* b_fc1     = (const float*)d_in[19];
  const float* ln_g      = (const float*)d_in[20];
  const float* ln_b      = (const float*)d_in[21];
  const float* W_fc2     = (const float*)d_in[22];
  const float* b_fc2     = (const float*)d_in[23];

  // re-arm tags + zero initial LSTM state
  hipMemsetAsync(d_ws, 0, (size_t)offsetof(WS, hz), stream);
  hipLaunchKernelGGL(s2s_kernel, dim3(NWG), dim3(TPB), 0, stream,
      input_ids, labels, emb, W_e2e, b_e2e, W_e2d, b_e2d,
      encWih, encWhh, encbih, encbhh, decWih, decWhh, decbih, decbhh,
      W_cls, b_cls, W_fc1, b_fc1, ln_g, ln_b, W_fc2, b_fc2,
      (float*)d_out, (WS*)d_ws);
}

// Round 6
// 7599.731 us; speedup vs baseline: 3.8548x; 1.1282x over previous
//
#include <hip/hip_runtime.h>
#include <stdint.h>
#include <stddef.h>
#include <math.h>

// ============================================================================
// Seq2SeqReinforce — persistent kernel, round 6: barrier-free dataflow.
//  - h-state exchange via self-validating 8B atomic chunks {seq, value}:
//    consumer spins on the chunk itself; seq==cc validates the value in the
//    SAME load. No cluster barrier, no vmcnt-drain-before-tag, no separate
//    data fetch. 2-slot parity ring is reuse-safe (dataflow bounds skew < 2).
//  - every tick publishes BOTH layers (copy-forward when a layer is idle) so
//    the expected seq is uniformly `cc`.
//  - side channels (hz / z1n / xcur / px0) use per-WAVE release tags (fixes
//    the latent multi-wave-store / single-wave-release ordering race).
// ============================================================================

#define PARTITIONABLE_PRNG 1   // bit-exact vs JAX, confirmed rounds 1-5

namespace s2sr {

constexpr int kV = 50257, kE = 256, kH = 256, kCc = 64, kB = 4, kT = 48;
constexpr int kZ = kH + kCc;   // 320
constexpr int kG = 4 * kH;     // 1024
constexpr int kMask = 103;
constexpr float kEps = 1e-5f;
constexpr float kTiny = 1.17549435e-38f;

constexpr int NWG = 256, TPB = 256;
constexpr int NCL = 32;                        // cluster WGs
constexpr int LEAD = 32;
constexpr int GANG0 = 33;
constexpr int NGANG = NWG - GANG0;             // 223
constexpr int RPW = (kV + NGANG - 1) / NGANG;  // 226 rows/WG
constexpr int NPX = 16;                        // gang WGs doing px0 duty

// LDS float offsets (cluster tick layout)
constexpr int SH_H0 = 0;      // 1024: staged h0prev  [b][256]
constexpr int SH_H1 = 1024;   // 1024: staged h1prev  [b][256]
constexpr int SH_P0 = 2048;   // 1024: l0 partials
constexpr int SH_P1 = 3072;   // 1024: l1 partials
constexpr int SH_Z  = 4096;   // 256:  z rows
constexpr int SH_TOT = 4608;
// leader LDS offsets
constexpr int LD_ZIN = 0;     // 1280: fc1 input [b][320]
constexpr int LD_Z1  = 1280;  // 1280: fc1 out / LN result
constexpr int LD_CLS = 2560;  // 256:  cls cache [b][64]
constexpr int LD_LSE = 2816;  // 4
constexpr int LD_WPS = 2820;  // 16: wave psum partials

struct alignas(128) Tag { unsigned v; unsigned _p[31]; };
struct alignas(128) GOut {
  unsigned long long key[kB];  // 32B
  float ps[kB];                // 16B
  unsigned tag;                // 4B
  unsigned _p[19];
};

struct SyncBlk {
  Tag ictr, igen;        // init barrier (RMW; init only)
  Tag ptok4[NPX][4];     // px0[t] per-wave tags (value t)
  Tag ztag4[4];          // z1n per-wave tags (value t)
  Tag etok4[4];          // xcur per-wave tags (value t)
  Tag hztag[NCL];        // hz per-cluster-WG tags (value hzt)
  GOut gout[NGANG];      // per-gang-WG sampling outputs
};

struct WS {
  // ---- zeroed head (memset each launch) ----
  SyncBlk s;
  unsigned long long hc[2][2][NCL][32];  // [slot][layer][wg][32]: {seq, float}
  float hzbuf[2][kB][kH];   // scan-boundary h1 (gated by hztag)
  float z1n[2][kB][kZ];     // LN output (gated by ztag4)
  float xcur[kB][kH];       // decoder x_t (gated by etok4)
  // ---- not zeroed (written before read, gated) ----
  float xd0[kB][kH];
  float px0[kT][kB][kG];
  float pxe[kT][kB][kG];
};

// ---------------- agent-scope helpers (LLC) ----------------
__device__ __forceinline__ float aldf(const float* p) {
  return __hip_atomic_load(p, __ATOMIC_RELAXED, __HIP_MEMORY_SCOPE_AGENT);
}
__device__ __forceinline__ void astf(float* p, float v) {
  __hip_atomic_store(p, v, __ATOMIC_RELAXED, __HIP_MEMORY_SCOPE_AGENT);
}
__device__ __forceinline__ unsigned ldu(const unsigned* p) {
  return __hip_atomic_load(p, __ATOMIC_RELAXED, __HIP_MEMORY_SCOPE_AGENT);
}
__device__ __forceinline__ unsigned long long ld64(const unsigned long long* p) {
  return __hip_atomic_load(p, __ATOMIC_RELAXED, __HIP_MEMORY_SCOPE_AGENT);
}
__device__ __forceinline__ void st64(unsigned long long* p, unsigned long long v) {
  __hip_atomic_store(p, v, __ATOMIC_RELAXED, __HIP_MEMORY_SCOPE_AGENT);
}
__device__ __forceinline__ void relTag(Tag* tg, unsigned v) {
  __hip_atomic_store(&tg->v, v, __ATOMIC_RELEASE, __HIP_MEMORY_SCOPE_AGENT);
}
// init barrier (startup only)
__device__ __forceinline__ void gbar(SyncBlk* sb, unsigned tgt) {
  __syncthreads();
  if (threadIdx.x == 0) {
    const unsigned old = __hip_atomic_fetch_add(&sb->ictr.v, 1u, __ATOMIC_RELEASE,
                                                __HIP_MEMORY_SCOPE_AGENT);
    if (old == tgt - 1u) relTag(&sb->igen, tgt);
    while (ldu(&sb->igen.v) < tgt) __builtin_amdgcn_s_sleep(2);
    __atomic_signal_fence(__ATOMIC_ACQUIRE);
  }
  __syncthreads();
}

// ---------------- Threefry2x32 (bit-exact vs JAX; validated) ----------------
__device__ __forceinline__ unsigned rotl32(unsigned v, int n) {
  return (v << n) | (v >> (32 - n));
}
__device__ __forceinline__ void tf2x32(unsigned k0, unsigned k1, unsigned x0, unsigned x1,
                                       unsigned& o0, unsigned& o1) {
  const unsigned k2 = k0 ^ k1 ^ 0x1BD11BDAu;
  unsigned v0 = x0 + k0, v1 = x1 + k1;
  v0 += v1; v1 = rotl32(v1, 13); v1 ^= v0;
  v0 += v1; v1 = rotl32(v1, 15); v1 ^= v0;
  v0 += v1; v1 = rotl32(v1, 26); v1 ^= v0;
  v0 += v1; v1 = rotl32(v1, 6);  v1 ^= v0;
  v0 += k1; v1 += k2 + 1u;
  v0 += v1; v1 = rotl32(v1, 17); v1 ^= v0;
  v0 += v1; v1 = rotl32(v1, 29); v1 ^= v0;
  v0 += v1; v1 = rotl32(v1, 16); v1 ^= v0;
  v0 += v1; v1 = rotl32(v1, 24); v1 ^= v0;
  v0 += k2; v1 += k0 + 2u;
  v0 += v1; v1 = rotl32(v1, 13); v1 ^= v0;
  v0 += v1; v1 = rotl32(v1, 15); v1 ^= v0;
  v0 += v1; v1 = rotl32(v1, 26); v1 ^= v0;
  v0 += v1; v1 = rotl32(v1, 6);  v1 ^= v0;
  v0 += k0; v1 += k1 + 3u;
  v0 += v1; v1 = rotl32(v1, 17); v1 ^= v0;
  v0 += v1; v1 = rotl32(v1, 29); v1 ^= v0;
  v0 += v1; v1 = rotl32(v1, 16); v1 ^= v0;
  v0 += v1; v1 = rotl32(v1, 24); v1 ^= v0;
  v0 += k1; v1 += k2 + 4u;
  v0 += v1; v1 = rotl32(v1, 13); v1 ^= v0;
  v0 += v1; v1 = rotl32(v1, 15); v1 ^= v0;
  v0 += v1; v1 = rotl32(v1, 26); v1 ^= v0;
  v0 += v1; v1 = rotl32(v1, 6);  v1 ^= v0;
  o0 = v0 + k2; o1 = v1 + k0 + 5u;
}
__device__ __forceinline__ unsigned rbits(unsigned k0, unsigned k1, unsigned i) {
#if PARTITIONABLE_PRNG
  unsigned a, b; tf2x32(k0, k1, 0u, i, a, b);
  return a ^ b;
#else
  constexpr unsigned HALF = (unsigned)((kB * kV + 1) / 2);
  unsigned a, b;
  if (i < HALF) { tf2x32(k0, k1, i, i + HALF, a, b); return a; }
  tf2x32(k0, k1, i - HALF, i, a, b); return b;
#endif
}
__device__ __forceinline__ float gumbel_from_bits(unsigned bits) {
  float f = __uint_as_float((bits >> 9) | 0x3f800000u) - 1.0f;
  f = fmaxf(f, kTiny);
  return -logf(-logf(f));
}
__device__ __forceinline__ unsigned ordkey(float f) {
  const unsigned u = __float_as_uint(f);
  return (u & 0x80000000u) ? ~u : (u | 0x80000000u);
}
__device__ __forceinline__ unsigned long long shflx64(unsigned long long v, int m) {
  unsigned lo = (unsigned)v, hi = (unsigned)(v >> 32);
  lo = (unsigned)__shfl_xor((int)lo, m, 64);
  hi = (unsigned)__shfl_xor((int)hi, m, 64);
  return ((unsigned long long)hi << 32) | (unsigned long long)lo;
}
__device__ __forceinline__ float sigm(float x) { return 1.0f / (1.0f + expf(-x)); }

// ---------------- chunk-synced LSTM tick (no barrier) -----------------------
template <bool STREAM>
__device__ __forceinline__ void lstm_tick(
    WS* ws, float* shf, int cw, int cc, bool do_l0, bool do_l1,
    const float* px, const float* pW0, const float* pW1,
    const float4* w0r, const float4* w1r, float biasr,
    float& c0, float& c1, float& h0last, float& h1last,
    int grow, int r, int w, int hzt) {
  const int tid = (int)threadIdx.x;
  float pxv0 = 0.f, pxv1 = 0.f, pxv2 = 0.f, pxv3 = 0.f;
  if (do_l0 && tid < 32) {   // issue px loads before the chunk spin (overlap)
    pxv0 = aldf(px + 0 * kG + grow);
    pxv1 = aldf(px + 1 * kG + grow);
    pxv2 = aldf(px + 2 * kG + grow);
    pxv3 = aldf(px + 3 * kG + grow);
  }
  // ---- consume 2048 chunks of tick cc-1 (8 per thread, batched spin) ----
  {
    const unsigned long long* base = &ws->hc[(cc + 1) & 1][0][0][0];
    const unsigned exp = (unsigned)cc;
    unsigned long long v[8];
#pragma unroll
    for (int k = 0; k < 8; ++k) v[k] = ld64(base + tid * 8 + k);
    unsigned pend = 0;
#pragma unroll
    for (int k = 0; k < 8; ++k) if ((unsigned)v[k] != exp) pend |= 1u << k;
    while (pend) {
#pragma unroll
      for (int k = 0; k < 8; ++k)
        if (pend & (1u << k)) v[k] = ld64(base + tid * 8 + k);
#pragma unroll
      for (int k = 0; k < 8; ++k)
        if ((unsigned)v[k] == exp) pend &= ~(1u << k);
    }
#pragma unroll
    for (int k = 0; k < 8; ++k) {
      const int c = tid * 8 + k, L = c >> 10, rem = c & 1023;
      const int wg2 = rem >> 5, s = rem & 31;
      shf[L * 1024 + (s >> 3) * 256 + wg2 * 8 + (s & 7)] =
          __uint_as_float((unsigned)(v[k] >> 32));
    }
  }
  __syncthreads();
  float4 wv0[8], wv1[16];
  if (do_l0) {
#pragma unroll
    for (int i = 0; i < 8; ++i)
      wv0[i] = STREAM ? *reinterpret_cast<const float4*>(pW0 + i * 4) : w0r[i];
  }
  if (do_l1) {
#pragma unroll
    for (int i = 0; i < 16; ++i)
      wv1[i] = STREAM ? *reinterpret_cast<const float4*>(pW1 + i * 4) : w1r[i];
  }
  if (do_l0) {
    const float* A = &shf[SH_H0 + w * 32];
    float a0 = 0.f, a1 = 0.f, a2 = 0.f, a3 = 0.f;
#pragma unroll
    for (int i = 0; i < 8; ++i) {
      const float4 wv = wv0[i];
      const float4 x0 = *reinterpret_cast<const float4*>(A + 0 * 256 + i * 4);
      const float4 x1 = *reinterpret_cast<const float4*>(A + 1 * 256 + i * 4);
      const float4 x2 = *reinterpret_cast<const float4*>(A + 2 * 256 + i * 4);
      const float4 x3 = *reinterpret_cast<const float4*>(A + 3 * 256 + i * 4);
      a0 = fmaf(wv.x, x0.x, a0); a0 = fmaf(wv.y, x0.y, a0); a0 = fmaf(wv.z, x0.z, a0); a0 = fmaf(wv.w, x0.w, a0);
      a1 = fmaf(wv.x, x1.x, a1); a1 = fmaf(wv.y, x1.y, a1); a1 = fmaf(wv.z, x1.z, a1); a1 = fmaf(wv.w, x1.w, a1);
      a2 = fmaf(wv.x, x2.x, a2); a2 = fmaf(wv.y, x2.y, a2); a2 = fmaf(wv.z, x2.z, a2); a2 = fmaf(wv.w, x2.w, a2);
      a3 = fmaf(wv.x, x3.x, a3); a3 = fmaf(wv.y, x3.y, a3); a3 = fmaf(wv.z, x3.z, a3); a3 = fmaf(wv.w, x3.w, a3);
    }
    *reinterpret_cast<float4*>(&shf[SH_P0 + w * 128 + r * 4]) = float4{a0, a1, a2, a3};
  }
  if (do_l1) {
    const float* Bp = (w < 4) ? &shf[SH_H0 + w * 64] : &shf[SH_H1 + (w - 4) * 64];
    float a0 = 0.f, a1 = 0.f, a2 = 0.f, a3 = 0.f;
#pragma unroll
    for (int i = 0; i < 16; ++i) {
      const float4 wv = wv1[i];
      const float4 x0 = *reinterpret_cast<const float4*>(Bp + 0 * 256 + i * 4);
      const float4 x1 = *reinterpret_cast<const float4*>(Bp + 1 * 256 + i * 4);
      const float4 x2 = *reinterpret_cast<const float4*>(Bp + 2 * 256 + i * 4);
      const float4 x3 = *reinterpret_cast<const float4*>(Bp + 3 * 256 + i * 4);
      a0 = fmaf(wv.x, x0.x, a0); a0 = fmaf(wv.y, x0.y, a0); a0 = fmaf(wv.z, x0.z, a0); a0 = fmaf(wv.w, x0.w, a0);
      a1 = fmaf(wv.x, x1.x, a1); a1 = fmaf(wv.y, x1.y, a1); a1 = fmaf(wv.z, x1.z, a1); a1 = fmaf(wv.w, x1.w, a1);
      a2 = fmaf(wv.x, x2.x, a2); a2 = fmaf(wv.y, x2.y, a2); a2 = fmaf(wv.z, x2.z, a2); a2 = fmaf(wv.w, x2.w, a2);
      a3 = fmaf(wv.x, x3.x, a3); a3 = fmaf(wv.y, x3.y, a3); a3 = fmaf(wv.z, x3.z, a3); a3 = fmaf(wv.w, x3.w, a3);
    }
    *reinterpret_cast<float4*>(&shf[SH_P1 + w * 128 + r * 4]) = float4{a0, a1, a2, a3};
  }
  __syncthreads();
  if (tid < 64) {
    const int L = tid >> 5, rr = tid & 31;
    const bool en = L ? do_l1 : do_l0;
    if (en) {
      const int base = (L ? SH_P1 : SH_P0) + rr * 4;
      float4 z = float4{0.f, 0.f, 0.f, 0.f};
#pragma unroll
      for (int w2 = 0; w2 < 8; ++w2) {
        const float4 p = *reinterpret_cast<const float4*>(&shf[base + w2 * 128]);
        z.x += p.x; z.y += p.y; z.z += p.z; z.w += p.w;
      }
      z.x += biasr; z.y += biasr; z.z += biasr; z.w += biasr;
      if (L == 0) { z.x += pxv0; z.y += pxv1; z.z += pxv2; z.w += pxv3; }
      *reinterpret_cast<float4*>(&shf[SH_Z + L * 128 + rr * 4]) = z;
    }
  }
  __syncthreads();
  if (tid < 64) {
    const int L = tid >> 5, slot = tid & 31, b = slot >> 3, u = slot & 7;
    const bool en = L ? do_l1 : do_l0;
    float hn;
    if (en) {
      const int zb = SH_Z + L * 128 + u * 16 + b;
      const float zi = shf[zb], zf = shf[zb + 4], zg = shf[zb + 8], zo = shf[zb + 12];
      const float cs = L ? c1 : c0;
      const float cn = sigm(zf) * cs + sigm(zi) * tanhf(zg);
      hn = sigm(zo) * tanhf(cn);
      if (L) c1 = cn; else c0 = cn;
    } else {
      hn = L ? h1last : h0last;
    }
    if (L) h1last = hn; else h0last = hn;
    st64(&ws->hc[cc & 1][L][cw][slot],
         ((unsigned long long)__float_as_uint(hn) << 32) |
         (unsigned long long)(unsigned)(cc + 1));
    if (L && hzt >= 0) astf(&ws->hzbuf[hzt & 1][b][cw * 8 + u], hn);
  }
}

// ---------------- kernel ----------------
__global__ void __launch_bounds__(TPB, 1) s2s_kernel(
    const int* __restrict__ input_ids, const float* __restrict__ labels,
    const float* __restrict__ emb,
    const float* __restrict__ W_e2e, const float* __restrict__ b_e2e,
    const float* __restrict__ W_e2d, const float* __restrict__ b_e2d,
    const float* __restrict__ encWih, const float* __restrict__ encWhh,
    const float* __restrict__ encbih, const float* __restrict__ encbhh,
    const float* __restrict__ decWih, const float* __restrict__ decWhh,
    const float* __restrict__ decbih, const float* __restrict__ decbhh,
    const float* __restrict__ W_cls, const float* __restrict__ b_cls,
    const float* __restrict__ Wfc1, const float* __restrict__ bfc1,
    const float* __restrict__ lng, const float* __restrict__ lnb,
    const float* __restrict__ W_fc2, const float* __restrict__ b_fc2,
    float* __restrict__ out, WS* __restrict__ ws) {
  const int wg = (int)blockIdx.x;
  const int tid = (int)threadIdx.x;
  SyncBlk* sb = &ws->s;
  __shared__ __align__(16) float shf[SH_TOT];
  __shared__ unsigned long long shk[16];
  __shared__ int shi[8];

  // ================= init phase 1 =================
  if (wg < kB * kT) {
    const int b = wg / kT, j = wg % kT;
    const int id = input_ids[b * kT + j];
    for (int i = tid; i < kE; i += 256) shf[i] = emb[(size_t)id * kE + i];
    __syncthreads();
    const float* wr = W_e2e + (size_t)tid * kE;
    float acc = b_e2e[tid];
    for (int k = 0; k < kE; k += 4) {
      const float4 wv = *reinterpret_cast<const float4*>(wr + k);
      const float4 xv = *reinterpret_cast<const float4*>(&shf[k]);
      acc = fmaf(xv.x, wv.x, acc); acc = fmaf(xv.y, wv.y, acc);
      acc = fmaf(xv.z, wv.z, acc); acc = fmaf(xv.w, wv.w, acc);
    }
    __syncthreads();
    shf[256 + tid] = fmaxf(acc, 0.f);
  } else if (wg == 192) {
    if (tid < kB) {
      const int t0 = input_ids[tid * kT];
      out[tid * kT] = 0.f;
      out[kB * kT + tid * kT] = (float)t0;
    }
  } else if (wg == 193) {
    const float* wr = W_e2d + (size_t)tid * kE;
    const float* e0 = emb + (size_t)input_ids[0 * kT] * kE;
    const float* e1 = emb + (size_t)input_ids[1 * kT] * kE;
    const float* e2 = emb + (size_t)input_ids[2 * kT] * kE;
    const float* e3 = emb + (size_t)input_ids[3 * kT] * kE;
    const float bb = b_e2d[tid];
    float a0 = bb, a1 = bb, a2 = bb, a3 = bb;
    for (int k = 0; k < kE; k += 4) {
      const float4 wv = *reinterpret_cast<const float4*>(wr + k);
      const float4 v0 = *reinterpret_cast<const float4*>(e0 + k);
      const float4 v1 = *reinterpret_cast<const float4*>(e1 + k);
      const float4 v2 = *reinterpret_cast<const float4*>(e2 + k);
      const float4 v3 = *reinterpret_cast<const float4*>(e3 + k);
      a0 = fmaf(v0.x, wv.x, a0); a0 = fmaf(v0.y, wv.y, a0); a0 = fmaf(v0.z, wv.z, a0); a0 = fmaf(v0.w, wv.w, a0);
      a1 = fmaf(v1.x, wv.x, a1); a1 = fmaf(v1.y, wv.y, a1); a1 = fmaf(v1.z, wv.z, a1); a1 = fmaf(v1.w, wv.w, a1);
      a2 = fmaf(v2.x, wv.x, a2); a2 = fmaf(v2.y, wv.y, a2); a2 = fmaf(v2.z, wv.z, a2); a2 = fmaf(v2.w, wv.w, a2);
      a3 = fmaf(v3.x, wv.x, a3); a3 = fmaf(v3.y, wv.y, a3); a3 = fmaf(v3.z, wv.z, a3); a3 = fmaf(v3.w, wv.w, a3);
    }
    astf(&ws->xd0[0][tid], fmaxf(a0, 0.f));
    astf(&ws->xd0[1][tid], fmaxf(a1, 0.f));
    astf(&ws->xd0[2][tid], fmaxf(a2, 0.f));
    astf(&ws->xd0[3][tid], fmaxf(a3, 0.f));
  }
  gbar(sb, (unsigned)NWG);

  // ================= init phase 2 =================
  if (wg < kB * kT) {
    const int b = wg / kT, j = wg % kT;
#pragma unroll
    for (int rr = 0; rr < 4; ++rr) {
      const int g = rr * 256 + tid;
      const float* wr = encWih + (size_t)g * kH;
      float acc = 0.f;
      for (int k = 0; k < kH; k += 4) {
        const float4 wv = *reinterpret_cast<const float4*>(wr + k);
        const float4 xv = *reinterpret_cast<const float4*>(&shf[256 + k]);
        acc = fmaf(xv.x, wv.x, acc); acc = fmaf(xv.y, wv.y, acc);
        acc = fmaf(xv.z, wv.z, acc); acc = fmaf(xv.w, wv.w, acc);
      }
      astf(&ws->pxe[j][0][0] + (size_t)b * kG + g, acc);
    }
  } else if (wg >= 192 && wg < 208) {
    const int w2 = wg - 192, b = w2 >> 2, q = w2 & 3;
    const int g = q * 256 + tid;
    for (int i = tid; i < kH; i += 256) shf[i] = aldf(&ws->xd0[b][i]);
    __syncthreads();
    const float* wr = decWih + (size_t)g * kH;
    float acc = 0.f;
    for (int k = 0; k < kH; k += 4) {
      const float4 wv = *reinterpret_cast<const float4*>(wr + k);
      const float4 xv = *reinterpret_cast<const float4*>(&shf[k]);
      acc = fmaf(xv.x, wv.x, acc); acc = fmaf(xv.y, wv.y, acc);
      acc = fmaf(xv.z, wv.z, acc); acc = fmaf(xv.w, wv.w, acc);
    }
    astf(&ws->px0[0][0][0] + (size_t)b * kG + g, acc);
  }
  gbar(sb, (unsigned)(2 * NWG));

  // ================= roles =================
  if (wg < NCL) {
    // ---------------- cluster ----------------
    const int cw = wg;
    const int r = tid & 31, w = tid >> 5;
    const int grow = (r & 3) * 256 + cw * 8 + (r >> 2);
    const int L = tid >> 5;
    float c0 = 0.f, c1 = 0.f, h0last = 0.f, h1last = 0.f;
    float biasr = 0.f;
    if (tid < 64)
      biasr = (L == 0) ? encbih[grow] + encbhh[grow]
                       : encbih[kG + grow] + encbhh[kG + grow];
    const float* pW0e = encWhh + (size_t)grow * kH + w * 32;
    const float* pW1e = (w < 4)
        ? encWih + (size_t)kG * kH + (size_t)grow * kH + w * 64
        : encWhh + (size_t)kG * kH + (size_t)grow * kH + (w - 4) * 64;
    int cc = 0;
    for (int j = 0; j < kT; ++j, ++cc)
      lstm_tick<true>(ws, shf, cw, cc, true, j > 0, &ws->pxe[j][0][0],
                      pW0e, pW1e, nullptr, nullptr, biasr, c0, c1,
                      h0last, h1last, grow, r, w, -1);
    lstm_tick<true>(ws, shf, cw, cc, false, true, nullptr,
                    pW0e, pW1e, nullptr, nullptr, biasr, c0, c1,
                    h0last, h1last, grow, r, w, -1);
    ++cc;
    float4 w0d[8], w1d[16];
    {
      const float* p0 = decWhh + (size_t)grow * kH + w * 32;
#pragma unroll
      for (int i = 0; i < 8; ++i) w0d[i] = *reinterpret_cast<const float4*>(p0 + i * 4);
      const float* p1 = (w < 4)
          ? decWih + (size_t)kG * kH + (size_t)grow * kH + w * 64
          : decWhh + (size_t)kG * kH + (size_t)grow * kH + (w - 4) * 64;
#pragma unroll
      for (int i = 0; i < 16; ++i) w1d[i] = *reinterpret_cast<const float4*>(p1 + i * 4);
      if (tid < 64)
        biasr = (L == 0) ? decbih[grow] + decbhh[grow]
                         : decbih[kG + grow] + decbhh[kG + grow];
    }
    for (int t = 1; t < kT; ++t) {
      for (int j = 0; j < t; ++j, ++cc) {
        const bool d1 = (j > 0) || (t >= 2);
        const int hzt = (j == 0 && t >= 2) ? (t - 1) : -1;
        if (j == t - 1 && t >= 2) {
          if (tid < 64) {
            Tag* p = &sb->ptok4[tid >> 2][tid & 3];
            while (ldu(&p->v) < (unsigned)(t - 1)) {}
            __atomic_signal_fence(__ATOMIC_ACQUIRE);
          }
          __syncthreads();
        }
        lstm_tick<false>(ws, shf, cw, cc, true, d1, &ws->px0[j][0][0],
                         nullptr, nullptr, w0d, w1d, biasr, c0, c1,
                         h0last, h1last, grow, r, w, hzt);
        if (hzt >= 0 && tid == 0) relTag(&sb->hztag[cw], (unsigned)hzt);
      }
    }
    lstm_tick<false>(ws, shf, cw, cc, false, true, nullptr,
                     nullptr, nullptr, w0d, w1d, biasr, c0, c1,
                     h0last, h1last, grow, r, w, kT - 1);
    if (tid == 0) relTag(&sb->hztag[cw], (unsigned)(kT - 1));
  } else if (wg == LEAD) {
    // ---------------- leader ----------------
    if (tid < kB * kCc) {
      const int b = tid >> 6, c = tid & 63;
      shf[LD_CLS + tid] = fmaf(labels[b], W_cls[c], b_cls[c]);
    }
    __syncthreads();
    for (int t = 1; t < kT; ++t) {
      if (tid < NCL) {
        while (ldu(&sb->hztag[tid].v) < (unsigned)t) __builtin_amdgcn_s_sleep(1);
        __atomic_signal_fence(__ATOMIC_ACQUIRE);
      }
      __syncthreads();
      for (int i = tid; i < kB * kZ; i += 256) {
        const int b = i / kZ, k = i - b * kZ;
        shf[LD_ZIN + i] = (k < kH) ? aldf(&ws->hzbuf[t & 1][b][k])
                                   : shf[LD_CLS + b * kCc + (k - kH)];
      }
      __syncthreads();
#pragma unroll
      for (int rep = 0; rep < 5; ++rep) {
        const int task = tid + rep * 256;
        const int b = task / kZ, o = task - b * kZ;
        const float* wr = Wfc1 + (size_t)o * kZ;
        const float* zz = &shf[LD_ZIN + b * kZ];
        float acc = bfc1[o];
        for (int k = 0; k < kZ; k += 4) {
          const float4 wv = *reinterpret_cast<const float4*>(wr + k);
          const float4 zv = *reinterpret_cast<const float4*>(zz + k);
          acc = fmaf(zv.x, wv.x, acc); acc = fmaf(zv.y, wv.y, acc);
          acc = fmaf(zv.z, wv.z, acc); acc = fmaf(zv.w, wv.w, acc);
        }
        shf[LD_Z1 + task] = fmaxf(acc, 0.f);
      }
      __syncthreads();
      {
        const int b = tid >> 6, ln = tid & 63;
        float s1 = 0.f, s2 = 0.f;
        for (int i = ln; i < kZ; i += 64) {
          const float v = shf[LD_Z1 + b * kZ + i]; s1 += v; s2 += v * v;
        }
#pragma unroll
        for (int o = 32; o > 0; o >>= 1) { s1 += __shfl_xor(s1, o, 64); s2 += __shfl_xor(s2, o, 64); }
        const float mu = s1 * (1.0f / kZ);
        const float var = s2 * (1.0f / kZ) - mu * mu;
        const float rs = 1.0f / sqrtf(var + kEps);
        for (int i = ln; i < kZ; i += 64) {
          const float v = fmaf((shf[LD_Z1 + b * kZ + i] - mu) * rs, lng[i], lnb[i]);
          shf[LD_Z1 + b * kZ + i] = v;
          astf(&ws->z1n[t & 1][b][i], v);
        }
        if (ln == 0) relTag(&sb->ztag4[b], (unsigned)t);
      }
      if (tid < NGANG) {
        while (ldu(&sb->gout[tid].tag) < (unsigned)t) __builtin_amdgcn_s_sleep(2);
        __atomic_signal_fence(__ATOMIC_ACQUIRE);
      }
      __syncthreads();
      {
        unsigned long long kk[kB];
        float pp[kB];
        if (tid < NGANG) {
          const GOut* g = &sb->gout[tid];
#pragma unroll
          for (int b = 0; b < kB; ++b) { kk[b] = ld64(&g->key[b]); pp[b] = aldf(&g->ps[b]); }
        } else {
#pragma unroll
          for (int b = 0; b < kB; ++b) { kk[b] = 0ull; pp[b] = 0.f; }
        }
#pragma unroll
        for (int b = 0; b < kB; ++b) {
#pragma unroll
          for (int m = 1; m < 64; m <<= 1) {
            const unsigned long long ko = shflx64(kk[b], m);
            pp[b] += __shfl_xor(pp[b], m, 64);
            if (ko > kk[b]) kk[b] = ko;
          }
        }
        if ((tid & 63) == 0) {
          const int wv = tid >> 6;
#pragma unroll
          for (int b = 0; b < kB; ++b) { shk[wv * kB + b] = kk[b]; shf[LD_WPS + wv * kB + b] = pp[b]; }
        }
      }
      __syncthreads();
      if (tid < kB) {
        const int b = tid;
        unsigned long long key = shk[b];
        float s = shf[LD_WPS + b];
        for (int wv = 1; wv < 4; ++wv) {
          const unsigned long long ko = shk[wv * kB + b];
          if (ko > key) key = ko;
          s += shf[LD_WPS + wv * kB + b];
        }
        const int samp = (int)(0xFFFFFFFFu - (unsigned)(key & 0xFFFFFFFFull));
        const float lse = logf(s);
        const int cur = input_ids[b * kT + t];
        const int nxt = (cur == kMask) ? samp : cur;
        out[kB * kT + b * kT + t] = (float)nxt;
        shi[b] = nxt; shi[4 + b] = samp;
        shf[LD_LSE + b] = lse;
      }
      __syncthreads();
      if (t < kT - 1) {
        const float* wr = W_e2d + (size_t)tid * kE;
        const float* e0 = emb + (size_t)shi[0] * kE;
        const float* e1 = emb + (size_t)shi[1] * kE;
        const float* e2 = emb + (size_t)shi[2] * kE;
        const float* e3 = emb + (size_t)shi[3] * kE;
        const float bb = b_e2d[tid];
        float a0 = bb, a1 = bb, a2 = bb, a3 = bb;
        for (int k = 0; k < kE; k += 4) {
          const float4 wv = *reinterpret_cast<const float4*>(wr + k);
          const float4 v0 = *reinterpret_cast<const float4*>(e0 + k);
          const float4 v1 = *reinterpret_cast<const float4*>(e1 + k);
          const float4 v2 = *reinterpret_cast<const float4*>(e2 + k);
          const float4 v3 = *reinterpret_cast<const float4*>(e3 + k);
          a0 = fmaf(v0.x, wv.x, a0); a0 = fmaf(v0.y, wv.y, a0); a0 = fmaf(v0.z, wv.z, a0); a0 = fmaf(v0.w, wv.w, a0);
          a1 = fmaf(v1.x, wv.x, a1); a1 = fmaf(v1.y, wv.y, a1); a1 = fmaf(v1.z, wv.z, a1); a1 = fmaf(v1.w, wv.w, a1);
          a2 = fmaf(v2.x, wv.x, a2); a2 = fmaf(v2.y, wv.y, a2); a2 = fmaf(v2.z, wv.z, a2); a2 = fmaf(v2.w, wv.w, a2);
          a3 = fmaf(v3.x, wv.x, a3); a3 = fmaf(v3.y, wv.y, a3); a3 = fmaf(v3.z, wv.z, a3); a3 = fmaf(v3.w, wv.w, a3);
        }
        astf(&ws->xcur[0][tid], fmaxf(a0, 0.f));
        astf(&ws->xcur[1][tid], fmaxf(a1, 0.f));
        astf(&ws->xcur[2][tid], fmaxf(a2, 0.f));
        astf(&ws->xcur[3][tid], fmaxf(a3, 0.f));
        if ((tid & 63) == 0) relTag(&sb->etok4[tid >> 6], (unsigned)t);
      }
      {
        const int b = tid >> 6, lane = tid & 63;
        const int sp = shi[4 + b];
        const float* wr = W_fc2 + (size_t)sp * kZ;
        float acc = 0.f;
#pragma unroll
        for (int i = 0; i < 5; ++i)
          acc = fmaf(shf[LD_Z1 + b * kZ + lane + i * 64], wr[lane + i * 64], acc);
#pragma unroll
        for (int o = 32; o > 0; o >>= 1) acc += __shfl_xor(acc, o, 64);
        if (lane == 0) out[b * kT + t] = acc + b_fc2[sp] - shf[LD_LSE + b];
      }
      __syncthreads();
    }
  } else {
    // ---------------- gang ----------------
    const int gi = wg - GANG0;
    const int start = gi * RPW;
    const int cnt = (RPW < kV - start) ? RPW : (kV - start);
    const bool act = tid < cnt;
    const int row = start + tid;
    for (int t = 1; t < kT; ++t) {
      if (tid < 4) {
        while (ldu(&sb->ztag4[tid].v) < (unsigned)t) __builtin_amdgcn_s_sleep(16);
        __atomic_signal_fence(__ATOMIC_ACQUIRE);
      }
      __syncthreads();
      for (int i = tid; i < kB * kZ; i += 256) shf[i] = aldf(&ws->z1n[t & 1][0][0] + i);
      __syncthreads();
      unsigned fk0, fk1;
      tf2x32(0u, 1234u, 0u, (unsigned)t, fk0, fk1);
      float lv[kB] = {0.f, 0.f, 0.f, 0.f};
      if (act) {
        const float* wr = W_fc2 + (size_t)row * kZ;
        const float bb = b_fc2[row];
        float a0 = bb, a1 = bb, a2 = bb, a3 = bb;
        for (int k = 0; k < kZ; k += 4) {
          const float4 wv = *reinterpret_cast<const float4*>(wr + k);
          const float4 z0 = *reinterpret_cast<const float4*>(&shf[0 * kZ + k]);
          const float4 z1 = *reinterpret_cast<const float4*>(&shf[1 * kZ + k]);
          const float4 z2 = *reinterpret_cast<const float4*>(&shf[2 * kZ + k]);
          const float4 z3 = *reinterpret_cast<const float4*>(&shf[3 * kZ + k]);
          a0 = fmaf(z0.x, wv.x, a0); a0 = fmaf(z0.y, wv.y, a0); a0 = fmaf(z0.z, wv.z, a0); a0 = fmaf(z0.w, wv.w, a0);
          a1 = fmaf(z1.x, wv.x, a1); a1 = fmaf(z1.y, wv.y, a1); a1 = fmaf(z1.z, wv.z, a1); a1 = fmaf(z1.w, wv.w, a1);
          a2 = fmaf(z2.x, wv.x, a2); a2 = fmaf(z2.y, wv.y, a2); a2 = fmaf(z2.z, wv.z, a2); a2 = fmaf(z2.w, wv.w, a2);
          a3 = fmaf(z3.x, wv.x, a3); a3 = fmaf(z3.y, wv.y, a3); a3 = fmaf(z3.z, wv.z, a3); a3 = fmaf(z3.w, wv.w, a3);
        }
        lv[0] = a0; lv[1] = a1; lv[2] = a2; lv[3] = a3;
      }
#pragma unroll
      for (int b = 0; b < kB; ++b) {
        unsigned long long key = 0ull;
        float sv = 0.f;
        if (act) {
          const unsigned bits = rbits(fk0, fk1, (unsigned)(b * kV + row));
          const float pv = lv[b] + gumbel_from_bits(bits);
          key = ((unsigned long long)ordkey(pv) << 32) |
                (unsigned long long)(0xFFFFFFFFu - (unsigned)row);
          sv = expf(lv[b]);
        }
#pragma unroll
        for (int m = 1; m < 64; m <<= 1) {
          const unsigned long long ko = shflx64(key, m);
          sv += __shfl_xor(sv, m, 64);
          if (ko > key) key = ko;
        }
        if ((tid & 63) == 0) { shk[(tid >> 6) * kB + b] = key; shf[1408 + (tid >> 6) * kB + b] = sv; }
      }
      __syncthreads();
      if (tid == 0) {
        GOut* g = &sb->gout[gi];
#pragma unroll
        for (int b = 0; b < kB; ++b) {
          unsigned long long key = shk[b];
          float s = shf[1408 + b];
          for (int w2 = 1; w2 < 4; ++w2) {
            const unsigned long long ko = shk[w2 * kB + b];
            if (ko > key) key = ko;
            s += shf[1408 + w2 * kB + b];
          }
          st64(&g->key[b], key);
          astf(&g->ps[b], s);
        }
        __hip_atomic_store(&g->tag, (unsigned)t, __ATOMIC_RELEASE, __HIP_MEMORY_SCOPE_AGENT);
      }
      __syncthreads();
      if (gi < NPX && t < kT - 1) {
        if (tid < 4) {
          while (ldu(&sb->etok4[tid].v) < (unsigned)t) __builtin_amdgcn_s_sleep(8);
          __atomic_signal_fence(__ATOMIC_ACQUIRE);
        }
        __syncthreads();
        for (int i = tid; i < kB * kH; i += 256) shf[i] = aldf(&ws->xcur[0][0] + i);
        __syncthreads();
        {
          const int rowg = gi * 64 + (tid & 63), b = tid >> 6;
          const float* wr = decWih + (size_t)rowg * kH;
          const float* xz = &shf[b * kH];
          float acc = 0.f;
          for (int k = 0; k < kH; k += 4) {
            const float4 wv = *reinterpret_cast<const float4*>(wr + k);
            const float4 xv = *reinterpret_cast<const float4*>(xz + k);
            acc = fmaf(xv.x, wv.x, acc); acc = fmaf(xv.y, wv.y, acc);
            acc = fmaf(xv.z, wv.z, acc); acc = fmaf(xv.w, wv.w, acc);
          }
          astf(&ws->px0[t][0][0] + (size_t)b * kG + rowg, acc);
          if ((tid & 63) == 0) relTag(&sb->ptok4[gi][tid >> 6], (unsigned)t);
        }
      }
      __syncthreads();
    }
  }
}

} // namespace s2sr

extern "C" void kernel_launch(void* const* d_in, const int* in_sizes, int n_in,
                              void* d_out, int out_size, void* d_ws, size_t ws_size,
                              hipStream_t stream) {
  using namespace s2sr;
  (void)in_sizes; (void)n_in; (void)out_size;
  if (ws_size < sizeof(WS)) return;
  const int*   input_ids = (const int*)d_in[0];
  // d_in[1] = attention_mask (unused)
  const float* labels    = (const float*)d_in[2];
  const float* emb       = (const float*)d_in[3];
  const float* W_e2e     = (const float*)d_in[4];
  const float* b_e2e     = (const float*)d_in[5];
  const float* W_e2d     = (const float*)d_in[6];
  const float* b_e2d     = (const float*)d_in[7];
  const float* encWih    = (const float*)d_in[8];
  const float* encWhh    = (const float*)d_in[9];
  const float* encbih    = (const float*)d_in[10];
  const float* encbhh    = (const float*)d_in[11];
  const float* decWih    = (const float*)d_in[12];
  const float* decWhh    = (const float*)d_in[13];
  const float* decbih    = (const float*)d_in[14];
  const float* decbhh    = (const float*)d_in[15];
  const float* W_cls     = (const float*)d_in[16];
  const float* b_cls     = (const float*)d_in[17];
  const float* W_fc1     = (const float*)d_in[18];
  const float* b_fc1     = (const float*)d_in[19];
  const float* ln_g      = (const float*)d_in[20];
  const float* ln_b      = (const float*)d_in[21];
  const float* W_fc2     = (const float*)d_in[22];
  const float* b_fc2     = (const float*)d_in[23];

  // re-arm tags + zero chunk seqs
  hipMemsetAsync(d_ws, 0, (size_t)offsetof(WS, xd0), stream);
  hipLaunchKernelGGL(s2s_kernel, dim3(NWG), dim3(TPB), 0, stream,
      input_ids, labels, emb, W_e2e, b_e2e, W_e2d, b_e2d,
      encWih, encWhh, encbih, encbhh, decWih, decWhh, decbih, decbhh,
      W_cls, b_cls, W_fc1, b_fc1, ln_g, ln_b, W_fc2, b_fc2,
      (float*)d_out, (WS*)d_ws);
}